// Round 1
// baseline (2788.747 us; speedup 1.0000x reference)
//
#include <hip/hip_runtime.h>
#include <hip/hip_bf16.h>
#include <math.h>

// Problem constants
#define BS   8
#define NSEQ 1025
#define DIM  768
#define C3   2304      // 3*DIM
#define HEADS 12
#define DH   64
#define MROWS (BS*NSEQ) // 8200

// ---------------------------------------------------------------------------
// Generic fp32 SGEMM with bias: C[M,N] = A[M,K] @ B[K,N] + bias[N]
// 128x128 block tile, BK=8, 256 threads, 8x8 per-thread microtile.
// ---------------------------------------------------------------------------
__global__ __launch_bounds__(256) void sgemm_bias_kernel(
    const float* __restrict__ A, const float* __restrict__ B,
    const float* __restrict__ bias, float* __restrict__ C,
    int M, int N, int K) {
  __shared__ float As[8][128];   // transposed A tile: As[k][m]
  __shared__ float Bs[8][128];
  const int tid = threadIdx.x;
  const int m0 = blockIdx.y * 128;
  const int n0 = blockIdx.x * 128;
  const int ty = tid >> 4;       // 0..15
  const int tx = tid & 15;       // 0..15
  const int arow = tid >> 1;           // 0..127
  const int ak   = (tid & 1) << 2;     // 0 or 4
  const int brow = tid >> 5;           // 0..7
  const int bcol = (tid & 31) << 2;    // 0..124
  const bool aval = (m0 + arow) < M;
  const float* Aptr = A + (size_t)(m0 + arow) * K + ak;
  const float* Bptr = B + (size_t)brow * N + n0 + bcol;

  float acc[8][8];
  #pragma unroll
  for (int i = 0; i < 8; ++i)
    #pragma unroll
    for (int j = 0; j < 8; ++j) acc[i][j] = 0.f;

  for (int k0 = 0; k0 < K; k0 += 8) {
    float4 av = aval ? *(const float4*)(Aptr + k0)
                     : make_float4(0.f, 0.f, 0.f, 0.f);
    float4 bv = *(const float4*)(Bptr + (size_t)k0 * N);
    As[ak + 0][arow] = av.x;
    As[ak + 1][arow] = av.y;
    As[ak + 2][arow] = av.z;
    As[ak + 3][arow] = av.w;
    *(float4*)&Bs[brow][bcol] = bv;
    __syncthreads();
    #pragma unroll
    for (int kk = 0; kk < 8; ++kk) {
      float4 a0 = *(const float4*)&As[kk][ty * 8];
      float4 a1 = *(const float4*)&As[kk][ty * 8 + 4];
      float4 b0 = *(const float4*)&Bs[kk][tx * 8];
      float4 b1 = *(const float4*)&Bs[kk][tx * 8 + 4];
      float a[8] = {a0.x, a0.y, a0.z, a0.w, a1.x, a1.y, a1.z, a1.w};
      float bb[8] = {b0.x, b0.y, b0.z, b0.w, b1.x, b1.y, b1.z, b1.w};
      #pragma unroll
      for (int i = 0; i < 8; ++i)
        #pragma unroll
        for (int j = 0; j < 8; ++j) acc[i][j] += a[i] * bb[j];
    }
    __syncthreads();
  }

  #pragma unroll
  for (int i = 0; i < 8; ++i) {
    int row = m0 + ty * 8 + i;
    if (row < M) {
      float* cp = &C[(size_t)row * N + n0 + tx * 8];
      const float* bp = &bias[n0 + tx * 8];
      #pragma unroll
      for (int j = 0; j < 8; ++j) cp[j] = acc[i][j] + bp[j];
    }
  }
}

// ---------------------------------------------------------------------------
// In-place LayerNorm on q and k portions of qkv[M, 2304].
// One wave per (row, head). Q additionally scaled by 1/sqrt(DH)=0.125.
// ---------------------------------------------------------------------------
__global__ __launch_bounds__(256) void ln_qk_kernel(
    float* __restrict__ qkv,
    const float* __restrict__ gq, const float* __restrict__ bq,
    const float* __restrict__ gk, const float* __restrict__ bk) {
  const int task = blockIdx.x * 4 + (threadIdx.x >> 6);
  const int lane = threadIdx.x & 63;
  const int TASKS = MROWS * HEADS;
  if (task >= TASKS) return;
  const int row = task / HEADS;
  const int h = task - row * HEADS;
  const size_t base = (size_t)row * C3 + h * DH;
  float xq = qkv[base + lane];
  float xk = qkv[base + DIM + lane];
  float sq = xq, s2q = xq * xq, sk = xk, s2k = xk * xk;
  #pragma unroll
  for (int off = 32; off; off >>= 1) {
    sq  += __shfl_xor(sq,  off);
    s2q += __shfl_xor(s2q, off);
    sk  += __shfl_xor(sk,  off);
    s2k += __shfl_xor(s2k, off);
  }
  const float inv64 = 1.f / 64.f;
  float mq = sq * inv64, vq = s2q * inv64 - mq * mq;
  float mk = sk * inv64, vk = s2k * inv64 - mk * mk;
  float rq = rsqrtf(vq + 1e-5f), rk = rsqrtf(vk + 1e-5f);
  qkv[base + lane]       = ((xq - mq) * rq * gq[lane] + bq[lane]) * 0.125f;
  qkv[base + DIM + lane] =  (xk - mk) * rk * gk[lane] + bk[lane];
}

// ---------------------------------------------------------------------------
// Flash-style attention. Block = 64 threads (1 wave) handles 64 query rows
// of one (b,h). K/V tiles staged in LDS; per-thread Q row + O accumulator in
// registers; per-key online softmax. Q is pre-scaled by 0.125.
// Output layout: attn_out[row*768 + h*64 + d]  (row = b*NSEQ + n)
// ---------------------------------------------------------------------------
__global__ __launch_bounds__(64) void attn_kernel(
    const float* __restrict__ qkv, float* __restrict__ attn_out) {
  const int bh = blockIdx.y;           // 0..95
  const int b = bh / HEADS, h = bh % HEADS;
  const int q0 = blockIdx.x * 64;
  const int t = threadIdx.x;
  __shared__ float kt[64 * 64];
  __shared__ float vt[64 * 64];
  const size_t rowbase = (size_t)b * NSEQ;

  const int qi = q0 + t;
  float4 q4[16];
  if (qi < NSEQ) {
    const float* qp = &qkv[(rowbase + qi) * C3 + h * DH];
    #pragma unroll
    for (int i = 0; i < 16; ++i) q4[i] = *(const float4*)&qp[i * 4];
  } else {
    #pragma unroll
    for (int i = 0; i < 16; ++i) q4[i] = make_float4(0.f, 0.f, 0.f, 0.f);
  }

  float4 o4[16];
  #pragma unroll
  for (int i = 0; i < 16; ++i) o4[i] = make_float4(0.f, 0.f, 0.f, 0.f);
  float m = -INFINITY, l = 0.f;

  const int r = t >> 4;              // 0..3
  const int f = (t & 15) << 2;       // 0..60

  for (int k0 = 0; k0 < NSEQ; k0 += 64) {
    const int nk = min(64, NSEQ - k0);
    #pragma unroll
    for (int p = 0; p < 16; ++p) {
      int row = p * 4 + r;
      if (row < nk) {
        const float* kp = &qkv[(rowbase + k0 + row) * C3 + DIM + h * DH];
        *(float4*)&kt[row * 64 + f] = *(const float4*)&kp[f];
        *(float4*)&vt[row * 64 + f] = *(const float4*)&kp[DIM + f];
      }
    }
    __syncthreads();
    for (int j = 0; j < nk; ++j) {
      const float4* kr = (const float4*)&kt[j * 64];
      float s = 0.f;
      #pragma unroll
      for (int i = 0; i < 16; ++i) {
        float4 kv = kr[i];
        float4 qv = q4[i];
        s += qv.x * kv.x + qv.y * kv.y + qv.z * kv.z + qv.w * kv.w;
      }
      float mn = fmaxf(m, s);
      float corr = __expf(m - mn);   // m=-inf first iter -> 0
      float p = __expf(s - mn);
      l = l * corr + p;
      const float4* vr = (const float4*)&vt[j * 64];
      #pragma unroll
      for (int i = 0; i < 16; ++i) {
        float4 vv = vr[i];
        o4[i].x = o4[i].x * corr + p * vv.x;
        o4[i].y = o4[i].y * corr + p * vv.y;
        o4[i].z = o4[i].z * corr + p * vv.z;
        o4[i].w = o4[i].w * corr + p * vv.w;
      }
      m = mn;
    }
    __syncthreads();
  }

  if (qi < NSEQ) {
    float inv = 1.f / l;
    float* op = &attn_out[(rowbase + qi) * DIM + h * DH];
    #pragma unroll
    for (int i = 0; i < 16; ++i) {
      float4 ov = o4[i];
      ov.x *= inv; ov.y *= inv; ov.z *= inv; ov.w *= inv;
      *(float4*)&op[i * 4] = ov;
    }
  }
}

// ---------------------------------------------------------------------------
// attn_map: softmax(q_row0 . K) averaged over heads, keys 1..1024, per batch.
// Grid = 8 blocks (one per b), 256 threads.
// ---------------------------------------------------------------------------
__global__ __launch_bounds__(256) void attn_map_kernel(
    const float* __restrict__ qkv, float* __restrict__ map) {
  const int b = blockIdx.x;
  const int tid = threadIdx.x;
  __shared__ float q0s[64];
  __shared__ float red[256];
  float acc[5] = {0.f, 0.f, 0.f, 0.f, 0.f};
  const size_t rowbase = (size_t)b * NSEQ;

  for (int h = 0; h < HEADS; ++h) {
    __syncthreads();
    if (tid < 64) q0s[tid] = qkv[rowbase * C3 + h * DH + tid];
    __syncthreads();
    float s[5];
    float lm = -INFINITY;
    #pragma unroll
    for (int sl = 0; sl < 5; ++sl) {
      int j = tid + sl * 256;
      s[sl] = -INFINITY;
      if (j < NSEQ) {
        const float* kp = &qkv[(rowbase + j) * C3 + DIM + h * DH];
        float d0 = 0.f;
        #pragma unroll
        for (int d = 0; d < 64; d += 4) {
          float4 kv = *(const float4*)&kp[d];
          d0 += q0s[d] * kv.x + q0s[d + 1] * kv.y + q0s[d + 2] * kv.z + q0s[d + 3] * kv.w;
        }
        s[sl] = d0;
        lm = fmaxf(lm, d0);
      }
    }
    red[tid] = lm; __syncthreads();
    for (int off = 128; off > 0; off >>= 1) {
      if (tid < off) red[tid] = fmaxf(red[tid], red[tid + off]);
      __syncthreads();
    }
    const float Mx = red[0]; __syncthreads();
    float p[5];
    float ls = 0.f;
    #pragma unroll
    for (int sl = 0; sl < 5; ++sl) {
      int j = tid + sl * 256;
      p[sl] = 0.f;
      if (j < NSEQ) { p[sl] = __expf(s[sl] - Mx); ls += p[sl]; }
    }
    red[tid] = ls; __syncthreads();
    for (int off = 128; off > 0; off >>= 1) {
      if (tid < off) red[tid] += red[tid + off];
      __syncthreads();
    }
    const float S = red[0]; __syncthreads();
    const float inv = 1.f / (S * (float)HEADS);
    #pragma unroll
    for (int sl = 0; sl < 5; ++sl) {
      int j = tid + sl * 256;
      if (j < NSEQ) acc[sl] += p[sl] * inv;
    }
  }
  #pragma unroll
  for (int sl = 0; sl < 5; ++sl) {
    int j = tid + sl * 256;
    if (j >= 1 && j < NSEQ) map[(size_t)b * (NSEQ - 1) + j - 1] = acc[sl];
  }
}

// ---------------------------------------------------------------------------
extern "C" void kernel_launch(void* const* d_in, const int* in_sizes, int n_in,
                              void* d_out, int out_size, void* d_ws, size_t ws_size,
                              hipStream_t stream) {
  const float* x     = (const float*)d_in[0];
  const float* Wqkv  = (const float*)d_in[1];
  const float* bqkv  = (const float*)d_in[2];
  const float* Wproj = (const float*)d_in[3];
  const float* bproj = (const float*)d_in[4];
  const float* gq    = (const float*)d_in[5];
  const float* betaq = (const float*)d_in[6];
  const float* gk    = (const float*)d_in[7];
  const float* betak = (const float*)d_in[8];

  float* qkv      = (float*)d_ws;                           // [8200, 2304]
  float* attn_out = qkv + (size_t)MROWS * C3;               // [8200, 768]
  float* out      = (float*)d_out;                          // [8200, 768]
  float* map      = out + (size_t)MROWS * DIM;              // [8, 1024]

  // 1) qkv = x @ Wqkv + bqkv
  {
    dim3 grid(C3 / 128, (MROWS + 127) / 128);
    sgemm_bias_kernel<<<grid, 256, 0, stream>>>(x, Wqkv, bqkv, qkv, MROWS, C3, DIM);
  }
  // 2) in-place LN on q,k (q scaled by 0.125)
  {
    int blocks = (MROWS * HEADS + 3) / 4;
    ln_qk_kernel<<<blocks, 256, 0, stream>>>(qkv, gq, betaq, gk, betak);
  }
  // 3) attention
  {
    dim3 grid((NSEQ + 63) / 64, BS * HEADS);
    attn_kernel<<<grid, 64, 0, stream>>>(qkv, attn_out);
  }
  // 4) attn_map
  attn_map_kernel<<<BS, 256, 0, stream>>>(qkv, map);
  // 5) out = attn_out @ Wproj + bproj
  {
    dim3 grid(DIM / 128, (MROWS + 127) / 128);
    sgemm_bias_kernel<<<grid, 256, 0, stream>>>(attn_out, Wproj, bproj, out, MROWS, DIM, DIM);
  }
}

// Round 2
// 2424.572 us; speedup vs baseline: 1.1502x; 1.1502x over previous
//
#include <hip/hip_runtime.h>
#include <hip/hip_bf16.h>
#include <math.h>

// Problem constants
#define BS   8
#define NSEQ 1025
#define DIM  768
#define C3   2304      // 3*DIM
#define HEADS 12
#define DH   64
#define MROWS (BS*NSEQ) // 8200

// log2(e) folded into Q during LN so softmax uses exp2
#define QSCALE (0.125f * 1.44269504088896340736f)

// ---------------------------------------------------------------------------
// Generic fp32 SGEMM with bias: C[M,N] = A[M,K] @ B[K,N] + bias[N]
// 128x128 block tile, BK=8, 256 threads, 8x8 per-thread microtile.
// ---------------------------------------------------------------------------
__global__ __launch_bounds__(256) void sgemm_bias_kernel(
    const float* __restrict__ A, const float* __restrict__ B,
    const float* __restrict__ bias, float* __restrict__ C,
    int M, int N, int K) {
  __shared__ float As[8][128];   // transposed A tile: As[k][m]
  __shared__ float Bs[8][128];
  const int tid = threadIdx.x;
  const int m0 = blockIdx.y * 128;
  const int n0 = blockIdx.x * 128;
  const int ty = tid >> 4;       // 0..15
  const int tx = tid & 15;       // 0..15
  const int arow = tid >> 1;           // 0..127
  const int ak   = (tid & 1) << 2;     // 0 or 4
  const int brow = tid >> 5;           // 0..7
  const int bcol = (tid & 31) << 2;    // 0..124
  const bool aval = (m0 + arow) < M;
  const float* Aptr = A + (size_t)(m0 + arow) * K + ak;
  const float* Bptr = B + (size_t)brow * N + n0 + bcol;

  float acc[8][8];
  #pragma unroll
  for (int i = 0; i < 8; ++i)
    #pragma unroll
    for (int j = 0; j < 8; ++j) acc[i][j] = 0.f;

  for (int k0 = 0; k0 < K; k0 += 8) {
    float4 av = aval ? *(const float4*)(Aptr + k0)
                     : make_float4(0.f, 0.f, 0.f, 0.f);
    float4 bv = *(const float4*)(Bptr + (size_t)k0 * N);
    As[ak + 0][arow] = av.x;
    As[ak + 1][arow] = av.y;
    As[ak + 2][arow] = av.z;
    As[ak + 3][arow] = av.w;
    *(float4*)&Bs[brow][bcol] = bv;
    __syncthreads();
    #pragma unroll
    for (int kk = 0; kk < 8; ++kk) {
      float4 a0 = *(const float4*)&As[kk][ty * 8];
      float4 a1 = *(const float4*)&As[kk][ty * 8 + 4];
      float4 b0 = *(const float4*)&Bs[kk][tx * 8];
      float4 b1 = *(const float4*)&Bs[kk][tx * 8 + 4];
      float a[8] = {a0.x, a0.y, a0.z, a0.w, a1.x, a1.y, a1.z, a1.w};
      float bb[8] = {b0.x, b0.y, b0.z, b0.w, b1.x, b1.y, b1.z, b1.w};
      #pragma unroll
      for (int i = 0; i < 8; ++i)
        #pragma unroll
        for (int j = 0; j < 8; ++j) acc[i][j] += a[i] * bb[j];
    }
    __syncthreads();
  }

  #pragma unroll
  for (int i = 0; i < 8; ++i) {
    int row = m0 + ty * 8 + i;
    if (row < M) {
      float* cp = &C[(size_t)row * N + n0 + tx * 8];
      const float* bp = &bias[n0 + tx * 8];
      #pragma unroll
      for (int j = 0; j < 8; ++j) cp[j] = acc[i][j] + bp[j];
    }
  }
}

// ---------------------------------------------------------------------------
// In-place LayerNorm on q and k portions of qkv[M, 2304].
// One wave per (row, head). Q additionally scaled by 0.125*log2(e) so the
// attention softmax can use exp2 throughout.
// ---------------------------------------------------------------------------
__global__ __launch_bounds__(256) void ln_qk_kernel(
    float* __restrict__ qkv,
    const float* __restrict__ gq, const float* __restrict__ bq,
    const float* __restrict__ gk, const float* __restrict__ bk) {
  const int task = blockIdx.x * 4 + (threadIdx.x >> 6);
  const int lane = threadIdx.x & 63;
  const int TASKS = MROWS * HEADS;
  if (task >= TASKS) return;
  const int row = task / HEADS;
  const int h = task - row * HEADS;
  const size_t base = (size_t)row * C3 + h * DH;
  float xq = qkv[base + lane];
  float xk = qkv[base + DIM + lane];
  float sq = xq, s2q = xq * xq, sk = xk, s2k = xk * xk;
  #pragma unroll
  for (int off = 32; off; off >>= 1) {
    sq  += __shfl_xor(sq,  off);
    s2q += __shfl_xor(s2q, off);
    sk  += __shfl_xor(sk,  off);
    s2k += __shfl_xor(s2k, off);
  }
  const float inv64 = 1.f / 64.f;
  float mq = sq * inv64, vq = s2q * inv64 - mq * mq;
  float mk = sk * inv64, vk = s2k * inv64 - mk * mk;
  float rq = rsqrtf(vq + 1e-5f), rk = rsqrtf(vk + 1e-5f);
  qkv[base + lane]       = ((xq - mq) * rq * gq[lane] + bq[lane]) * QSCALE;
  qkv[base + DIM + lane] =  (xk - mk) * rk * gk[lane] + bk[lane];
}

// ---------------------------------------------------------------------------
// Flash-style attention v2.
// Block = 128 threads (2 waves), each thread owns one query row; both waves
// share the 64-key K/V LDS tile. Scores computed 8 keys at a time for ILP;
// deferred rescale: O is only rescaled when the chunk max beats the running
// max. Q carries the 0.125*log2e scale -> exp2f everywhere.
// NSEQ = 16*64 + 1: 16 full unconditional tiles + 1 tail key from global.
// Output layout: attn_out[row*768 + h*64 + d]  (row = b*NSEQ + n)
// ---------------------------------------------------------------------------
__global__ __launch_bounds__(128) void attn_kernel(
    const float* __restrict__ qkv, float* __restrict__ attn_out) {
  const int bh = blockIdx.y;           // 0..95
  const int b = bh / HEADS, h = bh % HEADS;
  const int q0 = blockIdx.x * 128;
  const int tid = threadIdx.x;
  __shared__ float kt[64][DH];
  __shared__ float vt[64][DH];
  const size_t rowbase = (size_t)b * NSEQ;

  const int qi = q0 + tid;
  float4 q4[16];
  if (qi < NSEQ) {
    const float* qp = &qkv[(rowbase + qi) * C3 + h * DH];
    #pragma unroll
    for (int i = 0; i < 16; ++i) q4[i] = *(const float4*)&qp[i * 4];
  } else {
    #pragma unroll
    for (int i = 0; i < 16; ++i) q4[i] = make_float4(0.f, 0.f, 0.f, 0.f);
  }

  float4 o4[16];
  #pragma unroll
  for (int i = 0; i < 16; ++i) o4[i] = make_float4(0.f, 0.f, 0.f, 0.f);
  float m = -INFINITY, l = 0.f;

  for (int k0 = 0; k0 < 1024; k0 += 64) {
    __syncthreads();   // protect previous tile's readers
    #pragma unroll
    for (int i = 0; i < 8; ++i) {
      int f = i * 128 + tid;          // 0..1023
      int row = f >> 4;               // 0..63
      int c = (f & 15) << 2;          // 0..60
      const float* kp = &qkv[(rowbase + k0 + row) * C3 + DIM + h * DH + c];
      *(float4*)&kt[row][c] = *(const float4*)kp;
      *(float4*)&vt[row][c] = *(const float4*)(kp + DIM);
    }
    __syncthreads();

    #pragma unroll 1
    for (int cc = 0; cc < 8; ++cc) {
      float s[8];
      #pragma unroll
      for (int j = 0; j < 8; ++j) {
        const float4* kr = (const float4*)&kt[cc * 8 + j][0];
        float sx = 0.f, sy = 0.f, sz = 0.f, sw = 0.f;
        #pragma unroll
        for (int i = 0; i < 16; ++i) {
          float4 kv = kr[i];
          float4 qv = q4[i];
          sx += qv.x * kv.x; sy += qv.y * kv.y;
          sz += qv.z * kv.z; sw += qv.w * kv.w;
        }
        s[j] = (sx + sy) + (sz + sw);
      }
      float cmax = s[0];
      #pragma unroll
      for (int j = 1; j < 8; ++j) cmax = fmaxf(cmax, s[j]);
      if (cmax > m) {
        float corr = exp2f(m - cmax);   // m=-inf first chunk -> 0
        l *= corr;
        #pragma unroll
        for (int i = 0; i < 16; ++i) {
          o4[i].x *= corr; o4[i].y *= corr; o4[i].z *= corr; o4[i].w *= corr;
        }
        m = cmax;
      }
      #pragma unroll
      for (int j = 0; j < 8; ++j) {
        float p = exp2f(s[j] - m);
        l += p;
        const float4* vr = (const float4*)&vt[cc * 8 + j][0];
        #pragma unroll
        for (int i = 0; i < 16; ++i) {
          float4 vv = vr[i];
          o4[i].x += p * vv.x; o4[i].y += p * vv.y;
          o4[i].z += p * vv.z; o4[i].w += p * vv.w;
        }
      }
    }
  }

  // tail key 1024 (broadcast reads via cache)
  {
    const float* kp = &qkv[(rowbase + 1024) * C3 + DIM + h * DH];
    float sx = 0.f, sy = 0.f, sz = 0.f, sw = 0.f;
    #pragma unroll
    for (int i = 0; i < 16; ++i) {
      float4 kv = *(const float4*)&kp[i * 4];
      float4 qv = q4[i];
      sx += qv.x * kv.x; sy += qv.y * kv.y;
      sz += qv.z * kv.z; sw += qv.w * kv.w;
    }
    float s = (sx + sy) + (sz + sw);
    if (s > m) {
      float corr = exp2f(m - s);
      l *= corr;
      #pragma unroll
      for (int i = 0; i < 16; ++i) {
        o4[i].x *= corr; o4[i].y *= corr; o4[i].z *= corr; o4[i].w *= corr;
      }
      m = s;
    }
    float p = exp2f(s - m);
    l += p;
    const float* vp = kp + DIM;
    #pragma unroll
    for (int i = 0; i < 16; ++i) {
      float4 vv = *(const float4*)&vp[i * 4];
      o4[i].x += p * vv.x; o4[i].y += p * vv.y;
      o4[i].z += p * vv.z; o4[i].w += p * vv.w;
    }
  }

  if (qi < NSEQ) {
    float inv = 1.f / l;
    float* op = &attn_out[(rowbase + qi) * DIM + h * DH];
    #pragma unroll
    for (int i = 0; i < 16; ++i) {
      float4 ov = o4[i];
      ov.x *= inv; ov.y *= inv; ov.z *= inv; ov.w *= inv;
      *(float4*)&op[i * 4] = ov;
    }
  }
}

// ---------------------------------------------------------------------------
// attn_map: softmax(q_row0 . K) averaged over heads, keys 1..1024, per batch.
// Scores are already in log2 domain (Q carries 0.125*log2e).
// Grid = 8 blocks (one per b), 256 threads.
// ---------------------------------------------------------------------------
__global__ __launch_bounds__(256) void attn_map_kernel(
    const float* __restrict__ qkv, float* __restrict__ map) {
  const int b = blockIdx.x;
  const int tid = threadIdx.x;
  __shared__ float q0s[64];
  __shared__ float red[256];
  float acc[5] = {0.f, 0.f, 0.f, 0.f, 0.f};
  const size_t rowbase = (size_t)b * NSEQ;

  for (int h = 0; h < HEADS; ++h) {
    __syncthreads();
    if (tid < 64) q0s[tid] = qkv[rowbase * C3 + h * DH + tid];
    __syncthreads();
    float s[5];
    float lm = -INFINITY;
    #pragma unroll
    for (int sl = 0; sl < 5; ++sl) {
      int j = tid + sl * 256;
      s[sl] = -INFINITY;
      if (j < NSEQ) {
        const float* kp = &qkv[(rowbase + j) * C3 + DIM + h * DH];
        float d0 = 0.f;
        #pragma unroll
        for (int d = 0; d < 64; d += 4) {
          float4 kv = *(const float4*)&kp[d];
          d0 += q0s[d] * kv.x + q0s[d + 1] * kv.y + q0s[d + 2] * kv.z + q0s[d + 3] * kv.w;
        }
        s[sl] = d0;
        lm = fmaxf(lm, d0);
      }
    }
    red[tid] = lm; __syncthreads();
    for (int off = 128; off > 0; off >>= 1) {
      if (tid < off) red[tid] = fmaxf(red[tid], red[tid + off]);
      __syncthreads();
    }
    const float Mx = red[0]; __syncthreads();
    float p[5];
    float ls = 0.f;
    #pragma unroll
    for (int sl = 0; sl < 5; ++sl) {
      int j = tid + sl * 256;
      p[sl] = 0.f;
      if (j < NSEQ) { p[sl] = exp2f(s[sl] - Mx); ls += p[sl]; }
    }
    red[tid] = ls; __syncthreads();
    for (int off = 128; off > 0; off >>= 1) {
      if (tid < off) red[tid] += red[tid + off];
      __syncthreads();
    }
    const float S = red[0]; __syncthreads();
    const float inv = 1.f / (S * (float)HEADS);
    #pragma unroll
    for (int sl = 0; sl < 5; ++sl) {
      int j = tid + sl * 256;
      if (j < NSEQ) acc[sl] += p[sl] * inv;
    }
  }
  #pragma unroll
  for (int sl = 0; sl < 5; ++sl) {
    int j = tid + sl * 256;
    if (j >= 1 && j < NSEQ) map[(size_t)b * (NSEQ - 1) + j - 1] = acc[sl];
  }
}

// ---------------------------------------------------------------------------
extern "C" void kernel_launch(void* const* d_in, const int* in_sizes, int n_in,
                              void* d_out, int out_size, void* d_ws, size_t ws_size,
                              hipStream_t stream) {
  const float* x     = (const float*)d_in[0];
  const float* Wqkv  = (const float*)d_in[1];
  const float* bqkv  = (const float*)d_in[2];
  const float* Wproj = (const float*)d_in[3];
  const float* bproj = (const float*)d_in[4];
  const float* gq    = (const float*)d_in[5];
  const float* betaq = (const float*)d_in[6];
  const float* gk    = (const float*)d_in[7];
  const float* betak = (const float*)d_in[8];

  float* qkv      = (float*)d_ws;                           // [8200, 2304]
  float* attn_out = qkv + (size_t)MROWS * C3;               // [8200, 768]
  float* out      = (float*)d_out;                          // [8200, 768]
  float* map      = out + (size_t)MROWS * DIM;              // [8, 1024]

  // 1) qkv = x @ Wqkv + bqkv
  {
    dim3 grid(C3 / 128, (MROWS + 127) / 128);
    sgemm_bias_kernel<<<grid, 256, 0, stream>>>(x, Wqkv, bqkv, qkv, MROWS, C3, DIM);
  }
  // 2) in-place LN on q,k (q scaled by 0.125*log2e)
  {
    int blocks = (MROWS * HEADS + 3) / 4;
    ln_qk_kernel<<<blocks, 256, 0, stream>>>(qkv, gq, betaq, gk, betak);
  }
  // 3) attention
  {
    dim3 grid((NSEQ + 127) / 128, BS * HEADS);
    attn_kernel<<<grid, 128, 0, stream>>>(qkv, attn_out);
  }
  // 4) attn_map
  attn_map_kernel<<<BS, 256, 0, stream>>>(qkv, map);
  // 5) out = attn_out @ Wproj + bproj
  {
    dim3 grid(DIM / 128, (MROWS + 127) / 128);
    sgemm_bias_kernel<<<grid, 256, 0, stream>>>(attn_out, Wproj, bproj, out, MROWS, DIM, DIM);
  }
}

// Round 3
// 928.857 us; speedup vs baseline: 3.0023x; 2.6103x over previous
//
#include <hip/hip_runtime.h>
#include <hip/hip_bf16.h>
#include <math.h>

// Problem constants
#define BS   8
#define NSEQ 1025
#define DIM  768
#define C3   2304      // 3*DIM
#define HEADS 12
#define DH   64
#define MROWS (BS*NSEQ) // 8200
#define NKPAD 1088      // 17*64, padded sequence length for MFMA tiles
#define NBH   (BS*HEADS)

// log2(e) folded into Q during LN so softmax uses exp2
#define QSCALE (0.125f * 1.44269504088896340736f)
#define SBOUND 10.0f    // fixed softmax offset (log2 domain); ratios unchanged

typedef __attribute__((ext_vector_type(8))) short bf16x8;
typedef __attribute__((ext_vector_type(4))) float f32x4;

static __device__ __forceinline__ unsigned short f2bf(float f) {
  unsigned int u = __float_as_uint(f);
  unsigned int r = (u + 0x7fffu + ((u >> 16) & 1u)) >> 16;
  return (unsigned short)r;
}

// ---------------------------------------------------------------------------
// Generic fp32 SGEMM with bias: C[M,N] = A[M,K] @ B[K,N] + bias[N]
// ---------------------------------------------------------------------------
__global__ __launch_bounds__(256) void sgemm_bias_kernel(
    const float* __restrict__ A, const float* __restrict__ B,
    const float* __restrict__ bias, float* __restrict__ C,
    int M, int N, int K) {
  __shared__ float As[8][128];   // transposed A tile: As[k][m]
  __shared__ float Bs[8][128];
  const int tid = threadIdx.x;
  const int m0 = blockIdx.y * 128;
  const int n0 = blockIdx.x * 128;
  const int ty = tid >> 4;       // 0..15
  const int tx = tid & 15;       // 0..15
  const int arow = tid >> 1;           // 0..127
  const int ak   = (tid & 1) << 2;     // 0 or 4
  const int brow = tid >> 5;           // 0..7
  const int bcol = (tid & 31) << 2;    // 0..124
  const bool aval = (m0 + arow) < M;
  const float* Aptr = A + (size_t)(m0 + arow) * K + ak;
  const float* Bptr = B + (size_t)brow * N + n0 + bcol;

  float acc[8][8];
  #pragma unroll
  for (int i = 0; i < 8; ++i)
    #pragma unroll
    for (int j = 0; j < 8; ++j) acc[i][j] = 0.f;

  for (int k0 = 0; k0 < K; k0 += 8) {
    float4 av = aval ? *(const float4*)(Aptr + k0)
                     : make_float4(0.f, 0.f, 0.f, 0.f);
    float4 bv = *(const float4*)(Bptr + (size_t)k0 * N);
    As[ak + 0][arow] = av.x;
    As[ak + 1][arow] = av.y;
    As[ak + 2][arow] = av.z;
    As[ak + 3][arow] = av.w;
    *(float4*)&Bs[brow][bcol] = bv;
    __syncthreads();
    #pragma unroll
    for (int kk = 0; kk < 8; ++kk) {
      float4 a0 = *(const float4*)&As[kk][ty * 8];
      float4 a1 = *(const float4*)&As[kk][ty * 8 + 4];
      float4 b0 = *(const float4*)&Bs[kk][tx * 8];
      float4 b1 = *(const float4*)&Bs[kk][tx * 8 + 4];
      float a[8] = {a0.x, a0.y, a0.z, a0.w, a1.x, a1.y, a1.z, a1.w};
      float bb[8] = {b0.x, b0.y, b0.z, b0.w, b1.x, b1.y, b1.z, b1.w};
      #pragma unroll
      for (int i = 0; i < 8; ++i)
        #pragma unroll
        for (int j = 0; j < 8; ++j) acc[i][j] += a[i] * bb[j];
    }
    __syncthreads();
  }

  #pragma unroll
  for (int i = 0; i < 8; ++i) {
    int row = m0 + ty * 8 + i;
    if (row < M) {
      float* cp = &C[(size_t)row * N + n0 + tx * 8];
      const float* bp = &bias[n0 + tx * 8];
      #pragma unroll
      for (int j = 0; j < 8; ++j) cp[j] = acc[i][j] + bp[j];
    }
  }
}

// ---------------------------------------------------------------------------
// In-place LayerNorm on q and k of qkv[M, 2304]; Q scaled by 0.125*log2e.
// Also writes bf16 copies to qb/kb in [bh][n][64] layout (n real rows only;
// pad rows are zeroed by vt_convert_kernel).
// ---------------------------------------------------------------------------
__global__ __launch_bounds__(256) void ln_qk_kernel(
    float* __restrict__ qkv,
    const float* __restrict__ gq, const float* __restrict__ bq,
    const float* __restrict__ gk, const float* __restrict__ bk,
    short* __restrict__ qb, short* __restrict__ kb) {
  const int task = blockIdx.x * 4 + (threadIdx.x >> 6);
  const int lane = threadIdx.x & 63;
  const int TASKS = MROWS * HEADS;
  if (task >= TASKS) return;
  const int row = task / HEADS;
  const int h = task - row * HEADS;
  const size_t base = (size_t)row * C3 + h * DH;
  float xq = qkv[base + lane];
  float xk = qkv[base + DIM + lane];
  float sq = xq, s2q = xq * xq, sk = xk, s2k = xk * xk;
  #pragma unroll
  for (int off = 32; off; off >>= 1) {
    sq  += __shfl_xor(sq,  off);
    s2q += __shfl_xor(s2q, off);
    sk  += __shfl_xor(sk,  off);
    s2k += __shfl_xor(s2k, off);
  }
  const float inv64 = 1.f / 64.f;
  float mq = sq * inv64, vq = s2q * inv64 - mq * mq;
  float mk = sk * inv64, vk = s2k * inv64 - mk * mk;
  float rq = rsqrtf(vq + 1e-5f), rk = rsqrtf(vk + 1e-5f);
  float qn = ((xq - mq) * rq * gq[lane] + bq[lane]) * QSCALE;
  float kn =  (xk - mk) * rk * gk[lane] + bk[lane];
  qkv[base + lane]       = qn;
  qkv[base + DIM + lane] = kn;
  const int b = row / NSEQ;
  const int n = row - b * NSEQ;
  const size_t o = ((size_t)(b * HEADS + h) * NKPAD + n) * DH + lane;
  qb[o] = (short)f2bf(qn);
  kb[o] = (short)f2bf(kn);
}

// ---------------------------------------------------------------------------
// V convert+transpose: qkv v-part fp32 [row][2*DIM + h*64 + d] ->
// vt bf16 [bh][d][NKPAD] (keys padded with zeros).
// Also zero-fills qb/kb pad rows (1025..1087) on the last key tile.
// Grid: (17, 96), 256 threads.
// ---------------------------------------------------------------------------
__global__ __launch_bounds__(256) void vt_convert_kernel(
    const float* __restrict__ qkv, short* __restrict__ vt,
    short* __restrict__ qb, short* __restrict__ kb) {
  const int kt = blockIdx.x;     // key tile 0..16
  const int bh = blockIdx.y;     // 0..95
  const int b = bh / HEADS, h = bh - (bh / HEADS) * HEADS;
  const int t = threadIdx.x;
  __shared__ float tile[64][65];
  const int r = t >> 2;          // 0..63
  const int c0 = (t & 3) * 16;   // 0,16,32,48
  const int grow = kt * 64 + r;  // key index 0..1087

  const float* src = qkv + (size_t)(b * NSEQ + grow) * C3 + 2 * DIM + h * DH + c0;
  #pragma unroll
  for (int j = 0; j < 16; j += 4) {
    float4 v = (grow < NSEQ) ? *(const float4*)(src + j)
                             : make_float4(0.f, 0.f, 0.f, 0.f);
    tile[r][c0 + j]     = v.x;
    tile[r][c0 + j + 1] = v.y;
    tile[r][c0 + j + 2] = v.z;
    tile[r][c0 + j + 3] = v.w;
  }
  __syncthreads();
  // write transposed row d=r, keys kt*64 + c0 .. +15
  bf16x8 w0, w1;
  #pragma unroll
  for (int j = 0; j < 8; ++j) {
    w0[j] = (short)f2bf(tile[c0 + j][r]);
    w1[j] = (short)f2bf(tile[c0 + 8 + j][r]);
  }
  short* dst = vt + ((size_t)bh * DH + r) * NKPAD + kt * 64 + c0;
  *(bf16x8*)dst = w0;
  *(bf16x8*)(dst + 8) = w1;

  if (kt == 16 && grow >= NSEQ) {   // zero qb/kb pad rows
    const size_t o = ((size_t)bh * NKPAD + grow) * DH + c0;
    #pragma unroll
    for (int j = 0; j < 16; ++j) { qb[o + j] = 0; kb[o + j] = 0; }
  }
}

// ---------------------------------------------------------------------------
// MFMA bf16 flash attention (fixed-offset softmax).
// Block = 256 threads (4 waves); wave owns 16 query rows. 17 key tiles of 64.
// Fragments read directly from global (K/V are L2-resident per (b,h)).
// P transposed to A-fragment layout via a per-wave LDS buffer.
// Grid: (17, 96).
// ---------------------------------------------------------------------------
__global__ __launch_bounds__(256) void attn_mfma_kernel(
    const short* __restrict__ qb, const short* __restrict__ kb,
    const short* __restrict__ vt, float* __restrict__ attn_out) {
  const int bh = blockIdx.y;
  const int b = bh / HEADS, h = bh - (bh / HEADS) * HEADS;
  const int wid = threadIdx.x >> 6;
  const int lane = threadIdx.x & 63;
  const int lo = lane & 15, hi = lane >> 4;
  const int q0 = blockIdx.x * 64 + wid * 16;

  __shared__ short Pb[4][16][72];   // per-wave P buffer, stride 72 (bank-safe)

  const short* kbase = kb + (size_t)bh * NKPAD * DH;
  const short* vbase = vt + (size_t)bh * DH * NKPAD;

  // Q A-fragments: rows q0+lo, k-chunks [0,32) and [32,64)
  bf16x8 aq0, aq1;
  {
    const short* qp = qb + (size_t)bh * NKPAD * DH + (size_t)(q0 + lo) * DH + hi * 8;
    aq0 = *(const bf16x8*)qp;
    aq1 = *(const bf16x8*)(qp + 32);
  }

  f32x4 o[4];
  float lsum[4];
  #pragma unroll
  for (int nt = 0; nt < 4; ++nt) {
    o[nt][0] = o[nt][1] = o[nt][2] = o[nt][3] = 0.f;
    lsum[nt] = 0.f;
  }

  for (int kt = 0; kt < 17; ++kt) {
    // S[16q x 64k] = Q . K^T
    f32x4 s[4];
    #pragma unroll
    for (int nt = 0; nt < 4; ++nt) s[nt][0] = s[nt][1] = s[nt][2] = s[nt][3] = 0.f;
    const short* kpt = kbase + (size_t)kt * 64 * DH;
    #pragma unroll
    for (int nt = 0; nt < 4; ++nt) {
      const short* kr = kpt + (size_t)(nt * 16 + lo) * DH + hi * 8;
      bf16x8 b0 = *(const bf16x8*)kr;
      bf16x8 b1 = *(const bf16x8*)(kr + 32);
      s[nt] = __builtin_amdgcn_mfma_f32_16x16x32_bf16(aq0, b0, s[nt], 0, 0, 0);
      s[nt] = __builtin_amdgcn_mfma_f32_16x16x32_bf16(aq1, b1, s[nt], 0, 0, 0);
    }
    if (kt == 16) {   // mask keys >= 1025 (only key 1024 is real here)
      #pragma unroll
      for (int nt = 0; nt < 4; ++nt) {
        if (1024 + nt * 16 + lo >= NSEQ) {
          s[nt][0] = s[nt][1] = s[nt][2] = s[nt][3] = -1e30f;
        }
      }
    }
    // p = exp2(s - SBOUND); accumulate denom; stage bf16 P for transpose
    #pragma unroll
    for (int nt = 0; nt < 4; ++nt) {
      #pragma unroll
      for (int r = 0; r < 4; ++r) {
        float p = exp2f(s[nt][r] - SBOUND);
        lsum[r] += p;
        Pb[wid][4 * hi + r][nt * 16 + lo] = (short)f2bf(p);
      }
    }
    // O += P . V   (A = P re-read in A-layout, B = V^T rows)
    #pragma unroll
    for (int ks = 0; ks < 2; ++ks) {
      bf16x8 pa = *(const bf16x8*)&Pb[wid][lo][ks * 32 + hi * 8];
      #pragma unroll
      for (int nt = 0; nt < 4; ++nt) {
        const short* vr = vbase + (size_t)(nt * 16 + lo) * NKPAD
                        + kt * 64 + ks * 32 + hi * 8;
        bf16x8 bv = *(const bf16x8*)vr;
        o[nt] = __builtin_amdgcn_mfma_f32_16x16x32_bf16(pa, bv, o[nt], 0, 0, 0);
      }
    }
  }

  // finalize denominator: sum over the 16 key-columns held across lo lanes
  #pragma unroll
  for (int r = 0; r < 4; ++r) {
    float v = lsum[r];
    v += __shfl_xor(v, 1);
    v += __shfl_xor(v, 2);
    v += __shfl_xor(v, 4);
    v += __shfl_xor(v, 8);
    lsum[r] = v;
  }
  // store O rows q0 + 4*hi + r, col d = nt*16 + lo
  #pragma unroll
  for (int r = 0; r < 4; ++r) {
    const int qrow = q0 + 4 * hi + r;
    if (qrow < NSEQ) {
      const float inv = 1.f / lsum[r];
      float* op = attn_out + (size_t)(b * NSEQ + qrow) * DIM + h * DH + lo;
      #pragma unroll
      for (int nt = 0; nt < 4; ++nt) op[nt * 16] = o[nt][r] * inv;
    }
  }
}

// ---------------------------------------------------------------------------
// attn_map: softmax(q_row0 . K) averaged over heads, keys 1..1024, per batch.
// Reads the exact fp32 LN'd values (log2 domain). Grid = 8, 256 threads.
// ---------------------------------------------------------------------------
__global__ __launch_bounds__(256) void attn_map_kernel(
    const float* __restrict__ qkv, float* __restrict__ map) {
  const int b = blockIdx.x;
  const int tid = threadIdx.x;
  __shared__ float q0s[64];
  __shared__ float red[256];
  float acc[5] = {0.f, 0.f, 0.f, 0.f, 0.f};
  const size_t rowbase = (size_t)b * NSEQ;

  for (int h = 0; h < HEADS; ++h) {
    __syncthreads();
    if (tid < 64) q0s[tid] = qkv[rowbase * C3 + h * DH + tid];
    __syncthreads();
    float s[5];
    float lm = -INFINITY;
    #pragma unroll
    for (int sl = 0; sl < 5; ++sl) {
      int j = tid + sl * 256;
      s[sl] = -INFINITY;
      if (j < NSEQ) {
        const float* kp = &qkv[(rowbase + j) * C3 + DIM + h * DH];
        float d0 = 0.f;
        #pragma unroll
        for (int d = 0; d < 64; d += 4) {
          float4 kv = *(const float4*)&kp[d];
          d0 += q0s[d] * kv.x + q0s[d + 1] * kv.y + q0s[d + 2] * kv.z + q0s[d + 3] * kv.w;
        }
        s[sl] = d0;
        lm = fmaxf(lm, d0);
      }
    }
    red[tid] = lm; __syncthreads();
    for (int off = 128; off > 0; off >>= 1) {
      if (tid < off) red[tid] = fmaxf(red[tid], red[tid + off]);
      __syncthreads();
    }
    const float Mx = red[0]; __syncthreads();
    float p[5];
    float ls = 0.f;
    #pragma unroll
    for (int sl = 0; sl < 5; ++sl) {
      int j = tid + sl * 256;
      p[sl] = 0.f;
      if (j < NSEQ) { p[sl] = exp2f(s[sl] - Mx); ls += p[sl]; }
    }
    red[tid] = ls; __syncthreads();
    for (int off = 128; off > 0; off >>= 1) {
      if (tid < off) red[tid] += red[tid + off];
      __syncthreads();
    }
    const float S = red[0]; __syncthreads();
    const float inv = 1.f / (S * (float)HEADS);
    #pragma unroll
    for (int sl = 0; sl < 5; ++sl) {
      int j = tid + sl * 256;
      if (j < NSEQ) acc[sl] += p[sl] * inv;
    }
  }
  #pragma unroll
  for (int sl = 0; sl < 5; ++sl) {
    int j = tid + sl * 256;
    if (j >= 1 && j < NSEQ) map[(size_t)b * (NSEQ - 1) + j - 1] = acc[sl];
  }
}

// ---------------------------------------------------------------------------
extern "C" void kernel_launch(void* const* d_in, const int* in_sizes, int n_in,
                              void* d_out, int out_size, void* d_ws, size_t ws_size,
                              hipStream_t stream) {
  const float* x     = (const float*)d_in[0];
  const float* Wqkv  = (const float*)d_in[1];
  const float* bqkv  = (const float*)d_in[2];
  const float* Wproj = (const float*)d_in[3];
  const float* bproj = (const float*)d_in[4];
  const float* gq    = (const float*)d_in[5];
  const float* betaq = (const float*)d_in[6];
  const float* gk    = (const float*)d_in[7];
  const float* betak = (const float*)d_in[8];

  float* qkv      = (float*)d_ws;                           // [8200, 2304] f32
  float* attn_out = qkv + (size_t)MROWS * C3;               // [8200, 768]  f32
  short* qb = (short*)(attn_out + (size_t)MROWS * DIM);     // [96,1088,64] bf16
  short* kb = qb + (size_t)NBH * NKPAD * DH;                // [96,1088,64] bf16
  short* vt = kb + (size_t)NBH * NKPAD * DH;                // [96,64,1088] bf16
  float* out      = (float*)d_out;                          // [8200, 768]
  float* map      = out + (size_t)MROWS * DIM;              // [8, 1024]

  // 1) qkv = x @ Wqkv + bqkv
  {
    dim3 grid(C3 / 128, (MROWS + 127) / 128);
    sgemm_bias_kernel<<<grid, 256, 0, stream>>>(x, Wqkv, bqkv, qkv, MROWS, C3, DIM);
  }
  // 2) LN on q,k (fp32 in-place + bf16 qb/kb)
  {
    int blocks = (MROWS * HEADS + 3) / 4;
    ln_qk_kernel<<<blocks, 256, 0, stream>>>(qkv, gq, betaq, gk, betak, qb, kb);
  }
  // 3) V transpose/convert + pad zeroing
  {
    dim3 grid(17, NBH);
    vt_convert_kernel<<<grid, 256, 0, stream>>>(qkv, vt, qb, kb);
  }
  // 4) MFMA attention
  {
    dim3 grid(17, NBH);
    attn_mfma_kernel<<<grid, 256, 0, stream>>>(qb, kb, vt, attn_out);
  }
  // 5) attn_map (exact fp32 path)
  attn_map_kernel<<<BS, 256, 0, stream>>>(qkv, map);
  // 6) out = attn_out @ Wproj + bproj
  {
    dim3 grid(DIM / 128, (MROWS + 127) / 128);
    sgemm_bias_kernel<<<grid, 256, 0, stream>>>(attn_out, Wproj, bproj, out, MROWS, DIM, DIM);
  }
}

// Round 4
// 510.387 us; speedup vs baseline: 5.4640x; 1.8199x over previous
//
#include <hip/hip_runtime.h>
#include <hip/hip_bf16.h>
#include <math.h>

// Problem constants
#define BS   8
#define NSEQ 1025
#define DIM  768
#define C3   2304      // 3*DIM
#define HEADS 12
#define DH   64
#define MROWS (BS*NSEQ) // 8200
#define MPAD  8320      // 65*128, padded M for GEMM tiles
#define NKPAD 1088      // 17*64, padded sequence length for MFMA tiles
#define NBH   (BS*HEADS)

// log2(e) folded into Q during LN so softmax uses exp2
#define QSCALE (0.125f * 1.44269504088896340736f)
#define SBOUND 10.0f    // fixed softmax offset (log2 domain); ratios unchanged

typedef __attribute__((ext_vector_type(8))) short bf16x8;
typedef __attribute__((ext_vector_type(4))) float f32x4;

static __device__ __forceinline__ unsigned short f2bf(float f) {
  unsigned int u = __float_as_uint(f);
  unsigned int r = (u + 0x7fffu + ((u >> 16) & 1u)) >> 16;
  return (unsigned short)r;
}

static __device__ __forceinline__ void gload16(const short* g, short* l) {
  __builtin_amdgcn_global_load_lds(
      (const __attribute__((address_space(1))) unsigned int*)g,
      (__attribute__((address_space(3))) unsigned int*)l, 16, 0, 0);
}

// ---------------------------------------------------------------------------
// x fp32 [MROWS][DIM] -> xb bf16 [MPAD][DIM], pad rows zeroed.
// 8 elements per thread.
// ---------------------------------------------------------------------------
__global__ __launch_bounds__(256) void convert_x_kernel(
    const float* __restrict__ x, short* __restrict__ xb) {
  const size_t i = ((size_t)blockIdx.x * 256 + threadIdx.x) * 8;
  const size_t row = i / DIM;
  bf16x8 w;
  if (row < MROWS) {
    float4 v0 = *(const float4*)&x[i];
    float4 v1 = *(const float4*)&x[i + 4];
    w[0] = (short)f2bf(v0.x); w[1] = (short)f2bf(v0.y);
    w[2] = (short)f2bf(v0.z); w[3] = (short)f2bf(v0.w);
    w[4] = (short)f2bf(v1.x); w[5] = (short)f2bf(v1.y);
    w[6] = (short)f2bf(v1.z); w[7] = (short)f2bf(v1.w);
  } else {
    #pragma unroll
    for (int j = 0; j < 8; ++j) w[j] = 0;
  }
  *(bf16x8*)&xb[i] = w;
}

// ---------------------------------------------------------------------------
// W fp32 [K][N] -> Wt bf16 [N][K] (transpose + convert). Grid (N/64, K/64).
// ---------------------------------------------------------------------------
__global__ __launch_bounds__(256) void wtrans_kernel(
    const float* __restrict__ W, short* __restrict__ Wt, int K, int N) {
  const int n0 = blockIdx.x * 64, k0 = blockIdx.y * 64;
  __shared__ float tile[64][65];
  const int r = threadIdx.x >> 2;        // 0..63
  const int c0 = (threadIdx.x & 3) * 16; // 0,16,32,48
  const float* src = W + (size_t)(k0 + r) * N + n0 + c0;
  #pragma unroll
  for (int j = 0; j < 16; j += 4) {
    float4 v = *(const float4*)(src + j);
    tile[r][c0 + j]     = v.x;
    tile[r][c0 + j + 1] = v.y;
    tile[r][c0 + j + 2] = v.z;
    tile[r][c0 + j + 3] = v.w;
  }
  __syncthreads();
  bf16x8 w0, w1;
  #pragma unroll
  for (int j = 0; j < 8; ++j) {
    w0[j] = (short)f2bf(tile[c0 + j][r]);
    w1[j] = (short)f2bf(tile[c0 + 8 + j][r]);
  }
  short* dst = Wt + (size_t)(n0 + r) * K + k0 + c0;
  *(bf16x8*)dst = w0;
  *(bf16x8*)(dst + 8) = w1;
}

// ---------------------------------------------------------------------------
// bf16 MFMA GEMM: C[M,N] f32 = A[Mp,K]bf16 . Bt[N,K]bf16^T + bias[N].
// 128x128 tile, BK=64, 4 waves (2x2), global_load_lds staging (m97 structure).
// Requires M-tiles padded in A (rows >= M readable), N%128==0, K%64==0.
// ---------------------------------------------------------------------------
__global__ __launch_bounds__(256) void gemm_bf16_kernel(
    const short* __restrict__ A, const short* __restrict__ Bt,
    const float* __restrict__ bias, float* __restrict__ C,
    int M, int N, int K) {
  __shared__ short As[128 * 64];
  __shared__ short Bs[128 * 64];
  const int tid = threadIdx.x;
  const int wid = tid >> 6, lane = tid & 63;
  const int lo = lane & 15, hi = lane >> 4;
  const int wr = wid >> 1, wc = wid & 1;
  const int m0 = blockIdx.y * 128, n0 = blockIdx.x * 128;
  const int rl = lane >> 3;            // 0..7
  const int cb = (lane & 7) * 8;       // bf16 col offset within 64

  f32x4 acc[4][4];
  #pragma unroll
  for (int m = 0; m < 4; ++m)
    #pragma unroll
    for (int n = 0; n < 4; ++n)
      acc[m][n][0] = acc[m][n][1] = acc[m][n][2] = acc[m][n][3] = 0.f;

  const short* Abase = A + (size_t)(m0 + wid * 32 + rl) * K + cb;
  const short* Bbase = Bt + (size_t)(n0 + wid * 32 + rl) * K + cb;

  for (int k0 = 0; k0 < K; k0 += 64) {
    #pragma unroll
    for (int i = 0; i < 4; ++i) {
      gload16(Abase + (size_t)(i * 8) * K + k0, &As[(wid * 32 + i * 8) * 64]);
      gload16(Bbase + (size_t)(i * 8) * K + k0, &Bs[(wid * 32 + i * 8) * 64]);
    }
    __syncthreads();
    #pragma unroll
    for (int kk = 0; kk < 2; ++kk) {
      bf16x8 a[4], bfr[4];
      #pragma unroll
      for (int m = 0; m < 4; ++m)
        a[m] = *(const bf16x8*)&As[(wr * 64 + m * 16 + lo) * 64 + kk * 32 + hi * 8];
      #pragma unroll
      for (int n = 0; n < 4; ++n)
        bfr[n] = *(const bf16x8*)&Bs[(wc * 64 + n * 16 + lo) * 64 + kk * 32 + hi * 8];
      #pragma unroll
      for (int m = 0; m < 4; ++m)
        #pragma unroll
        for (int n = 0; n < 4; ++n)
          acc[m][n] = __builtin_amdgcn_mfma_f32_16x16x32_bf16(a[m], bfr[n], acc[m][n], 0, 0, 0);
    }
    __syncthreads();
  }

  #pragma unroll
  for (int m = 0; m < 4; ++m) {
    #pragma unroll
    for (int r = 0; r < 4; ++r) {
      const int grow = m0 + wr * 64 + m * 16 + hi * 4 + r;
      if (grow < M) {
        float* cp = C + (size_t)grow * N + n0 + wc * 64 + lo;
        const float* bp = bias + n0 + wc * 64 + lo;
        #pragma unroll
        for (int n = 0; n < 4; ++n) cp[n * 16] = acc[m][n][r] + bp[n * 16];
      }
    }
  }
}

// ---------------------------------------------------------------------------
// In-place LayerNorm on q and k of qkv[M, 2304]; Q scaled by 0.125*log2e.
// Also writes bf16 copies to qb/kb in [bh][n][64] layout.
// ---------------------------------------------------------------------------
__global__ __launch_bounds__(256) void ln_qk_kernel(
    float* __restrict__ qkv,
    const float* __restrict__ gq, const float* __restrict__ bq,
    const float* __restrict__ gk, const float* __restrict__ bk,
    short* __restrict__ qb, short* __restrict__ kb) {
  const int task = blockIdx.x * 4 + (threadIdx.x >> 6);
  const int lane = threadIdx.x & 63;
  const int TASKS = MROWS * HEADS;
  if (task >= TASKS) return;
  const int row = task / HEADS;
  const int h = task - row * HEADS;
  const size_t base = (size_t)row * C3 + h * DH;
  float xq = qkv[base + lane];
  float xk = qkv[base + DIM + lane];
  float sq = xq, s2q = xq * xq, sk = xk, s2k = xk * xk;
  #pragma unroll
  for (int off = 32; off; off >>= 1) {
    sq  += __shfl_xor(sq,  off);
    s2q += __shfl_xor(s2q, off);
    sk  += __shfl_xor(sk,  off);
    s2k += __shfl_xor(s2k, off);
  }
  const float inv64 = 1.f / 64.f;
  float mq = sq * inv64, vq = s2q * inv64 - mq * mq;
  float mk = sk * inv64, vk = s2k * inv64 - mk * mk;
  float rq = rsqrtf(vq + 1e-5f), rk = rsqrtf(vk + 1e-5f);
  float qn = ((xq - mq) * rq * gq[lane] + bq[lane]) * QSCALE;
  float kn =  (xk - mk) * rk * gk[lane] + bk[lane];
  qkv[base + lane]       = qn;
  qkv[base + DIM + lane] = kn;
  const int b = row / NSEQ;
  const int n = row - b * NSEQ;
  const size_t o = ((size_t)(b * HEADS + h) * NKPAD + n) * DH + lane;
  qb[o] = (short)f2bf(qn);
  kb[o] = (short)f2bf(kn);
}

// ---------------------------------------------------------------------------
// V convert+transpose: qkv v-part fp32 -> vt bf16 [bh][d][NKPAD] (zero pad).
// Also zero-fills qb/kb pad rows. Grid: (17, 96), 256 threads.
// ---------------------------------------------------------------------------
__global__ __launch_bounds__(256) void vt_convert_kernel(
    const float* __restrict__ qkv, short* __restrict__ vt,
    short* __restrict__ qb, short* __restrict__ kb) {
  const int kt = blockIdx.x;     // key tile 0..16
  const int bh = blockIdx.y;     // 0..95
  const int b = bh / HEADS, h = bh - (bh / HEADS) * HEADS;
  const int t = threadIdx.x;
  __shared__ float tile[64][65];
  const int r = t >> 2;          // 0..63
  const int c0 = (t & 3) * 16;   // 0,16,32,48
  const int grow = kt * 64 + r;  // key index 0..1087

  const float* src = qkv + (size_t)(b * NSEQ + grow) * C3 + 2 * DIM + h * DH + c0;
  #pragma unroll
  for (int j = 0; j < 16; j += 4) {
    float4 v = (grow < NSEQ) ? *(const float4*)(src + j)
                             : make_float4(0.f, 0.f, 0.f, 0.f);
    tile[r][c0 + j]     = v.x;
    tile[r][c0 + j + 1] = v.y;
    tile[r][c0 + j + 2] = v.z;
    tile[r][c0 + j + 3] = v.w;
  }
  __syncthreads();
  bf16x8 w0, w1;
  #pragma unroll
  for (int j = 0; j < 8; ++j) {
    w0[j] = (short)f2bf(tile[c0 + j][r]);
    w1[j] = (short)f2bf(tile[c0 + 8 + j][r]);
  }
  short* dst = vt + ((size_t)bh * DH + r) * NKPAD + kt * 64 + c0;
  *(bf16x8*)dst = w0;
  *(bf16x8*)(dst + 8) = w1;

  if (kt == 16 && grow >= NSEQ) {
    const size_t o = ((size_t)bh * NKPAD + grow) * DH + c0;
    #pragma unroll
    for (int j = 0; j < 16; ++j) { qb[o + j] = 0; kb[o + j] = 0; }
  }
}

// ---------------------------------------------------------------------------
// MFMA bf16 flash attention (fixed-offset softmax). Output written as bf16
// into ab[MPAD rows][DIM] (row = b*NSEQ + n) for the proj GEMM A-operand.
// Grid: (17, 96), 256 threads (4 waves; wave owns 16 query rows).
// ---------------------------------------------------------------------------
__global__ __launch_bounds__(256) void attn_mfma_kernel(
    const short* __restrict__ qb, const short* __restrict__ kb,
    const short* __restrict__ vt, short* __restrict__ ab) {
  const int bh = blockIdx.y;
  const int b = bh / HEADS, h = bh - (bh / HEADS) * HEADS;
  const int wid = threadIdx.x >> 6;
  const int lane = threadIdx.x & 63;
  const int lo = lane & 15, hi = lane >> 4;
  const int q0 = blockIdx.x * 64 + wid * 16;

  __shared__ short Pb[4][16][72];   // per-wave P buffer, stride 72 (bank-safe)

  const short* kbase = kb + (size_t)bh * NKPAD * DH;
  const short* vbase = vt + (size_t)bh * DH * NKPAD;

  bf16x8 aq0, aq1;
  {
    const short* qp = qb + (size_t)bh * NKPAD * DH + (size_t)(q0 + lo) * DH + hi * 8;
    aq0 = *(const bf16x8*)qp;
    aq1 = *(const bf16x8*)(qp + 32);
  }

  f32x4 o[4];
  float lsum[4];
  #pragma unroll
  for (int nt = 0; nt < 4; ++nt) {
    o[nt][0] = o[nt][1] = o[nt][2] = o[nt][3] = 0.f;
    lsum[nt] = 0.f;
  }

  for (int kt = 0; kt < 17; ++kt) {
    f32x4 s[4];
    #pragma unroll
    for (int nt = 0; nt < 4; ++nt) s[nt][0] = s[nt][1] = s[nt][2] = s[nt][3] = 0.f;
    const short* kpt = kbase + (size_t)kt * 64 * DH;
    #pragma unroll
    for (int nt = 0; nt < 4; ++nt) {
      const short* kr = kpt + (size_t)(nt * 16 + lo) * DH + hi * 8;
      bf16x8 b0 = *(const bf16x8*)kr;
      bf16x8 b1 = *(const bf16x8*)(kr + 32);
      s[nt] = __builtin_amdgcn_mfma_f32_16x16x32_bf16(aq0, b0, s[nt], 0, 0, 0);
      s[nt] = __builtin_amdgcn_mfma_f32_16x16x32_bf16(aq1, b1, s[nt], 0, 0, 0);
    }
    if (kt == 16) {
      #pragma unroll
      for (int nt = 0; nt < 4; ++nt) {
        if (1024 + nt * 16 + lo >= NSEQ) {
          s[nt][0] = s[nt][1] = s[nt][2] = s[nt][3] = -1e30f;
        }
      }
    }
    #pragma unroll
    for (int nt = 0; nt < 4; ++nt) {
      #pragma unroll
      for (int r = 0; r < 4; ++r) {
        float p = exp2f(s[nt][r] - SBOUND);
        lsum[r] += p;
        Pb[wid][4 * hi + r][nt * 16 + lo] = (short)f2bf(p);
      }
    }
    #pragma unroll
    for (int ks = 0; ks < 2; ++ks) {
      bf16x8 pa = *(const bf16x8*)&Pb[wid][lo][ks * 32 + hi * 8];
      #pragma unroll
      for (int nt = 0; nt < 4; ++nt) {
        const short* vr = vbase + (size_t)(nt * 16 + lo) * NKPAD
                        + kt * 64 + ks * 32 + hi * 8;
        bf16x8 bv = *(const bf16x8*)vr;
        o[nt] = __builtin_amdgcn_mfma_f32_16x16x32_bf16(pa, bv, o[nt], 0, 0, 0);
      }
    }
  }

  #pragma unroll
  for (int r = 0; r < 4; ++r) {
    float v = lsum[r];
    v += __shfl_xor(v, 1);
    v += __shfl_xor(v, 2);
    v += __shfl_xor(v, 4);
    v += __shfl_xor(v, 8);
    lsum[r] = v;
  }
  #pragma unroll
  for (int r = 0; r < 4; ++r) {
    const int qrow = q0 + 4 * hi + r;
    if (qrow < NSEQ) {
      const float inv = 1.f / lsum[r];
      short* op = ab + (size_t)(b * NSEQ + qrow) * DIM + h * DH + lo;
      #pragma unroll
      for (int nt = 0; nt < 4; ++nt) op[nt * 16] = (short)f2bf(o[nt][r] * inv);
    }
  }
}

// ---------------------------------------------------------------------------
// attn_map: softmax(q_row0 . K) averaged over heads, keys 1..1024, per batch.
// ---------------------------------------------------------------------------
__global__ __launch_bounds__(256) void attn_map_kernel(
    const float* __restrict__ qkv, float* __restrict__ map) {
  const int b = blockIdx.x;
  const int tid = threadIdx.x;
  __shared__ float q0s[64];
  __shared__ float red[256];
  float acc[5] = {0.f, 0.f, 0.f, 0.f, 0.f};
  const size_t rowbase = (size_t)b * NSEQ;

  for (int h = 0; h < HEADS; ++h) {
    __syncthreads();
    if (tid < 64) q0s[tid] = qkv[rowbase * C3 + h * DH + tid];
    __syncthreads();
    float s[5];
    float lm = -INFINITY;
    #pragma unroll
    for (int sl = 0; sl < 5; ++sl) {
      int j = tid + sl * 256;
      s[sl] = -INFINITY;
      if (j < NSEQ) {
        const float* kp = &qkv[(rowbase + j) * C3 + DIM + h * DH];
        float d0 = 0.f;
        #pragma unroll
        for (int d = 0; d < 64; d += 4) {
          float4 kv = *(const float4*)&kp[d];
          d0 += q0s[d] * kv.x + q0s[d + 1] * kv.y + q0s[d + 2] * kv.z + q0s[d + 3] * kv.w;
        }
        s[sl] = d0;
        lm = fmaxf(lm, d0);
      }
    }
    red[tid] = lm; __syncthreads();
    for (int off = 128; off > 0; off >>= 1) {
      if (tid < off) red[tid] = fmaxf(red[tid], red[tid + off]);
      __syncthreads();
    }
    const float Mx = red[0]; __syncthreads();
    float p[5];
    float ls = 0.f;
    #pragma unroll
    for (int sl = 0; sl < 5; ++sl) {
      int j = tid + sl * 256;
      p[sl] = 0.f;
      if (j < NSEQ) { p[sl] = exp2f(s[sl] - Mx); ls += p[sl]; }
    }
    red[tid] = ls; __syncthreads();
    for (int off = 128; off > 0; off >>= 1) {
      if (tid < off) red[tid] += red[tid + off];
      __syncthreads();
    }
    const float S = red[0]; __syncthreads();
    const float inv = 1.f / (S * (float)HEADS);
    #pragma unroll
    for (int sl = 0; sl < 5; ++sl) {
      int j = tid + sl * 256;
      if (j < NSEQ) acc[sl] += p[sl] * inv;
    }
  }
  #pragma unroll
  for (int sl = 0; sl < 5; ++sl) {
    int j = tid + sl * 256;
    if (j >= 1 && j < NSEQ) map[(size_t)b * (NSEQ - 1) + j - 1] = acc[sl];
  }
}

// ---------------------------------------------------------------------------
extern "C" void kernel_launch(void* const* d_in, const int* in_sizes, int n_in,
                              void* d_out, int out_size, void* d_ws, size_t ws_size,
                              hipStream_t stream) {
  const float* x     = (const float*)d_in[0];
  const float* Wqkv  = (const float*)d_in[1];
  const float* bqkv  = (const float*)d_in[2];
  const float* Wproj = (const float*)d_in[3];
  const float* bproj = (const float*)d_in[4];
  const float* gq    = (const float*)d_in[5];
  const float* betaq = (const float*)d_in[6];
  const float* gk    = (const float*)d_in[7];
  const float* betak = (const float*)d_in[8];

  float* qkv = (float*)d_ws;                              // [8200,2304] f32
  short* xb  = (short*)(qkv + (size_t)MROWS * C3);        // [8320,768] bf16 (reused as attn out)
  short* qb  = xb + (size_t)MPAD * DIM;                   // [96,1088,64] bf16
  short* kb  = qb + (size_t)NBH * NKPAD * DH;             // [96,1088,64] bf16
  short* vt  = kb + (size_t)NBH * NKPAD * DH;             // [96,64,1088] bf16
  short* wqt = vt + (size_t)NBH * DH * NKPAD;             // [2304,768] bf16
  short* wpt = wqt + (size_t)C3 * DIM;                    // [768,768] bf16
  float* out = (float*)d_out;                             // [8200,768]
  float* map = out + (size_t)MROWS * DIM;                 // [8,1024]

  // 0) conversions
  convert_x_kernel<<<MPAD * DIM / 2048, 256, 0, stream>>>(x, xb);
  {
    dim3 grid(C3 / 64, DIM / 64);
    wtrans_kernel<<<grid, 256, 0, stream>>>(Wqkv, wqt, DIM, C3);
  }
  {
    dim3 grid(DIM / 64, DIM / 64);
    wtrans_kernel<<<grid, 256, 0, stream>>>(Wproj, wpt, DIM, DIM);
  }
  // 1) qkv = x @ Wqkv + bqkv   (bf16 MFMA)
  {
    dim3 grid(C3 / 128, MPAD / 128);
    gemm_bf16_kernel<<<grid, 256, 0, stream>>>(xb, wqt, bqkv, qkv, MROWS, C3, DIM);
  }
  // 2) LN on q,k (fp32 in-place + bf16 qb/kb)
  {
    int blocks = (MROWS * HEADS + 3) / 4;
    ln_qk_kernel<<<blocks, 256, 0, stream>>>(qkv, gq, betaq, gk, betak, qb, kb);
  }
  // 3) V transpose/convert + pad zeroing
  {
    dim3 grid(17, NBH);
    vt_convert_kernel<<<grid, 256, 0, stream>>>(qkv, vt, qb, kb);
  }
  // 4) MFMA attention -> bf16 into xb (dead after step 1)
  {
    dim3 grid(17, NBH);
    attn_mfma_kernel<<<grid, 256, 0, stream>>>(qb, kb, vt, xb);
  }
  // 5) attn_map (exact fp32 path)
  attn_map_kernel<<<BS, 256, 0, stream>>>(qkv, map);
  // 6) out = attn_out @ Wproj + bproj   (bf16 MFMA)
  {
    dim3 grid(DIM / 128, MPAD / 128);
    gemm_bf16_kernel<<<grid, 256, 0, stream>>>(xb, wpt, bproj, out, MROWS, DIM, DIM);
  }
}

// Round 5
// 263.949 us; speedup vs baseline: 10.5655x; 1.9337x over previous
//
#include <hip/hip_runtime.h>
#include <hip/hip_bf16.h>
#include <math.h>

// Problem constants
#define BS   8
#define NSEQ 1025
#define DIM  768
#define C3   2304      // 3*DIM
#define HEADS 12
#define DH   64
#define MROWS (BS*NSEQ) // 8200
#define MPAD  8320      // 65*128, padded M for GEMM tiles
#define NKPAD 1088      // 17*64, padded key length for MFMA tiles
#define QPAD  1152      // 9*128, padded query length for attn blocks
#define NBH   (BS*HEADS)

// log2(e) folded into Q during LN so softmax uses exp2
#define QSCALE (0.125f * 1.44269504088896340736f)
#define SBOUND 10.0f    // fixed softmax offset (log2 domain); ratios unchanged

typedef __attribute__((ext_vector_type(8))) short bf16x8;
typedef __attribute__((ext_vector_type(4))) float f32x4;

static __device__ __forceinline__ unsigned short f2bf(float f) {
  unsigned int u = __float_as_uint(f);
  unsigned int r = (u + 0x7fffu + ((u >> 16) & 1u)) >> 16;
  return (unsigned short)r;
}

static __device__ __forceinline__ void gload16(const short* g, short* l) {
  __builtin_amdgcn_global_load_lds(
      (const __attribute__((address_space(1))) unsigned int*)g,
      (__attribute__((address_space(3))) unsigned int*)l, 16, 0, 0);
}

// ---------------------------------------------------------------------------
// x fp32 [MROWS][DIM] -> xb bf16 [MPAD][DIM], pad rows zeroed.
// ---------------------------------------------------------------------------
__global__ __launch_bounds__(256) void convert_x_kernel(
    const float* __restrict__ x, short* __restrict__ xb) {
  const size_t i = ((size_t)blockIdx.x * 256 + threadIdx.x) * 8;
  const size_t row = i / DIM;
  bf16x8 w;
  if (row < MROWS) {
    float4 v0 = *(const float4*)&x[i];
    float4 v1 = *(const float4*)&x[i + 4];
    w[0] = (short)f2bf(v0.x); w[1] = (short)f2bf(v0.y);
    w[2] = (short)f2bf(v0.z); w[3] = (short)f2bf(v0.w);
    w[4] = (short)f2bf(v1.x); w[5] = (short)f2bf(v1.y);
    w[6] = (short)f2bf(v1.z); w[7] = (short)f2bf(v1.w);
  } else {
    #pragma unroll
    for (int j = 0; j < 8; ++j) w[j] = 0;
  }
  *(bf16x8*)&xb[i] = w;
}

// ---------------------------------------------------------------------------
// W fp32 [K][N] -> Wt bf16 [N][K] (transpose + convert). Grid (N/64, K/64).
// ---------------------------------------------------------------------------
__global__ __launch_bounds__(256) void wtrans_kernel(
    const float* __restrict__ W, short* __restrict__ Wt, int K, int N) {
  const int n0 = blockIdx.x * 64, k0 = blockIdx.y * 64;
  __shared__ float tile[64][65];
  const int r = threadIdx.x >> 2;        // 0..63
  const int c0 = (threadIdx.x & 3) * 16; // 0,16,32,48
  const float* src = W + (size_t)(k0 + r) * N + n0 + c0;
  #pragma unroll
  for (int j = 0; j < 16; j += 4) {
    float4 v = *(const float4*)(src + j);
    tile[r][c0 + j]     = v.x;
    tile[r][c0 + j + 1] = v.y;
    tile[r][c0 + j + 2] = v.z;
    tile[r][c0 + j + 3] = v.w;
  }
  __syncthreads();
  bf16x8 w0, w1;
  #pragma unroll
  for (int j = 0; j < 8; ++j) {
    w0[j] = (short)f2bf(tile[c0 + j][r]);
    w1[j] = (short)f2bf(tile[c0 + 8 + j][r]);
  }
  short* dst = Wt + (size_t)(n0 + r) * K + k0 + c0;
  *(bf16x8*)dst = w0;
  *(bf16x8*)(dst + 8) = w1;
}

// ---------------------------------------------------------------------------
// bf16 MFMA GEMM: C[M,N] f32 = A[Mp,K]bf16 . Bt[N,K]bf16^T + bias[N].
// 128x128 tile, BK=64, 4 waves (2x2), global_load_lds staging (m97 structure).
// ---------------------------------------------------------------------------
__global__ __launch_bounds__(256) void gemm_bf16_kernel(
    const short* __restrict__ A, const short* __restrict__ Bt,
    const float* __restrict__ bias, float* __restrict__ C,
    int M, int N, int K) {
  __shared__ short As[128 * 64];
  __shared__ short Bs[128 * 64];
  const int tid = threadIdx.x;
  const int wid = tid >> 6, lane = tid & 63;
  const int lo = lane & 15, hi = lane >> 4;
  const int wr = wid >> 1, wc = wid & 1;
  const int m0 = blockIdx.y * 128, n0 = blockIdx.x * 128;
  const int rl = lane >> 3;            // 0..7
  const int cb = (lane & 7) * 8;       // bf16 col offset within 64

  f32x4 acc[4][4];
  #pragma unroll
  for (int m = 0; m < 4; ++m)
    #pragma unroll
    for (int n = 0; n < 4; ++n)
      acc[m][n][0] = acc[m][n][1] = acc[m][n][2] = acc[m][n][3] = 0.f;

  const short* Abase = A + (size_t)(m0 + wid * 32 + rl) * K + cb;
  const short* Bbase = Bt + (size_t)(n0 + wid * 32 + rl) * K + cb;

  for (int k0 = 0; k0 < K; k0 += 64) {
    #pragma unroll
    for (int i = 0; i < 4; ++i) {
      gload16(Abase + (size_t)(i * 8) * K + k0, &As[(wid * 32 + i * 8) * 64]);
      gload16(Bbase + (size_t)(i * 8) * K + k0, &Bs[(wid * 32 + i * 8) * 64]);
    }
    __syncthreads();
    #pragma unroll
    for (int kk = 0; kk < 2; ++kk) {
      bf16x8 a[4], bfr[4];
      #pragma unroll
      for (int m = 0; m < 4; ++m)
        a[m] = *(const bf16x8*)&As[(wr * 64 + m * 16 + lo) * 64 + kk * 32 + hi * 8];
      #pragma unroll
      for (int n = 0; n < 4; ++n)
        bfr[n] = *(const bf16x8*)&Bs[(wc * 64 + n * 16 + lo) * 64 + kk * 32 + hi * 8];
      #pragma unroll
      for (int m = 0; m < 4; ++m)
        #pragma unroll
        for (int n = 0; n < 4; ++n)
          acc[m][n] = __builtin_amdgcn_mfma_f32_16x16x32_bf16(a[m], bfr[n], acc[m][n], 0, 0, 0);
    }
    __syncthreads();
  }

  #pragma unroll
  for (int m = 0; m < 4; ++m) {
    #pragma unroll
    for (int r = 0; r < 4; ++r) {
      const int grow = m0 + wr * 64 + m * 16 + hi * 4 + r;
      if (grow < M) {
        float* cp = C + (size_t)grow * N + n0 + wc * 64 + lo;
        const float* bp = bias + n0 + wc * 64 + lo;
        #pragma unroll
        for (int n = 0; n < 4; ++n) cp[n * 16] = acc[m][n][r] + bp[n * 16];
      }
    }
  }
}

// ---------------------------------------------------------------------------
// In-place LayerNorm on q and k of qkv[M, 2304]; Q scaled by 0.125*log2e.
// bf16 copies: qb [bh][QPAD][64], kb [bh][NKPAD][64].
// ---------------------------------------------------------------------------
__global__ __launch_bounds__(256) void ln_qk_kernel(
    float* __restrict__ qkv,
    const float* __restrict__ gq, const float* __restrict__ bq,
    const float* __restrict__ gk, const float* __restrict__ bk,
    short* __restrict__ qb, short* __restrict__ kb) {
  const int task = blockIdx.x * 4 + (threadIdx.x >> 6);
  const int lane = threadIdx.x & 63;
  const int TASKS = MROWS * HEADS;
  if (task >= TASKS) return;
  const int row = task / HEADS;
  const int h = task - row * HEADS;
  const size_t base = (size_t)row * C3 + h * DH;
  float xq = qkv[base + lane];
  float xk = qkv[base + DIM + lane];
  float sq = xq, s2q = xq * xq, sk = xk, s2k = xk * xk;
  #pragma unroll
  for (int off = 32; off; off >>= 1) {
    sq  += __shfl_xor(sq,  off);
    s2q += __shfl_xor(s2q, off);
    sk  += __shfl_xor(sk,  off);
    s2k += __shfl_xor(s2k, off);
  }
  const float inv64 = 1.f / 64.f;
  float mq = sq * inv64, vq = s2q * inv64 - mq * mq;
  float mk = sk * inv64, vk = s2k * inv64 - mk * mk;
  float rq = rsqrtf(vq + 1e-5f), rk = rsqrtf(vk + 1e-5f);
  float qn = ((xq - mq) * rq * gq[lane] + bq[lane]) * QSCALE;
  float kn =  (xk - mk) * rk * gk[lane] + bk[lane];
  qkv[base + lane]       = qn;
  qkv[base + DIM + lane] = kn;
  const int b = row / NSEQ;
  const int n = row - b * NSEQ;
  const int bh = b * HEADS + h;
  qb[((size_t)bh * QPAD  + n) * DH + lane] = (short)f2bf(qn);
  kb[((size_t)bh * NKPAD + n) * DH + lane] = (short)f2bf(kn);
}

// ---------------------------------------------------------------------------
// V convert+transpose: qkv v-part fp32 -> vt bf16 [bh][d][NKPAD] (zero pad).
// Grid: (17, 96), 256 threads.
// ---------------------------------------------------------------------------
__global__ __launch_bounds__(256) void vt_convert_kernel(
    const float* __restrict__ qkv, short* __restrict__ vt) {
  const int kt = blockIdx.x;     // key tile 0..16
  const int bh = blockIdx.y;     // 0..95
  const int b = bh / HEADS, h = bh - (bh / HEADS) * HEADS;
  const int t = threadIdx.x;
  __shared__ float tile[64][65];
  const int r = t >> 2;          // 0..63
  const int c0 = (t & 3) * 16;   // 0,16,32,48
  const int grow = kt * 64 + r;  // key index 0..1087

  const float* src = qkv + (size_t)(b * NSEQ + grow) * C3 + 2 * DIM + h * DH + c0;
  #pragma unroll
  for (int j = 0; j < 16; j += 4) {
    float4 v = (grow < NSEQ) ? *(const float4*)(src + j)
                             : make_float4(0.f, 0.f, 0.f, 0.f);
    tile[r][c0 + j]     = v.x;
    tile[r][c0 + j + 1] = v.y;
    tile[r][c0 + j + 2] = v.z;
    tile[r][c0 + j + 3] = v.w;
  }
  __syncthreads();
  bf16x8 w0, w1;
  #pragma unroll
  for (int j = 0; j < 8; ++j) {
    w0[j] = (short)f2bf(tile[c0 + j][r]);
    w1[j] = (short)f2bf(tile[c0 + 8 + j][r]);
  }
  short* dst = vt + ((size_t)bh * DH + r) * NKPAD + kt * 64 + c0;
  *(bf16x8*)dst = w0;
  *(bf16x8*)(dst + 8) = w1;
}

// ---------------------------------------------------------------------------
// MFMA bf16 flash attention v2: LDS-staged K/V, double-buffered, swizzled.
// Block = 256 threads (4 waves); wave owns 32 query rows (2 m-frags).
// Grid: (QPAD/128 = 9, 96). Output bf16 into ab[row][DIM].
// ---------------------------------------------------------------------------
__global__ __launch_bounds__(256) void attn_mfma_kernel(
    const short* __restrict__ qb, const short* __restrict__ kb,
    const short* __restrict__ vt, short* __restrict__ ab) {
  const int bh = blockIdx.y;
  const int b = bh / HEADS, h = bh - (bh / HEADS) * HEADS;
  const int wid = threadIdx.x >> 6;
  const int lane = threadIdx.x & 63;
  const int lo = lane & 15, hi = lane >> 4;
  const int q0 = blockIdx.x * 128;
  const int xsw = (lo & 7) << 3;          // read-side XOR swizzle (shorts)

  __shared__ short Ks[2][64 * 64];        // swizzled K tile  [key][d]
  __shared__ short Vs[2][64 * 64];        // swizzled V^T tile [d][key]
  __shared__ short Pb[4][32][72];         // per-wave P buffer

  const short* kg = kb + (size_t)bh * NKPAD * DH;
  const short* vg = vt + (size_t)bh * DH * NKPAD;

  // staging: linear LDS dest (wave-uniform base + lane*16), pre-swizzled
  // global source so that read-side XOR sees conflict-free banks.
  auto stage = [&](int bf, int kt) {
    #pragma unroll
    for (int i = 0; i < 2; ++i) {
      const int r = wid * 16 + i * 8 + (lane >> 3);
      const int sw = ((lane & 7) ^ (lane >> 3)) << 3;
      gload16(kg + (size_t)(kt * 64 + r) * DH + sw,
              &Ks[bf][wid * 1024 + i * 512]);
      gload16(vg + (size_t)r * NKPAD + kt * 64 + sw,
              &Vs[bf][wid * 1024 + i * 512]);
    }
  };

  // Q A-fragments: 2 m-tiles x 2 k-chunks
  bf16x8 aq[2][2];
  #pragma unroll
  for (int m = 0; m < 2; ++m) {
    const short* qp = qb + (size_t)bh * QPAD * DH
                    + (size_t)(q0 + wid * 32 + m * 16 + lo) * DH + hi * 8;
    aq[m][0] = *(const bf16x8*)qp;
    aq[m][1] = *(const bf16x8*)(qp + 32);
  }

  f32x4 o[2][4];
  float lsum[2][4];
  #pragma unroll
  for (int m = 0; m < 2; ++m)
    #pragma unroll
    for (int nt = 0; nt < 4; ++nt) {
      o[m][nt][0] = o[m][nt][1] = o[m][nt][2] = o[m][nt][3] = 0.f;
      lsum[m][nt] = 0.f;
    }

  stage(0, 0);
  __syncthreads();

  for (int kt = 0; kt < 17; ++kt) {
    const int bf = kt & 1;
    if (kt < 16) stage(bf ^ 1, kt + 1);   // async prefetch into other buffer

    // ---- QK^T ----
    f32x4 s[2][4];
    #pragma unroll
    for (int m = 0; m < 2; ++m)
      #pragma unroll
      for (int nt = 0; nt < 4; ++nt)
        s[m][nt][0] = s[m][nt][1] = s[m][nt][2] = s[m][nt][3] = 0.f;
    #pragma unroll
    for (int kk = 0; kk < 2; ++kk) {
      bf16x8 kf[4];
      #pragma unroll
      for (int nt = 0; nt < 4; ++nt)
        kf[nt] = *(const bf16x8*)&Ks[bf][(nt * 16 + lo) * 64
                                         + ((kk * 32 + hi * 8) ^ xsw)];
      #pragma unroll
      for (int m = 0; m < 2; ++m)
        #pragma unroll
        for (int nt = 0; nt < 4; ++nt)
          s[m][nt] = __builtin_amdgcn_mfma_f32_16x16x32_bf16(
              aq[m][kk], kf[nt], s[m][nt], 0, 0, 0);
    }
    if (kt == 16) {   // mask keys >= 1025 (key index 1024 + nt*16+lo)
      #pragma unroll
      for (int m = 0; m < 2; ++m)
        #pragma unroll
        for (int nt = 0; nt < 4; ++nt)
          if (nt * 16 + lo >= 1)
            s[m][nt][0] = s[m][nt][1] = s[m][nt][2] = s[m][nt][3] = -1e30f;
    }
    // ---- softmax (fixed offset) + P staging ----
    #pragma unroll
    for (int m = 0; m < 2; ++m)
      #pragma unroll
      for (int nt = 0; nt < 4; ++nt)
        #pragma unroll
        for (int r = 0; r < 4; ++r) {
          float p = exp2f(s[m][nt][r] - SBOUND);
          lsum[m][r] += p;
          Pb[wid][m * 16 + 4 * hi + r][nt * 16 + lo] = (short)f2bf(p);
        }
    // ---- PV ----
    #pragma unroll
    for (int ks = 0; ks < 2; ++ks) {
      bf16x8 pa0 = *(const bf16x8*)&Pb[wid][lo][ks * 32 + hi * 8];
      bf16x8 pa1 = *(const bf16x8*)&Pb[wid][16 + lo][ks * 32 + hi * 8];
      #pragma unroll
      for (int nt = 0; nt < 4; ++nt) {
        bf16x8 vf = *(const bf16x8*)&Vs[bf][(nt * 16 + lo) * 64
                                            + ((ks * 32 + hi * 8) ^ xsw)];
        o[0][nt] = __builtin_amdgcn_mfma_f32_16x16x32_bf16(pa0, vf, o[0][nt], 0, 0, 0);
        o[1][nt] = __builtin_amdgcn_mfma_f32_16x16x32_bf16(pa1, vf, o[1][nt], 0, 0, 0);
      }
    }
    __syncthreads();   // drains vmcnt (prefetch) + all waves done with bf
  }

  #pragma unroll
  for (int m = 0; m < 2; ++m)
    #pragma unroll
    for (int r = 0; r < 4; ++r) {
      float v = lsum[m][r];
      v += __shfl_xor(v, 1);
      v += __shfl_xor(v, 2);
      v += __shfl_xor(v, 4);
      v += __shfl_xor(v, 8);
      lsum[m][r] = v;
    }
  #pragma unroll
  for (int m = 0; m < 2; ++m)
    #pragma unroll
    for (int r = 0; r < 4; ++r) {
      const int qrow = q0 + wid * 32 + m * 16 + 4 * hi + r;
      if (qrow < NSEQ) {
        const float inv = 1.f / lsum[m][r];
        short* op = ab + (size_t)(b * NSEQ + qrow) * DIM + h * DH + lo;
        #pragma unroll
        for (int nt = 0; nt < 4; ++nt)
          op[nt * 16] = (short)f2bf(o[m][nt][r] * inv);
      }
    }
}

// ---------------------------------------------------------------------------
// attn_map pass A: per-(b,h) row-0 softmax max & inv-denominator.
// Grid 96, 256 threads. ms[bh] = {max, 1/(sum*HEADS)}.
// ---------------------------------------------------------------------------
__global__ __launch_bounds__(256) void map_ms_kernel(
    const float* __restrict__ qkv, float* __restrict__ ms) {
  const int bh = blockIdx.x;
  const int b = bh / HEADS, h = bh - (bh / HEADS) * HEADS;
  const int tid = threadIdx.x;
  __shared__ float q0s[64];
  __shared__ float red[256];
  const size_t rowbase = (size_t)b * NSEQ;
  if (tid < 64) q0s[tid] = qkv[rowbase * C3 + h * DH + tid];
  __syncthreads();
  float s[5];
  float lm = -INFINITY;
  #pragma unroll
  for (int sl = 0; sl < 5; ++sl) {
    int j = tid + sl * 256;
    s[sl] = -INFINITY;
    if (j < NSEQ) {
      const float* kp = &qkv[(rowbase + j) * C3 + DIM + h * DH];
      float d0 = 0.f;
      #pragma unroll
      for (int d = 0; d < 64; d += 4) {
        float4 kv = *(const float4*)&kp[d];
        d0 += q0s[d] * kv.x + q0s[d + 1] * kv.y + q0s[d + 2] * kv.z + q0s[d + 3] * kv.w;
      }
      s[sl] = d0;
      lm = fmaxf(lm, d0);
    }
  }
  red[tid] = lm; __syncthreads();
  for (int off = 128; off > 0; off >>= 1) {
    if (tid < off) red[tid] = fmaxf(red[tid], red[tid + off]);
    __syncthreads();
  }
  const float Mx = red[0]; __syncthreads();
  float ls = 0.f;
  #pragma unroll
  for (int sl = 0; sl < 5; ++sl) {
    int j = tid + sl * 256;
    if (j < NSEQ) ls += exp2f(s[sl] - Mx);
  }
  red[tid] = ls; __syncthreads();
  for (int off = 128; off > 0; off >>= 1) {
    if (tid < off) red[tid] += red[tid + off];
    __syncthreads();
  }
  if (tid == 0) {
    ms[bh * 2]     = Mx;
    ms[bh * 2 + 1] = 1.f / (red[0] * (float)HEADS);
  }
}

// ---------------------------------------------------------------------------
// attn_map pass B: map[b][j-1] = sum_h exp2(q0_h . k_jh - M_h) * inv_h.
// Grid (4, 8), 256 threads; thread handles one (b, j).
// ---------------------------------------------------------------------------
__global__ __launch_bounds__(256) void map_p_kernel(
    const float* __restrict__ qkv, const float* __restrict__ ms,
    float* __restrict__ map) {
  const int b = blockIdx.y;
  const int j = blockIdx.x * 256 + threadIdx.x + 1;   // 1..1024
  const int tid = threadIdx.x;
  __shared__ float q0s[768];
  __shared__ float msb[24];
  const size_t rowbase = (size_t)b * NSEQ;
  for (int idx = tid; idx < 768; idx += 256) q0s[idx] = qkv[rowbase * C3 + idx];
  if (tid < 24) msb[tid] = ms[b * HEADS * 2 + tid];
  __syncthreads();
  const float* kp = &qkv[(rowbase + j) * C3 + DIM];
  float acc = 0.f;
  #pragma unroll
  for (int h = 0; h < HEADS; ++h) {
    float d0 = 0.f;
    #pragma unroll
    for (int d = 0; d < 64; d += 4) {
      float4 kv = *(const float4*)&kp[h * DH + d];
      const float* qp = &q0s[h * DH + d];
      d0 += qp[0] * kv.x + qp[1] * kv.y + qp[2] * kv.z + qp[3] * kv.w;
    }
    acc += exp2f(d0 - msb[h * 2]) * msb[h * 2 + 1];
  }
  map[(size_t)b * (NSEQ - 1) + j - 1] = acc;
}

// ---------------------------------------------------------------------------
extern "C" void kernel_launch(void* const* d_in, const int* in_sizes, int n_in,
                              void* d_out, int out_size, void* d_ws, size_t ws_size,
                              hipStream_t stream) {
  const float* x     = (const float*)d_in[0];
  const float* Wqkv  = (const float*)d_in[1];
  const float* bqkv  = (const float*)d_in[2];
  const float* Wproj = (const float*)d_in[3];
  const float* bproj = (const float*)d_in[4];
  const float* gq    = (const float*)d_in[5];
  const float* betaq = (const float*)d_in[6];
  const float* gk    = (const float*)d_in[7];
  const float* betak = (const float*)d_in[8];

  float* qkv = (float*)d_ws;                              // [8200,2304] f32
  short* xb  = (short*)(qkv + (size_t)MROWS * C3);        // [8320,768] bf16 (reused as attn out)
  short* qb  = xb + (size_t)MPAD * DIM;                   // [96,1152,64] bf16
  short* kb  = qb + (size_t)NBH * QPAD * DH;              // [96,1088,64] bf16
  short* vt  = kb + (size_t)NBH * NKPAD * DH;             // [96,64,1088] bf16
  short* wqt = vt + (size_t)NBH * DH * NKPAD;             // [2304,768] bf16
  short* wpt = wqt + (size_t)C3 * DIM;                    // [768,768] bf16
  float* ms  = (float*)(wpt + (size_t)DIM * DIM);         // [96,2] f32
  float* out = (float*)d_out;                             // [8200,768]
  float* map = out + (size_t)MROWS * DIM;                 // [8,1024]

  // 0) conversions
  convert_x_kernel<<<MPAD * DIM / 2048, 256, 0, stream>>>(x, xb);
  {
    dim3 grid(C3 / 64, DIM / 64);
    wtrans_kernel<<<grid, 256, 0, stream>>>(Wqkv, wqt, DIM, C3);
  }
  {
    dim3 grid(DIM / 64, DIM / 64);
    wtrans_kernel<<<grid, 256, 0, stream>>>(Wproj, wpt, DIM, DIM);
  }
  // 1) qkv = x @ Wqkv + bqkv   (bf16 MFMA)
  {
    dim3 grid(C3 / 128, MPAD / 128);
    gemm_bf16_kernel<<<grid, 256, 0, stream>>>(xb, wqt, bqkv, qkv, MROWS, C3, DIM);
  }
  // 2) LN on q,k (fp32 in-place + bf16 qb/kb)
  {
    int blocks = (MROWS * HEADS + 3) / 4;
    ln_qk_kernel<<<blocks, 256, 0, stream>>>(qkv, gq, betaq, gk, betak, qb, kb);
  }
  // 3) V transpose/convert
  {
    dim3 grid(17, NBH);
    vt_convert_kernel<<<grid, 256, 0, stream>>>(qkv, vt);
  }
  // 4) MFMA attention -> bf16 into xb (dead after step 1)
  {
    dim3 grid(QPAD / 128, NBH);
    attn_mfma_kernel<<<grid, 256, 0, stream>>>(qb, kb, vt, xb);
  }
  // 5) attn_map (exact fp32 path, two passes)
  map_ms_kernel<<<NBH, 256, 0, stream>>>(qkv, ms);
  {
    dim3 grid(4, BS);
    map_p_kernel<<<grid, 256, 0, stream>>>(qkv, ms, map);
  }
  // 6) out = attn_out @ Wproj + bproj   (bf16 MFMA)
  {
    dim3 grid(DIM / 128, MPAD / 128);
    gemm_bf16_kernel<<<grid, 256, 0, stream>>>(xb, wpt, bproj, out, MROWS, DIM, DIM);
  }
}

// Round 6
// 255.628 us; speedup vs baseline: 10.9094x; 1.0325x over previous
//
#include <hip/hip_runtime.h>
#include <hip/hip_bf16.h>
#include <math.h>

// Problem constants
#define BS   8
#define NSEQ 1025
#define DIM  768
#define C3   2304      // 3*DIM
#define HEADS 12
#define DH   64
#define MROWS (BS*NSEQ) // 8200
#define MPAD  8320      // 65*128, padded M for GEMM tiles
#define NKPAD 1088      // 17*64, padded key length for MFMA tiles
#define QPAD  1152      // 9*128, padded query length for attn blocks
#define NBH   (BS*HEADS)

// log2(e) folded into Q during LN so softmax uses exp2
#define QSCALE (0.125f * 1.44269504088896340736f)
#define SBOUND 10.0f    // fixed softmax offset (log2 domain); ratios unchanged

typedef __attribute__((ext_vector_type(8))) short bf16x8;
typedef __attribute__((ext_vector_type(4))) float f32x4;

static __device__ __forceinline__ unsigned short f2bf(float f) {
  unsigned int u = __float_as_uint(f);
  unsigned int r = (u + 0x7fffu + ((u >> 16) & 1u)) >> 16;
  return (unsigned short)r;
}

// packed f32x2 -> bf16x2 (RNE) in one instruction; low half = a, high = b
static __device__ __forceinline__ unsigned int cvtpk_bf16(float a, float b) {
  unsigned int r;
  asm("v_cvt_pk_bf16_f32 %0, %1, %2" : "=v"(r) : "v"(a), "v"(b));
  return r;
}

static __device__ __forceinline__ void gload16(const short* g, short* l) {
  __builtin_amdgcn_global_load_lds(
      (const __attribute__((address_space(1))) unsigned int*)g,
      (__attribute__((address_space(3))) unsigned int*)l, 16, 0, 0);
}

// ---------------------------------------------------------------------------
// x fp32 [MROWS][DIM] -> xb bf16 [MPAD][DIM], pad rows zeroed.
// ---------------------------------------------------------------------------
__global__ __launch_bounds__(256) void convert_x_kernel(
    const float* __restrict__ x, short* __restrict__ xb) {
  const size_t i = ((size_t)blockIdx.x * 256 + threadIdx.x) * 8;
  const size_t row = i / DIM;
  bf16x8 w;
  if (row < MROWS) {
    float4 v0 = *(const float4*)&x[i];
    float4 v1 = *(const float4*)&x[i + 4];
    w[0] = (short)f2bf(v0.x); w[1] = (short)f2bf(v0.y);
    w[2] = (short)f2bf(v0.z); w[3] = (short)f2bf(v0.w);
    w[4] = (short)f2bf(v1.x); w[5] = (short)f2bf(v1.y);
    w[6] = (short)f2bf(v1.z); w[7] = (short)f2bf(v1.w);
  } else {
    #pragma unroll
    for (int j = 0; j < 8; ++j) w[j] = 0;
  }
  *(bf16x8*)&xb[i] = w;
}

// ---------------------------------------------------------------------------
// W fp32 [K][N] -> Wt bf16 [N][K] (transpose + convert). Grid (N/64, K/64).
// ---------------------------------------------------------------------------
__global__ __launch_bounds__(256) void wtrans_kernel(
    const float* __restrict__ W, short* __restrict__ Wt, int K, int N) {
  const int n0 = blockIdx.x * 64, k0 = blockIdx.y * 64;
  __shared__ float tile[64][65];
  const int r = threadIdx.x >> 2;        // 0..63
  const int c0 = (threadIdx.x & 3) * 16; // 0,16,32,48
  const float* src = W + (size_t)(k0 + r) * N + n0 + c0;
  #pragma unroll
  for (int j = 0; j < 16; j += 4) {
    float4 v = *(const float4*)(src + j);
    tile[r][c0 + j]     = v.x;
    tile[r][c0 + j + 1] = v.y;
    tile[r][c0 + j + 2] = v.z;
    tile[r][c0 + j + 3] = v.w;
  }
  __syncthreads();
  bf16x8 w0, w1;
  #pragma unroll
  for (int j = 0; j < 8; ++j) {
    w0[j] = (short)f2bf(tile[c0 + j][r]);
    w1[j] = (short)f2bf(tile[c0 + 8 + j][r]);
  }
  short* dst = Wt + (size_t)(n0 + r) * K + k0 + c0;
  *(bf16x8*)dst = w0;
  *(bf16x8*)(dst + 8) = w1;
}

// ---------------------------------------------------------------------------
// bf16 MFMA GEMM: C[M,N] f32 = A[Mp,K]bf16 . Bt[N,K]bf16^T + bias[N].
// 128x128 tile, BK=64, 4 waves (2x2), global_load_lds staging (m97 structure).
// ---------------------------------------------------------------------------
__global__ __launch_bounds__(256) void gemm_bf16_kernel(
    const short* __restrict__ A, const short* __restrict__ Bt,
    const float* __restrict__ bias, float* __restrict__ C,
    int M, int N, int K) {
  __shared__ short As[128 * 64];
  __shared__ short Bs[128 * 64];
  const int tid = threadIdx.x;
  const int wid = tid >> 6, lane = tid & 63;
  const int lo = lane & 15, hi = lane >> 4;
  const int wr = wid >> 1, wc = wid & 1;
  const int m0 = blockIdx.y * 128, n0 = blockIdx.x * 128;
  const int rl = lane >> 3;            // 0..7
  const int cb = (lane & 7) * 8;       // bf16 col offset within 64

  f32x4 acc[4][4];
  #pragma unroll
  for (int m = 0; m < 4; ++m)
    #pragma unroll
    for (int n = 0; n < 4; ++n)
      acc[m][n][0] = acc[m][n][1] = acc[m][n][2] = acc[m][n][3] = 0.f;

  const short* Abase = A + (size_t)(m0 + wid * 32 + rl) * K + cb;
  const short* Bbase = Bt + (size_t)(n0 + wid * 32 + rl) * K + cb;

  for (int k0 = 0; k0 < K; k0 += 64) {
    #pragma unroll
    for (int i = 0; i < 4; ++i) {
      gload16(Abase + (size_t)(i * 8) * K + k0, &As[(wid * 32 + i * 8) * 64]);
      gload16(Bbase + (size_t)(i * 8) * K + k0, &Bs[(wid * 32 + i * 8) * 64]);
    }
    __syncthreads();
    #pragma unroll
    for (int kk = 0; kk < 2; ++kk) {
      bf16x8 a[4], bfr[4];
      #pragma unroll
      for (int m = 0; m < 4; ++m)
        a[m] = *(const bf16x8*)&As[(wr * 64 + m * 16 + lo) * 64 + kk * 32 + hi * 8];
      #pragma unroll
      for (int n = 0; n < 4; ++n)
        bfr[n] = *(const bf16x8*)&Bs[(wc * 64 + n * 16 + lo) * 64 + kk * 32 + hi * 8];
      #pragma unroll
      for (int m = 0; m < 4; ++m)
        #pragma unroll
        for (int n = 0; n < 4; ++n)
          acc[m][n] = __builtin_amdgcn_mfma_f32_16x16x32_bf16(a[m], bfr[n], acc[m][n], 0, 0, 0);
    }
    __syncthreads();
  }

  #pragma unroll
  for (int m = 0; m < 4; ++m) {
    #pragma unroll
    for (int r = 0; r < 4; ++r) {
      const int grow = m0 + wr * 64 + m * 16 + hi * 4 + r;
      if (grow < M) {
        float* cp = C + (size_t)grow * N + n0 + wc * 64 + lo;
        const float* bp = bias + n0 + wc * 64 + lo;
        #pragma unroll
        for (int n = 0; n < 4; ++n) cp[n * 16] = acc[m][n][r] + bp[n * 16];
      }
    }
  }
}

// ---------------------------------------------------------------------------
// In-place LayerNorm on q and k of qkv[M, 2304]; Q scaled by 0.125*log2e.
// bf16 copies: qb [bh][QPAD][64], kb [bh][NKPAD][64].
// ---------------------------------------------------------------------------
__global__ __launch_bounds__(256) void ln_qk_kernel(
    float* __restrict__ qkv,
    const float* __restrict__ gq, const float* __restrict__ bq,
    const float* __restrict__ gk, const float* __restrict__ bk,
    short* __restrict__ qb, short* __restrict__ kb) {
  const int task = blockIdx.x * 4 + (threadIdx.x >> 6);
  const int lane = threadIdx.x & 63;
  const int TASKS = MROWS * HEADS;
  if (task >= TASKS) return;
  const int row = task / HEADS;
  const int h = task - row * HEADS;
  const size_t base = (size_t)row * C3 + h * DH;
  float xq = qkv[base + lane];
  float xk = qkv[base + DIM + lane];
  float sq = xq, s2q = xq * xq, sk = xk, s2k = xk * xk;
  #pragma unroll
  for (int off = 32; off; off >>= 1) {
    sq  += __shfl_xor(sq,  off);
    s2q += __shfl_xor(s2q, off);
    sk  += __shfl_xor(sk,  off);
    s2k += __shfl_xor(s2k, off);
  }
  const float inv64 = 1.f / 64.f;
  float mq = sq * inv64, vq = s2q * inv64 - mq * mq;
  float mk = sk * inv64, vk = s2k * inv64 - mk * mk;
  float rq = rsqrtf(vq + 1e-5f), rk = rsqrtf(vk + 1e-5f);
  float qn = ((xq - mq) * rq * gq[lane] + bq[lane]) * QSCALE;
  float kn =  (xk - mk) * rk * gk[lane] + bk[lane];
  qkv[base + lane]       = qn;
  qkv[base + DIM + lane] = kn;
  const int b = row / NSEQ;
  const int n = row - b * NSEQ;
  const int bh = b * HEADS + h;
  qb[((size_t)bh * QPAD  + n) * DH + lane] = (short)f2bf(qn);
  kb[((size_t)bh * NKPAD + n) * DH + lane] = (short)f2bf(kn);
}

// ---------------------------------------------------------------------------
// V convert+transpose: qkv v-part fp32 -> vt bf16 [bh][d][NKPAD] (zero pad).
// Grid: (17, 96), 256 threads.
// ---------------------------------------------------------------------------
__global__ __launch_bounds__(256) void vt_convert_kernel(
    const float* __restrict__ qkv, short* __restrict__ vt) {
  const int kt = blockIdx.x;     // key tile 0..16
  const int bh = blockIdx.y;     // 0..95
  const int b = bh / HEADS, h = bh - (bh / HEADS) * HEADS;
  const int t = threadIdx.x;
  __shared__ float tile[64][65];
  const int r = t >> 2;          // 0..63
  const int c0 = (t & 3) * 16;   // 0,16,32,48
  const int grow = kt * 64 + r;  // key index 0..1087

  const float* src = qkv + (size_t)(b * NSEQ + grow) * C3 + 2 * DIM + h * DH + c0;
  #pragma unroll
  for (int j = 0; j < 16; j += 4) {
    float4 v = (grow < NSEQ) ? *(const float4*)(src + j)
                             : make_float4(0.f, 0.f, 0.f, 0.f);
    tile[r][c0 + j]     = v.x;
    tile[r][c0 + j + 1] = v.y;
    tile[r][c0 + j + 2] = v.z;
    tile[r][c0 + j + 3] = v.w;
  }
  __syncthreads();
  bf16x8 w0, w1;
  #pragma unroll
  for (int j = 0; j < 8; ++j) {
    w0[j] = (short)f2bf(tile[c0 + j][r]);
    w1[j] = (short)f2bf(tile[c0 + 8 + j][r]);
  }
  short* dst = vt + ((size_t)bh * DH + r) * NKPAD + kt * 64 + c0;
  *(bf16x8*)dst = w0;
  *(bf16x8*)(dst + 8) = w1;
}

// ---------------------------------------------------------------------------
// MFMA bf16 flash attention v3: LDS-staged K/V, double-buffered, swizzled,
// XCD-local grid (bh on blockIdx.x: 96 % 8 == 0 keeps all 9 q-tiles of one
// (b,h) on one XCD -> K/V fetched from HBM once per XCD), cvt_pk P-convert,
// setprio around MFMA clusters.
// Block = 256 threads (4 waves); wave owns 32 query rows (2 m-frags).
// Grid: (96, QPAD/128 = 9). Output bf16 into ab[row][DIM].
// ---------------------------------------------------------------------------
__global__ __launch_bounds__(256) void attn_mfma_kernel(
    const short* __restrict__ qb, const short* __restrict__ kb,
    const short* __restrict__ vt, short* __restrict__ ab) {
  const int bh = blockIdx.x;
  const int b = bh / HEADS, h = bh - (bh / HEADS) * HEADS;
  const int wid = threadIdx.x >> 6;
  const int lane = threadIdx.x & 63;
  const int lo = lane & 15, hi = lane >> 4;
  const int q0 = blockIdx.y * 128;
  const int xsw = (lo & 7) << 3;          // read-side XOR swizzle (shorts)

  __shared__ short Ks[2][64 * 64];        // swizzled K tile  [key][d]
  __shared__ short Vs[2][64 * 64];        // swizzled V^T tile [d][key]
  __shared__ short Pb[4][32][72];         // per-wave P buffer

  const short* kg = kb + (size_t)bh * NKPAD * DH;
  const short* vg = vt + (size_t)bh * DH * NKPAD;

  // staging: linear LDS dest (wave-uniform base + lane*16), pre-swizzled
  // global source so that read-side XOR sees conflict-free banks.
  auto stage = [&](int bf, int kt) {
    #pragma unroll
    for (int i = 0; i < 2; ++i) {
      const int r = wid * 16 + i * 8 + (lane >> 3);
      const int sw = ((lane & 7) ^ (lane >> 3)) << 3;
      gload16(kg + (size_t)(kt * 64 + r) * DH + sw,
              &Ks[bf][wid * 1024 + i * 512]);
      gload16(vg + (size_t)r * NKPAD + kt * 64 + sw,
              &Vs[bf][wid * 1024 + i * 512]);
    }
  };

  // Q A-fragments: 2 m-tiles x 2 k-chunks
  bf16x8 aq[2][2];
  #pragma unroll
  for (int m = 0; m < 2; ++m) {
    const short* qp = qb + (size_t)bh * QPAD * DH
                    + (size_t)(q0 + wid * 32 + m * 16 + lo) * DH + hi * 8;
    aq[m][0] = *(const bf16x8*)qp;
    aq[m][1] = *(const bf16x8*)(qp + 32);
  }

  f32x4 o[2][4];
  float lsum[2][4];
  #pragma unroll
  for (int m = 0; m < 2; ++m)
    #pragma unroll
    for (int nt = 0; nt < 4; ++nt) {
      o[m][nt][0] = o[m][nt][1] = o[m][nt][2] = o[m][nt][3] = 0.f;
      lsum[m][nt] = 0.f;
    }

  stage(0, 0);
  __syncthreads();

  for (int kt = 0; kt < 17; ++kt) {
    const int bf = kt & 1;
    if (kt < 16) stage(bf ^ 1, kt + 1);   // async prefetch into other buffer

    // ---- QK^T ----
    f32x4 s[2][4];
    #pragma unroll
    for (int m = 0; m < 2; ++m)
      #pragma unroll
      for (int nt = 0; nt < 4; ++nt)
        s[m][nt][0] = s[m][nt][1] = s[m][nt][2] = s[m][nt][3] = 0.f;
    __builtin_amdgcn_s_setprio(1);
    #pragma unroll
    for (int kk = 0; kk < 2; ++kk) {
      bf16x8 kf[4];
      #pragma unroll
      for (int nt = 0; nt < 4; ++nt)
        kf[nt] = *(const bf16x8*)&Ks[bf][(nt * 16 + lo) * 64
                                         + ((kk * 32 + hi * 8) ^ xsw)];
      #pragma unroll
      for (int m = 0; m < 2; ++m)
        #pragma unroll
        for (int nt = 0; nt < 4; ++nt)
          s[m][nt] = __builtin_amdgcn_mfma_f32_16x16x32_bf16(
              aq[m][kk], kf[nt], s[m][nt], 0, 0, 0);
    }
    __builtin_amdgcn_s_setprio(0);
    if (kt == 16) {   // mask keys >= 1025 (key index 1024 + nt*16+lo)
      #pragma unroll
      for (int m = 0; m < 2; ++m)
        #pragma unroll
        for (int nt = 0; nt < 4; ++nt)
          if (nt * 16 + lo >= 1)
            s[m][nt][0] = s[m][nt][1] = s[m][nt][2] = s[m][nt][3] = -1e30f;
    }
    // ---- softmax (fixed offset) + P staging (packed bf16 convert) ----
    #pragma unroll
    for (int m = 0; m < 2; ++m)
      #pragma unroll
      for (int nt = 0; nt < 4; ++nt) {
        float p0 = exp2f(s[m][nt][0] - SBOUND);
        float p1 = exp2f(s[m][nt][1] - SBOUND);
        float p2 = exp2f(s[m][nt][2] - SBOUND);
        float p3 = exp2f(s[m][nt][3] - SBOUND);
        lsum[m][0] += p0; lsum[m][1] += p1;
        lsum[m][2] += p2; lsum[m][3] += p3;
        unsigned int c01 = cvtpk_bf16(p0, p1);
        unsigned int c23 = cvtpk_bf16(p2, p3);
        unsigned short* pb = (unsigned short*)&Pb[wid][m * 16 + 4 * hi][nt * 16 + lo];
        pb[0]       = (unsigned short)c01;
        pb[72]      = (unsigned short)(c01 >> 16);
        pb[144]     = (unsigned short)c23;
        pb[216]     = (unsigned short)(c23 >> 16);
      }
    // ---- PV ----
    __builtin_amdgcn_s_setprio(1);
    #pragma unroll
    for (int ks = 0; ks < 2; ++ks) {
      bf16x8 pa0 = *(const bf16x8*)&Pb[wid][lo][ks * 32 + hi * 8];
      bf16x8 pa1 = *(const bf16x8*)&Pb[wid][16 + lo][ks * 32 + hi * 8];
      #pragma unroll
      for (int nt = 0; nt < 4; ++nt) {
        bf16x8 vf = *(const bf16x8*)&Vs[bf][(nt * 16 + lo) * 64
                                            + ((ks * 32 + hi * 8) ^ xsw)];
        o[0][nt] = __builtin_amdgcn_mfma_f32_16x16x32_bf16(pa0, vf, o[0][nt], 0, 0, 0);
        o[1][nt] = __builtin_amdgcn_mfma_f32_16x16x32_bf16(pa1, vf, o[1][nt], 0, 0, 0);
      }
    }
    __builtin_amdgcn_s_setprio(0);
    __syncthreads();   // drains vmcnt (prefetch) + all waves done with bf
  }

  #pragma unroll
  for (int m = 0; m < 2; ++m)
    #pragma unroll
    for (int r = 0; r < 4; ++r) {
      float v = lsum[m][r];
      v += __shfl_xor(v, 1);
      v += __shfl_xor(v, 2);
      v += __shfl_xor(v, 4);
      v += __shfl_xor(v, 8);
      lsum[m][r] = v;
    }
  #pragma unroll
  for (int m = 0; m < 2; ++m)
    #pragma unroll
    for (int r = 0; r < 4; ++r) {
      const int qrow = q0 + wid * 32 + m * 16 + 4 * hi + r;
      if (qrow < NSEQ) {
        const float inv = 1.f / lsum[m][r];
        short* op = ab + (size_t)(b * NSEQ + qrow) * DIM + h * DH + lo;
        #pragma unroll
        for (int nt = 0; nt < 4; ++nt)
          op[nt * 16] = (short)f2bf(o[m][nt][r] * inv);
      }
    }
}

// ---------------------------------------------------------------------------
// attn_map pass A: per-(b,h) row-0 softmax max & inv-denominator.
// Grid 96, 256 threads. ms[bh] = {max, 1/(sum*HEADS)}.
// ---------------------------------------------------------------------------
__global__ __launch_bounds__(256) void map_ms_kernel(
    const float* __restrict__ qkv, float* __restrict__ ms) {
  const int bh = blockIdx.x;
  const int b = bh / HEADS, h = bh - (bh / HEADS) * HEADS;
  const int tid = threadIdx.x;
  __shared__ float q0s[64];
  __shared__ float red[256];
  const size_t rowbase = (size_t)b * NSEQ;
  if (tid < 64) q0s[tid] = qkv[rowbase * C3 + h * DH + tid];
  __syncthreads();
  float s[5];
  float lm = -INFINITY;
  #pragma unroll
  for (int sl = 0; sl < 5; ++sl) {
    int j = tid + sl * 256;
    s[sl] = -INFINITY;
    if (j < NSEQ) {
      const float* kp = &qkv[(rowbase + j) * C3 + DIM + h * DH];
      float d0 = 0.f;
      #pragma unroll
      for (int d = 0; d < 64; d += 4) {
        float4 kv = *(const float4*)&kp[d];
        d0 += q0s[d] * kv.x + q0s[d + 1] * kv.y + q0s[d + 2] * kv.z + q0s[d + 3] * kv.w;
      }
      s[sl] = d0;
      lm = fmaxf(lm, d0);
    }
  }
  red[tid] = lm; __syncthreads();
  for (int off = 128; off > 0; off >>= 1) {
    if (tid < off) red[tid] = fmaxf(red[tid], red[tid + off]);
    __syncthreads();
  }
  const float Mx = red[0]; __syncthreads();
  float ls = 0.f;
  #pragma unroll
  for (int sl = 0; sl < 5; ++sl) {
    int j = tid + sl * 256;
    if (j < NSEQ) ls += exp2f(s[sl] - Mx);
  }
  red[tid] = ls; __syncthreads();
  for (int off = 128; off > 0; off >>= 1) {
    if (tid < off) red[tid] += red[tid + off];
    __syncthreads();
  }
  if (tid == 0) {
    ms[bh * 2]     = Mx;
    ms[bh * 2 + 1] = 1.f / (red[0] * (float)HEADS);
  }
}

// ---------------------------------------------------------------------------
// attn_map pass B: map[b][j-1] = sum_h exp2(q0_h . k_jh - M_h) * inv_h.
// Grid (4, 8), 256 threads; thread handles one (b, j).
// ---------------------------------------------------------------------------
__global__ __launch_bounds__(256) void map_p_kernel(
    const float* __restrict__ qkv, const float* __restrict__ ms,
    float* __restrict__ map) {
  const int b = blockIdx.y;
  const int j = blockIdx.x * 256 + threadIdx.x + 1;   // 1..1024
  const int tid = threadIdx.x;
  __shared__ float q0s[768];
  __shared__ float msb[24];
  const size_t rowbase = (size_t)b * NSEQ;
  for (int idx = tid; idx < 768; idx += 256) q0s[idx] = qkv[rowbase * C3 + idx];
  if (tid < 24) msb[tid] = ms[b * HEADS * 2 + tid];
  __syncthreads();
  const float* kp = &qkv[(rowbase + j) * C3 + DIM];
  float acc = 0.f;
  #pragma unroll
  for (int h = 0; h < HEADS; ++h) {
    float d0 = 0.f;
    #pragma unroll
    for (int d = 0; d < 64; d += 4) {
      float4 kv = *(const float4*)&kp[h * DH + d];
      const float* qp = &q0s[h * DH + d];
      d0 += qp[0] * kv.x + qp[1] * kv.y + qp[2] * kv.z + qp[3] * kv.w;
    }
    acc += exp2f(d0 - msb[h * 2]) * msb[h * 2 + 1];
  }
  map[(size_t)b * (NSEQ - 1) + j - 1] = acc;
}

// ---------------------------------------------------------------------------
extern "C" void kernel_launch(void* const* d_in, const int* in_sizes, int n_in,
                              void* d_out, int out_size, void* d_ws, size_t ws_size,
                              hipStream_t stream) {
  const float* x     = (const float*)d_in[0];
  const float* Wqkv  = (const float*)d_in[1];
  const float* bqkv  = (const float*)d_in[2];
  const float* Wproj = (const float*)d_in[3];
  const float* bproj = (const float*)d_in[4];
  const float* gq    = (const float*)d_in[5];
  const float* betaq = (const float*)d_in[6];
  const float* gk    = (const float*)d_in[7];
  const float* betak = (const float*)d_in[8];

  float* qkv = (float*)d_ws;                              // [8200,2304] f32
  short* xb  = (short*)(qkv + (size_t)MROWS * C3);        // [8320,768] bf16 (reused as attn out)
  short* qb  = xb + (size_t)MPAD * DIM;                   // [96,1152,64] bf16
  short* kb  = qb + (size_t)NBH * QPAD * DH;              // [96,1088,64] bf16
  short* vt  = kb + (size_t)NBH * NKPAD * DH;             // [96,64,1088] bf16
  short* wqt = vt + (size_t)NBH * DH * NKPAD;             // [2304,768] bf16
  short* wpt = wqt + (size_t)C3 * DIM;                    // [768,768] bf16
  float* ms  = (float*)(wpt + (size_t)DIM * DIM);         // [96,2] f32
  float* out = (float*)d_out;                             // [8200,768]
  float* map = out + (size_t)MROWS * DIM;                 // [8,1024]

  // 0) conversions
  convert_x_kernel<<<MPAD * DIM / 2048, 256, 0, stream>>>(x, xb);
  {
    dim3 grid(C3 / 64, DIM / 64);
    wtrans_kernel<<<grid, 256, 0, stream>>>(Wqkv, wqt, DIM, C3);
  }
  {
    dim3 grid(DIM / 64, DIM / 64);
    wtrans_kernel<<<grid, 256, 0, stream>>>(Wproj, wpt, DIM, DIM);
  }
  // 1) qkv = x @ Wqkv + bqkv   (bf16 MFMA)
  {
    dim3 grid(C3 / 128, MPAD / 128);
    gemm_bf16_kernel<<<grid, 256, 0, stream>>>(xb, wqt, bqkv, qkv, MROWS, C3, DIM);
  }
  // 2) LN on q,k (fp32 in-place + bf16 qb/kb)
  {
    int blocks = (MROWS * HEADS + 3) / 4;
    ln_qk_kernel<<<blocks, 256, 0, stream>>>(qkv, gq, betaq, gk, betak, qb, kb);
  }
  // 3) V transpose/convert
  {
    dim3 grid(17, NBH);
    vt_convert_kernel<<<grid, 256, 0, stream>>>(qkv, vt);
  }
  // 4) MFMA attention -> bf16 into xb (dead after step 1)
  {
    dim3 grid(NBH, QPAD / 128);
    attn_mfma_kernel<<<grid, 256, 0, stream>>>(qb, kb, vt, xb);
  }
  // 5) attn_map (exact fp32 path, two passes)
  map_ms_kernel<<<NBH, 256, 0, stream>>>(qkv, ms);
  {
    dim3 grid(4, BS);
    map_p_kernel<<<grid, 256, 0, stream>>>(qkv, ms, map);
  }
  // 6) out = attn_out @ Wproj + bproj   (bf16 MFMA)
  {
    dim3 grid(DIM / 128, MPAD / 128);
    gemm_bf16_kernel<<<grid, 256, 0, stream>>>(xb, wpt, bproj, out, MROWS, DIM, DIM);
  }
}

// Round 9
// 254.768 us; speedup vs baseline: 10.9462x; 1.0034x over previous
//
#include <hip/hip_runtime.h>
#include <hip/hip_bf16.h>
#include <math.h>

// Problem constants
#define BS   8
#define NSEQ 1025
#define DIM  768
#define C3   2304      // 3*DIM
#define HEADS 12
#define DH   64
#define MROWS (BS*NSEQ) // 8200
#define MPAD  8320      // 65*128, padded M for GEMM tiles
#define NKPAD 1088      // 17*64, padded key length for MFMA tiles
#define QPAD  1152      // 9*128, padded query length for attn blocks
#define NBH   (BS*HEADS)

// log2(e) folded into Q during LN so softmax uses exp2
#define QSCALE (0.125f * 1.44269504088896340736f)
#define SBOUND 10.0f    // fixed softmax offset (log2 domain); ratios unchanged

typedef __attribute__((ext_vector_type(8))) short bf16x8;
typedef __attribute__((ext_vector_type(4))) float f32x4;

static __device__ __forceinline__ unsigned short f2bf(float f) {
  unsigned int u = __float_as_uint(f);
  unsigned int r = (u + 0x7fffu + ((u >> 16) & 1u)) >> 16;
  return (unsigned short)r;
}

// packed f32x2 -> bf16x2 (RNE) in one instruction; low half = a, high = b
static __device__ __forceinline__ unsigned int cvtpk_bf16(float a, float b) {
  unsigned int r;
  asm("v_cvt_pk_bf16_f32 %0, %1, %2" : "=v"(r) : "v"(a), "v"(b));
  return r;
}

static __device__ __forceinline__ void gload16(const short* g, short* l) {
  __builtin_amdgcn_global_load_lds(
      (const __attribute__((address_space(1))) unsigned int*)g,
      (__attribute__((address_space(3))) unsigned int*)l, 16, 0, 0);
}

// ---------------------------------------------------------------------------
// x fp32 [MROWS][DIM] -> xb bf16 [MPAD][DIM], pad rows zeroed.
// ---------------------------------------------------------------------------
__global__ __launch_bounds__(256) void convert_x_kernel(
    const float* __restrict__ x, short* __restrict__ xb) {
  const size_t i = ((size_t)blockIdx.x * 256 + threadIdx.x) * 8;
  const size_t row = i / DIM;
  bf16x8 w;
  if (row < MROWS) {
    float4 v0 = *(const float4*)&x[i];
    float4 v1 = *(const float4*)&x[i + 4];
    w[0] = (short)f2bf(v0.x); w[1] = (short)f2bf(v0.y);
    w[2] = (short)f2bf(v0.z); w[3] = (short)f2bf(v0.w);
    w[4] = (short)f2bf(v1.x); w[5] = (short)f2bf(v1.y);
    w[6] = (short)f2bf(v1.z); w[7] = (short)f2bf(v1.w);
  } else {
    #pragma unroll
    for (int j = 0; j < 8; ++j) w[j] = 0;
  }
  *(bf16x8*)&xb[i] = w;
}

// ---------------------------------------------------------------------------
// W fp32 [K][N] -> Wt bf16 [N][K] (transpose + convert). Grid (N/64, K/64).
// ---------------------------------------------------------------------------
__global__ __launch_bounds__(256) void wtrans_kernel(
    const float* __restrict__ W, short* __restrict__ Wt, int K, int N) {
  const int n0 = blockIdx.x * 64, k0 = blockIdx.y * 64;
  __shared__ float tile[64][65];
  const int r = threadIdx.x >> 2;        // 0..63
  const int c0 = (threadIdx.x & 3) * 16; // 0,16,32,48
  const float* src = W + (size_t)(k0 + r) * N + n0 + c0;
  #pragma unroll
  for (int j = 0; j < 16; j += 4) {
    float4 v = *(const float4*)(src + j);
    tile[r][c0 + j]     = v.x;
    tile[r][c0 + j + 1] = v.y;
    tile[r][c0 + j + 2] = v.z;
    tile[r][c0 + j + 3] = v.w;
  }
  __syncthreads();
  bf16x8 w0, w1;
  #pragma unroll
  for (int j = 0; j < 8; ++j) {
    w0[j] = (short)f2bf(tile[c0 + j][r]);
    w1[j] = (short)f2bf(tile[c0 + 8 + j][r]);
  }
  short* dst = Wt + (size_t)(n0 + r) * K + k0 + c0;
  *(bf16x8*)dst = w0;
  *(bf16x8*)(dst + 8) = w1;
}

// ---------------------------------------------------------------------------
// bf16 MFMA GEMM: C[M,N] f32 = A[Mp,K]bf16 . Bt[N,K]bf16^T + bias[N].
// 128x128 tile, BK=64, 4 waves (2x2), global_load_lds staging (m97 structure).
// XCD-chunked bijective block swizzle (m204): value-identical, L2-local.
// ---------------------------------------------------------------------------
__global__ __launch_bounds__(256) void gemm_bf16_kernel(
    const short* __restrict__ A, const short* __restrict__ Bt,
    const float* __restrict__ bias, float* __restrict__ C,
    int M, int N, int K) {
  __shared__ short As[128 * 64];
  __shared__ short Bs[128 * 64];
  const int tid = threadIdx.x;
  const int wid = tid >> 6, lane = tid & 63;
  const int lo = lane & 15, hi = lane >> 4;
  const int wr = wid >> 1, wc = wid & 1;

  // bijective XCD-chunk remap (m204): consecutive hardware ids round-robin
  // the 8 XCDs; give each XCD a contiguous chunk of tile-space instead.
  const int nwg = gridDim.x * gridDim.y;
  int bid = blockIdx.y * gridDim.x + blockIdx.x;
  {
    const int q = nwg >> 3, rr = nwg & 7;
    const int xcd = bid & 7, idx = bid >> 3;
    bid = (xcd < rr ? xcd * (q + 1) : rr * (q + 1) + (xcd - rr) * q) + idx;
  }
  const int m0 = (bid / gridDim.x) * 128, n0 = (bid % gridDim.x) * 128;

  const int rl = lane >> 3;            // 0..7
  const int cb = (lane & 7) * 8;       // bf16 col offset within 64

  f32x4 acc[4][4];
  #pragma unroll
  for (int m = 0; m < 4; ++m)
    #pragma unroll
    for (int n = 0; n < 4; ++n)
      acc[m][n][0] = acc[m][n][1] = acc[m][n][2] = acc[m][n][3] = 0.f;

  const short* Abase = A + (size_t)(m0 + wid * 32 + rl) * K + cb;
  const short* Bbase = Bt + (size_t)(n0 + wid * 32 + rl) * K + cb;

  for (int k0 = 0; k0 < K; k0 += 64) {
    #pragma unroll
    for (int i = 0; i < 4; ++i) {
      gload16(Abase + (size_t)(i * 8) * K + k0, &As[(wid * 32 + i * 8) * 64]);
      gload16(Bbase + (size_t)(i * 8) * K + k0, &Bs[(wid * 32 + i * 8) * 64]);
    }
    __syncthreads();
    #pragma unroll
    for (int kk = 0; kk < 2; ++kk) {
      bf16x8 a[4], bfr[4];
      #pragma unroll
      for (int m = 0; m < 4; ++m)
        a[m] = *(const bf16x8*)&As[(wr * 64 + m * 16 + lo) * 64 + kk * 32 + hi * 8];
      #pragma unroll
      for (int n = 0; n < 4; ++n)
        bfr[n] = *(const bf16x8*)&Bs[(wc * 64 + n * 16 + lo) * 64 + kk * 32 + hi * 8];
      #pragma unroll
      for (int m = 0; m < 4; ++m)
        #pragma unroll
        for (int n = 0; n < 4; ++n)
          acc[m][n] = __builtin_amdgcn_mfma_f32_16x16x32_bf16(a[m], bfr[n], acc[m][n], 0, 0, 0);
    }
    __syncthreads();
  }

  #pragma unroll
  for (int m = 0; m < 4; ++m) {
    #pragma unroll
    for (int r = 0; r < 4; ++r) {
      const int grow = m0 + wr * 64 + m * 16 + hi * 4 + r;
      if (grow < M) {
        float* cp = C + (size_t)grow * N + n0 + wc * 64 + lo;
        const float* bp = bias + n0 + wc * 64 + lo;
        #pragma unroll
        for (int n = 0; n < 4; ++n) cp[n * 16] = acc[m][n][r] + bp[n * 16];
      }
    }
  }
}

// ---------------------------------------------------------------------------
// In-place LayerNorm on q and k of qkv[M, 2304]; Q scaled by 0.125*log2e.
// bf16 copies: qb [bh][QPAD][64], kb [bh][NKPAD][64].
// ---------------------------------------------------------------------------
__global__ __launch_bounds__(256) void ln_qk_kernel(
    float* __restrict__ qkv,
    const float* __restrict__ gq, const float* __restrict__ bq,
    const float* __restrict__ gk, const float* __restrict__ bk,
    short* __restrict__ qb, short* __restrict__ kb) {
  const int task = blockIdx.x * 4 + (threadIdx.x >> 6);
  const int lane = threadIdx.x & 63;
  const int TASKS = MROWS * HEADS;
  if (task >= TASKS) return;
  const int row = task / HEADS;
  const int h = task - row * HEADS;
  const size_t base = (size_t)row * C3 + h * DH;
  float xq = qkv[base + lane];
  float xk = qkv[base + DIM + lane];
  float sq = xq, s2q = xq * xq, sk = xk, s2k = xk * xk;
  #pragma unroll
  for (int off = 32; off; off >>= 1) {
    sq  += __shfl_xor(sq,  off);
    s2q += __shfl_xor(s2q, off);
    sk  += __shfl_xor(sk,  off);
    s2k += __shfl_xor(s2k, off);
  }
  const float inv64 = 1.f / 64.f;
  float mq = sq * inv64, vq = s2q * inv64 - mq * mq;
  float mk = sk * inv64, vk = s2k * inv64 - mk * mk;
  float rq = rsqrtf(vq + 1e-5f), rk = rsqrtf(vk + 1e-5f);
  float qn = ((xq - mq) * rq * gq[lane] + bq[lane]) * QSCALE;
  float kn =  (xk - mk) * rk * gk[lane] + bk[lane];
  qkv[base + lane]       = qn;
  qkv[base + DIM + lane] = kn;
  const int b = row / NSEQ;
  const int n = row - b * NSEQ;
  const int bh = b * HEADS + h;
  qb[((size_t)bh * QPAD  + n) * DH + lane] = (short)f2bf(qn);
  kb[((size_t)bh * NKPAD + n) * DH + lane] = (short)f2bf(kn);
}

// ---------------------------------------------------------------------------
// V convert+transpose: qkv v-part fp32 -> vt bf16 [bh][d][NKPAD] (zero pad).
// Grid: (17, 96), 256 threads.
// ---------------------------------------------------------------------------
__global__ __launch_bounds__(256) void vt_convert_kernel(
    const float* __restrict__ qkv, short* __restrict__ vt) {
  const int kt = blockIdx.x;     // key tile 0..16
  const int bh = blockIdx.y;     // 0..95
  const int b = bh / HEADS, h = bh - (bh / HEADS) * HEADS;
  const int t = threadIdx.x;
  __shared__ float tile[64][65];
  const int r = t >> 2;          // 0..63
  const int c0 = (t & 3) * 16;   // 0,16,32,48
  const int grow = kt * 64 + r;  // key index 0..1087

  const float* src = qkv + (size_t)(b * NSEQ + grow) * C3 + 2 * DIM + h * DH + c0;
  #pragma unroll
  for (int j = 0; j < 16; j += 4) {
    float4 v = (grow < NSEQ) ? *(const float4*)(src + j)
                             : make_float4(0.f, 0.f, 0.f, 0.f);
    tile[r][c0 + j]     = v.x;
    tile[r][c0 + j + 1] = v.y;
    tile[r][c0 + j + 2] = v.z;
    tile[r][c0 + j + 3] = v.w;
  }
  __syncthreads();
  bf16x8 w0, w1;
  #pragma unroll
  for (int j = 0; j < 8; ++j) {
    w0[j] = (short)f2bf(tile[c0 + j][r]);
    w1[j] = (short)f2bf(tile[c0 + 8 + j][r]);
  }
  short* dst = vt + ((size_t)bh * DH + r) * NKPAD + kt * 64 + c0;
  *(bf16x8*)dst = w0;
  *(bf16x8*)(dst + 8) = w1;
}

// ---------------------------------------------------------------------------
// MFMA bf16 flash attention (R6-proven): LDS-staged K/V, double-buffered,
// swizzled, XCD-local grid, cvt_pk P-convert, setprio on MFMA clusters.
// Block = 256 threads (4 waves); wave owns 32 query rows (2 m-frags).
// Grid: (96, QPAD/128 = 9). Output bf16 into ab[row][DIM].
// ---------------------------------------------------------------------------
__global__ __launch_bounds__(256) void attn_mfma_kernel(
    const short* __restrict__ qb, const short* __restrict__ kb,
    const short* __restrict__ vt, short* __restrict__ ab) {
  const int bh = blockIdx.x;
  const int b = bh / HEADS, h = bh - (bh / HEADS) * HEADS;
  const int wid = threadIdx.x >> 6;
  const int lane = threadIdx.x & 63;
  const int lo = lane & 15, hi = lane >> 4;
  const int q0 = blockIdx.y * 128;
  const int xsw = (lo & 7) << 3;          // read-side XOR swizzle (shorts)

  __shared__ short Ks[2][64 * 64];        // swizzled K tile  [key][d]
  __shared__ short Vs[2][64 * 64];        // swizzled V^T tile [d][key]
  __shared__ short Pb[4][32][72];         // per-wave P buffer

  const short* kg = kb + (size_t)bh * NKPAD * DH;
  const short* vg = vt + (size_t)bh * DH * NKPAD;

  auto stage = [&](int bf, int kt) {
    #pragma unroll
    for (int i = 0; i < 2; ++i) {
      const int r = wid * 16 + i * 8 + (lane >> 3);
      const int sw = ((lane & 7) ^ (lane >> 3)) << 3;
      gload16(kg + (size_t)(kt * 64 + r) * DH + sw,
              &Ks[bf][wid * 1024 + i * 512]);
      gload16(vg + (size_t)r * NKPAD + kt * 64 + sw,
              &Vs[bf][wid * 1024 + i * 512]);
    }
  };

  bf16x8 aq[2][2];
  #pragma unroll
  for (int m = 0; m < 2; ++m) {
    const short* qp = qb + (size_t)bh * QPAD * DH
                    + (size_t)(q0 + wid * 32 + m * 16 + lo) * DH + hi * 8;
    aq[m][0] = *(const bf16x8*)qp;
    aq[m][1] = *(const bf16x8*)(qp + 32);
  }

  f32x4 o[2][4];
  float lsum[2][4];
  #pragma unroll
  for (int m = 0; m < 2; ++m)
    #pragma unroll
    for (int nt = 0; nt < 4; ++nt) {
      o[m][nt][0] = o[m][nt][1] = o[m][nt][2] = o[m][nt][3] = 0.f;
      lsum[m][nt] = 0.f;
    }

  stage(0, 0);
  __syncthreads();

  for (int kt = 0; kt < 17; ++kt) {
    const int bf = kt & 1;
    if (kt < 16) stage(bf ^ 1, kt + 1);

    f32x4 s[2][4];
    #pragma unroll
    for (int m = 0; m < 2; ++m)
      #pragma unroll
      for (int nt = 0; nt < 4; ++nt)
        s[m][nt][0] = s[m][nt][1] = s[m][nt][2] = s[m][nt][3] = 0.f;
    __builtin_amdgcn_s_setprio(1);
    #pragma unroll
    for (int kk = 0; kk < 2; ++kk) {
      bf16x8 kf[4];
      #pragma unroll
      for (int nt = 0; nt < 4; ++nt)
        kf[nt] = *(const bf16x8*)&Ks[bf][(nt * 16 + lo) * 64
                                         + ((kk * 32 + hi * 8) ^ xsw)];
      #pragma unroll
      for (int m = 0; m < 2; ++m)
        #pragma unroll
        for (int nt = 0; nt < 4; ++nt)
          s[m][nt] = __builtin_amdgcn_mfma_f32_16x16x32_bf16(
              aq[m][kk], kf[nt], s[m][nt], 0, 0, 0);
    }
    __builtin_amdgcn_s_setprio(0);
    if (kt == 16) {
      #pragma unroll
      for (int m = 0; m < 2; ++m)
        #pragma unroll
        for (int nt = 0; nt < 4; ++nt)
          if (nt * 16 + lo >= 1)
            s[m][nt][0] = s[m][nt][1] = s[m][nt][2] = s[m][nt][3] = -1e30f;
    }
    #pragma unroll
    for (int m = 0; m < 2; ++m)
      #pragma unroll
      for (int nt = 0; nt < 4; ++nt) {
        float p0 = exp2f(s[m][nt][0] - SBOUND);
        float p1 = exp2f(s[m][nt][1] - SBOUND);
        float p2 = exp2f(s[m][nt][2] - SBOUND);
        float p3 = exp2f(s[m][nt][3] - SBOUND);
        lsum[m][0] += p0; lsum[m][1] += p1;
        lsum[m][2] += p2; lsum[m][3] += p3;
        unsigned int c01 = cvtpk_bf16(p0, p1);
        unsigned int c23 = cvtpk_bf16(p2, p3);
        unsigned short* pb = (unsigned short*)&Pb[wid][m * 16 + 4 * hi][nt * 16 + lo];
        pb[0]       = (unsigned short)c01;
        pb[72]      = (unsigned short)(c01 >> 16);
        pb[144]     = (unsigned short)c23;
        pb[216]     = (unsigned short)(c23 >> 16);
      }
    __builtin_amdgcn_s_setprio(1);
    #pragma unroll
    for (int ks = 0; ks < 2; ++ks) {
      bf16x8 pa0 = *(const bf16x8*)&Pb[wid][lo][ks * 32 + hi * 8];
      bf16x8 pa1 = *(const bf16x8*)&Pb[wid][16 + lo][ks * 32 + hi * 8];
      #pragma unroll
      for (int nt = 0; nt < 4; ++nt) {
        bf16x8 vf = *(const bf16x8*)&Vs[bf][(nt * 16 + lo) * 64
                                            + ((ks * 32 + hi * 8) ^ xsw)];
        o[0][nt] = __builtin_amdgcn_mfma_f32_16x16x32_bf16(pa0, vf, o[0][nt], 0, 0, 0);
        o[1][nt] = __builtin_amdgcn_mfma_f32_16x16x32_bf16(pa1, vf, o[1][nt], 0, 0, 0);
      }
    }
    __builtin_amdgcn_s_setprio(0);
    __syncthreads();
  }

  #pragma unroll
  for (int m = 0; m < 2; ++m)
    #pragma unroll
    for (int r = 0; r < 4; ++r) {
      float v = lsum[m][r];
      v += __shfl_xor(v, 1);
      v += __shfl_xor(v, 2);
      v += __shfl_xor(v, 4);
      v += __shfl_xor(v, 8);
      lsum[m][r] = v;
    }
  #pragma unroll
  for (int m = 0; m < 2; ++m)
    #pragma unroll
    for (int r = 0; r < 4; ++r) {
      const int qrow = q0 + wid * 32 + m * 16 + 4 * hi + r;
      if (qrow < NSEQ) {
        const float inv = 1.f / lsum[m][r];
        short* op = ab + (size_t)(b * NSEQ + qrow) * DIM + h * DH + lo;
        #pragma unroll
        for (int nt = 0; nt < 4; ++nt)
          op[nt * 16] = (short)f2bf(o[m][nt][r] * inv);
      }
    }
}

// ---------------------------------------------------------------------------
// attn_map pass A: per-(b,h) row-0 softmax max & inv-denominator (fp32 qkv).
// Grid 96, 256 threads. ms[bh] = {max, 1/(sum*HEADS)}.
// ---------------------------------------------------------------------------
__global__ __launch_bounds__(256) void map_ms_kernel(
    const float* __restrict__ qkv, float* __restrict__ ms) {
  const int bh = blockIdx.x;
  const int b = bh / HEADS, h = bh - (bh / HEADS) * HEADS;
  const int tid = threadIdx.x;
  __shared__ float q0s[64];
  __shared__ float red[256];
  const size_t rowbase = (size_t)b * NSEQ;
  if (tid < 64) q0s[tid] = qkv[rowbase * C3 + h * DH + tid];
  __syncthreads();
  float s[5];
  float lm = -INFINITY;
  #pragma unroll
  for (int sl = 0; sl < 5; ++sl) {
    int j = tid + sl * 256;
    s[sl] = -INFINITY;
    if (j < NSEQ) {
      const float* kp = &qkv[(rowbase + j) * C3 + DIM + h * DH];
      float d0 = 0.f;
      #pragma unroll
      for (int d = 0; d < 64; d += 4) {
        float4 kv = *(const float4*)&kp[d];
        d0 += q0s[d] * kv.x + q0s[d + 1] * kv.y + q0s[d + 2] * kv.z + q0s[d + 3] * kv.w;
      }
      s[sl] = d0;
      lm = fmaxf(lm, d0);
    }
  }
  red[tid] = lm; __syncthreads();
  for (int off = 128; off > 0; off >>= 1) {
    if (tid < off) red[tid] = fmaxf(red[tid], red[tid + off]);
    __syncthreads();
  }
  const float Mx = red[0]; __syncthreads();
  float ls = 0.f;
  #pragma unroll
  for (int sl = 0; sl < 5; ++sl) {
    int j = tid + sl * 256;
    if (j < NSEQ) ls += exp2f(s[sl] - Mx);
  }
  red[tid] = ls; __syncthreads();
  for (int off = 128; off > 0; off >>= 1) {
    if (tid < off) red[tid] += red[tid + off];
    __syncthreads();
  }
  if (tid == 0) {
    ms[bh * 2]     = Mx;
    ms[bh * 2 + 1] = 1.f / (red[0] * (float)HEADS);
  }
}

// ---------------------------------------------------------------------------
// attn_map pass B: map[b][j-1] = sum_h exp2(q0_h . k_jh - M_h) * inv_h.
// Grid (4, 8), 256 threads; thread handles one (b, j). fp32 qkv inputs.
// ---------------------------------------------------------------------------
__global__ __launch_bounds__(256) void map_p_kernel(
    const float* __restrict__ qkv, const float* __restrict__ ms,
    float* __restrict__ map) {
  const int b = blockIdx.y;
  const int j = blockIdx.x * 256 + threadIdx.x + 1;   // 1..1024
  const int tid = threadIdx.x;
  __shared__ float q0s[768];
  __shared__ float msb[24];
  const size_t rowbase = (size_t)b * NSEQ;
  for (int idx = tid; idx < 768; idx += 256) q0s[idx] = qkv[rowbase * C3 + idx];
  if (tid < 24) msb[tid] = ms[b * HEADS * 2 + tid];
  __syncthreads();
  const float* kp = &qkv[(rowbase + j) * C3 + DIM];
  float acc = 0.f;
  #pragma unroll
  for (int h = 0; h < HEADS; ++h) {
    float d0 = 0.f;
    #pragma unroll
    for (int d = 0; d < 64; d += 4) {
      float4 kv = *(const float4*)&kp[h * DH + d];
      const float* qp = &q0s[h * DH + d];
      d0 += qp[0] * kv.x + qp[1] * kv.y + qp[2] * kv.z + qp[3] * kv.w;
    }
    acc += exp2f(d0 - msb[h * 2]) * msb[h * 2 + 1];
  }
  map[(size_t)b * (NSEQ - 1) + j - 1] = acc;
}

// ---------------------------------------------------------------------------
extern "C" void kernel_launch(void* const* d_in, const int* in_sizes, int n_in,
                              void* d_out, int out_size, void* d_ws, size_t ws_size,
                              hipStream_t stream) {
  const float* x     = (const float*)d_in[0];
  const float* Wqkv  = (const float*)d_in[1];
  const float* bqkv  = (const float*)d_in[2];
  const float* Wproj = (const float*)d_in[3];
  const float* bproj = (const float*)d_in[4];
  const float* gq    = (const float*)d_in[5];
  const float* betaq = (const float*)d_in[6];
  const float* gk    = (const float*)d_in[7];
  const float* betak = (const float*)d_in[8];

  float* qkv = (float*)d_ws;                              // [8200,2304] f32
  short* xb  = (short*)(qkv + (size_t)MROWS * C3);        // [8320,768] bf16 (reused as attn out)
  short* qb  = xb + (size_t)MPAD * DIM;                   // [96,1152,64] bf16
  short* kb  = qb + (size_t)NBH * QPAD * DH;              // [96,1088,64] bf16
  short* vt  = kb + (size_t)NBH * NKPAD * DH;             // [96,64,1088] bf16
  short* wqt = vt + (size_t)NBH * DH * NKPAD;             // [2304,768] bf16
  short* wpt = wqt + (size_t)C3 * DIM;                    // [768,768] bf16
  float* ms  = (float*)(wpt + (size_t)DIM * DIM);         // [96,2] f32
  float* out = (float*)d_out;                             // [8200,768]
  float* map = out + (size_t)MROWS * DIM;                 // [8,1024]

  // 0) conversions
  convert_x_kernel<<<MPAD * DIM / 2048, 256, 0, stream>>>(x, xb);
  {
    dim3 grid(C3 / 64, DIM / 64);
    wtrans_kernel<<<grid, 256, 0, stream>>>(Wqkv, wqt, DIM, C3);
  }
  {
    dim3 grid(DIM / 64, DIM / 64);
    wtrans_kernel<<<grid, 256, 0, stream>>>(Wproj, wpt, DIM, DIM);
  }
  // 1) qkv = x @ Wqkv + bqkv   (bf16 MFMA)
  {
    dim3 grid(C3 / 128, MPAD / 128);
    gemm_bf16_kernel<<<grid, 256, 0, stream>>>(xb, wqt, bqkv, qkv, MROWS, C3, DIM);
  }
  // 2) LN on q,k (fp32 in-place + bf16 qb/kb)
  {
    int blocks = (MROWS * HEADS + 3) / 4;
    ln_qk_kernel<<<blocks, 256, 0, stream>>>(qkv, gq, betaq, gk, betak, qb, kb);
  }
  // 3) V transpose/convert
  {
    dim3 grid(17, NBH);
    vt_convert_kernel<<<grid, 256, 0, stream>>>(qkv, vt);
  }
  // 4) MFMA attention -> bf16 into xb (dead after step 1)
  {
    dim3 grid(NBH, QPAD / 128);
    attn_mfma_kernel<<<grid, 256, 0, stream>>>(qb, kb, vt, xb);
  }
  // 5) attn_map (exact fp32 path, two passes)
  map_ms_kernel<<<NBH, 256, 0, stream>>>(qkv, ms);
  {
    dim3 grid(4, BS);
    map_p_kernel<<<grid, 256, 0, stream>>>(qkv, ms, map);
  }
  // 6) out = attn_out @ Wproj + bproj   (bf16 MFMA)
  {
    dim3 grid(DIM / 128, MPAD / 128);
    gemm_bf16_kernel<<<grid, 256, 0, stream>>>(xb, wpt, bproj, out, MROWS, DIM, DIM);
  }
}

// Round 10
// 250.630 us; speedup vs baseline: 11.1269x; 1.0165x over previous
//
#include <hip/hip_runtime.h>
#include <hip/hip_bf16.h>
#include <math.h>

// Problem constants
#define BS   8
#define NSEQ 1025
#define DIM  768
#define C3   2304      // 3*DIM
#define HEADS 12
#define DH   64
#define MROWS (BS*NSEQ) // 8200
#define MPAD  8320      // 65*128, padded M for GEMM tiles
#define NKPAD 1088      // 17*64, padded key length for MFMA tiles
#define QPAD  1152      // 9*128, padded query length for attn blocks
#define NBH   (BS*HEADS)

// log2(e) folded into Q during LN so softmax uses exp2
#define QSCALE (0.125f * 1.44269504088896340736f)
#define SBOUND 10.0f    // fixed softmax offset (log2 domain); ratios unchanged

typedef __attribute__((ext_vector_type(8))) short bf16x8;
typedef __attribute__((ext_vector_type(4))) float f32x4;

static __device__ __forceinline__ unsigned short f2bf(float f) {
  unsigned int u = __float_as_uint(f);
  unsigned int r = (u + 0x7fffu + ((u >> 16) & 1u)) >> 16;
  return (unsigned short)r;
}

// packed f32x2 -> bf16x2 (RNE) in one instruction; low half = a, high = b
static __device__ __forceinline__ unsigned int cvtpk_bf16(float a, float b) {
  unsigned int r;
  asm("v_cvt_pk_bf16_f32 %0, %1, %2" : "=v"(r) : "v"(a), "v"(b));
  return r;
}

static __device__ __forceinline__ void gload16(const short* g, short* l) {
  __builtin_amdgcn_global_load_lds(
      (const __attribute__((address_space(1))) unsigned int*)g,
      (__attribute__((address_space(3))) unsigned int*)l, 16, 0, 0);
}

// ---------------------------------------------------------------------------
// x fp32 [MROWS][DIM] -> xb bf16 [MPAD][DIM], pad rows zeroed.
// ---------------------------------------------------------------------------
__global__ __launch_bounds__(256) void convert_x_kernel(
    const float* __restrict__ x, short* __restrict__ xb) {
  const size_t i = ((size_t)blockIdx.x * 256 + threadIdx.x) * 8;
  const size_t row = i / DIM;
  bf16x8 w;
  if (row < MROWS) {
    float4 v0 = *(const float4*)&x[i];
    float4 v1 = *(const float4*)&x[i + 4];
    w[0] = (short)f2bf(v0.x); w[1] = (short)f2bf(v0.y);
    w[2] = (short)f2bf(v0.z); w[3] = (short)f2bf(v0.w);
    w[4] = (short)f2bf(v1.x); w[5] = (short)f2bf(v1.y);
    w[6] = (short)f2bf(v1.z); w[7] = (short)f2bf(v1.w);
  } else {
    #pragma unroll
    for (int j = 0; j < 8; ++j) w[j] = 0;
  }
  *(bf16x8*)&xb[i] = w;
}

// ---------------------------------------------------------------------------
// W fp32 [K][N] -> Wt bf16 [N][K] (transpose + convert). Grid (N/64, K/64).
// ---------------------------------------------------------------------------
__global__ __launch_bounds__(256) void wtrans_kernel(
    const float* __restrict__ W, short* __restrict__ Wt, int K, int N) {
  const int n0 = blockIdx.x * 64, k0 = blockIdx.y * 64;
  __shared__ float tile[64][65];
  const int r = threadIdx.x >> 2;        // 0..63
  const int c0 = (threadIdx.x & 3) * 16; // 0,16,32,48
  const float* src = W + (size_t)(k0 + r) * N + n0 + c0;
  #pragma unroll
  for (int j = 0; j < 16; j += 4) {
    float4 v = *(const float4*)(src + j);
    tile[r][c0 + j]     = v.x;
    tile[r][c0 + j + 1] = v.y;
    tile[r][c0 + j + 2] = v.z;
    tile[r][c0 + j + 3] = v.w;
  }
  __syncthreads();
  bf16x8 w0, w1;
  #pragma unroll
  for (int j = 0; j < 8; ++j) {
    w0[j] = (short)f2bf(tile[c0 + j][r]);
    w1[j] = (short)f2bf(tile[c0 + 8 + j][r]);
  }
  short* dst = Wt + (size_t)(n0 + r) * K + k0 + c0;
  *(bf16x8*)dst = w0;
  *(bf16x8*)(dst + 8) = w1;
}

// ---------------------------------------------------------------------------
// bf16 MFMA GEMM: C[M,N] f32 = A[Mp,K]bf16 . Bt[N,K]bf16^T + bias[N].
// 128x128 tile, BK=64, 4 waves (2x2), global_load_lds staging (m97 structure).
// XCD-chunked bijective block swizzle (m204): value-identical, L2-local.
// ---------------------------------------------------------------------------
__global__ __launch_bounds__(256) void gemm_bf16_kernel(
    const short* __restrict__ A, const short* __restrict__ Bt,
    const float* __restrict__ bias, float* __restrict__ C,
    int M, int N, int K) {
  __shared__ short As[128 * 64];
  __shared__ short Bs[128 * 64];
  const int tid = threadIdx.x;
  const int wid = tid >> 6, lane = tid & 63;
  const int lo = lane & 15, hi = lane >> 4;
  const int wr = wid >> 1, wc = wid & 1;

  // bijective XCD-chunk remap (m204): consecutive hardware ids round-robin
  // the 8 XCDs; give each XCD a contiguous chunk of tile-space instead.
  const int nwg = gridDim.x * gridDim.y;
  int bid = blockIdx.y * gridDim.x + blockIdx.x;
  {
    const int q = nwg >> 3, rr = nwg & 7;
    const int xcd = bid & 7, idx = bid >> 3;
    bid = (xcd < rr ? xcd * (q + 1) : rr * (q + 1) + (xcd - rr) * q) + idx;
  }
  const int m0 = (bid / gridDim.x) * 128, n0 = (bid % gridDim.x) * 128;

  const int rl = lane >> 3;            // 0..7
  const int cb = (lane & 7) * 8;       // bf16 col offset within 64

  f32x4 acc[4][4];
  #pragma unroll
  for (int m = 0; m < 4; ++m)
    #pragma unroll
    for (int n = 0; n < 4; ++n)
      acc[m][n][0] = acc[m][n][1] = acc[m][n][2] = acc[m][n][3] = 0.f;

  const short* Abase = A + (size_t)(m0 + wid * 32 + rl) * K + cb;
  const short* Bbase = Bt + (size_t)(n0 + wid * 32 + rl) * K + cb;

  for (int k0 = 0; k0 < K; k0 += 64) {
    #pragma unroll
    for (int i = 0; i < 4; ++i) {
      gload16(Abase + (size_t)(i * 8) * K + k0, &As[(wid * 32 + i * 8) * 64]);
      gload16(Bbase + (size_t)(i * 8) * K + k0, &Bs[(wid * 32 + i * 8) * 64]);
    }
    __syncthreads();
    #pragma unroll
    for (int kk = 0; kk < 2; ++kk) {
      bf16x8 a[4], bfr[4];
      #pragma unroll
      for (int m = 0; m < 4; ++m)
        a[m] = *(const bf16x8*)&As[(wr * 64 + m * 16 + lo) * 64 + kk * 32 + hi * 8];
      #pragma unroll
      for (int n = 0; n < 4; ++n)
        bfr[n] = *(const bf16x8*)&Bs[(wc * 64 + n * 16 + lo) * 64 + kk * 32 + hi * 8];
      #pragma unroll
      for (int m = 0; m < 4; ++m)
        #pragma unroll
        for (int n = 0; n < 4; ++n)
          acc[m][n] = __builtin_amdgcn_mfma_f32_16x16x32_bf16(a[m], bfr[n], acc[m][n], 0, 0, 0);
    }
    __syncthreads();
  }

  #pragma unroll
  for (int m = 0; m < 4; ++m) {
    #pragma unroll
    for (int r = 0; r < 4; ++r) {
      const int grow = m0 + wr * 64 + m * 16 + hi * 4 + r;
      if (grow < M) {
        float* cp = C + (size_t)grow * N + n0 + wc * 64 + lo;
        const float* bp = bias + n0 + wc * 64 + lo;
        #pragma unroll
        for (int n = 0; n < 4; ++n) cp[n * 16] = acc[m][n][r] + bp[n * 16];
      }
    }
  }
}

// ---------------------------------------------------------------------------
// In-place LayerNorm on q and k of qkv[M, 2304]; Q scaled by 0.125*log2e.
// bf16 copies: qb [bh][QPAD][64], kb [bh][NKPAD][64].
// ---------------------------------------------------------------------------
__global__ __launch_bounds__(256) void ln_qk_kernel(
    float* __restrict__ qkv,
    const float* __restrict__ gq, const float* __restrict__ bq,
    const float* __restrict__ gk, const float* __restrict__ bk,
    short* __restrict__ qb, short* __restrict__ kb) {
  const int task = blockIdx.x * 4 + (threadIdx.x >> 6);
  const int lane = threadIdx.x & 63;
  const int TASKS = MROWS * HEADS;
  if (task >= TASKS) return;
  const int row = task / HEADS;
  const int h = task - row * HEADS;
  const size_t base = (size_t)row * C3 + h * DH;
  float xq = qkv[base + lane];
  float xk = qkv[base + DIM + lane];
  float sq = xq, s2q = xq * xq, sk = xk, s2k = xk * xk;
  #pragma unroll
  for (int off = 32; off; off >>= 1) {
    sq  += __shfl_xor(sq,  off);
    s2q += __shfl_xor(s2q, off);
    sk  += __shfl_xor(sk,  off);
    s2k += __shfl_xor(s2k, off);
  }
  const float inv64 = 1.f / 64.f;
  float mq = sq * inv64, vq = s2q * inv64 - mq * mq;
  float mk = sk * inv64, vk = s2k * inv64 - mk * mk;
  float rq = rsqrtf(vq + 1e-5f), rk = rsqrtf(vk + 1e-5f);
  float qn = ((xq - mq) * rq * gq[lane] + bq[lane]) * QSCALE;
  float kn =  (xk - mk) * rk * gk[lane] + bk[lane];
  qkv[base + lane]       = qn;
  qkv[base + DIM + lane] = kn;
  const int b = row / NSEQ;
  const int n = row - b * NSEQ;
  const int bh = b * HEADS + h;
  qb[((size_t)bh * QPAD  + n) * DH + lane] = (short)f2bf(qn);
  kb[((size_t)bh * NKPAD + n) * DH + lane] = (short)f2bf(kn);
}

// ---------------------------------------------------------------------------
// V convert+transpose: qkv v-part fp32 -> vt bf16 [bh][d][NKPAD] (zero pad).
// Grid: (17, 96), 256 threads.
// ---------------------------------------------------------------------------
__global__ __launch_bounds__(256) void vt_convert_kernel(
    const float* __restrict__ qkv, short* __restrict__ vt) {
  const int kt = blockIdx.x;     // key tile 0..16
  const int bh = blockIdx.y;     // 0..95
  const int b = bh / HEADS, h = bh - (bh / HEADS) * HEADS;
  const int t = threadIdx.x;
  __shared__ float tile[64][65];
  const int r = t >> 2;          // 0..63
  const int c0 = (t & 3) * 16;   // 0,16,32,48
  const int grow = kt * 64 + r;  // key index 0..1087

  const float* src = qkv + (size_t)(b * NSEQ + grow) * C3 + 2 * DIM + h * DH + c0;
  #pragma unroll
  for (int j = 0; j < 16; j += 4) {
    float4 v = (grow < NSEQ) ? *(const float4*)(src + j)
                             : make_float4(0.f, 0.f, 0.f, 0.f);
    tile[r][c0 + j]     = v.x;
    tile[r][c0 + j + 1] = v.y;
    tile[r][c0 + j + 2] = v.z;
    tile[r][c0 + j + 3] = v.w;
  }
  __syncthreads();
  bf16x8 w0, w1;
  #pragma unroll
  for (int j = 0; j < 8; ++j) {
    w0[j] = (short)f2bf(tile[c0 + j][r]);
    w1[j] = (short)f2bf(tile[c0 + 8 + j][r]);
  }
  short* dst = vt + ((size_t)bh * DH + r) * NKPAD + kt * 64 + c0;
  *(bf16x8*)dst = w0;
  *(bf16x8*)(dst + 8) = w1;
}

// ---------------------------------------------------------------------------
// MFMA bf16 flash attention v5: split-stage SINGLE-buffered K/V.
// Ks and Vs have disjoint consumption phases (QK^T reads Ks only, PV reads
// Vs only), so stageK(kt+1) overlaps softmax+PV(kt) and stageV(kt+1)
// overlaps QK^T(kt+1) -- near-dbuf overlap at half the K/V LDS.
// Each __syncthreads drains vmcnt(0), guaranteeing staged data visibility.
// LDS 34.8 KB -> 4 blocks/CU (was 51.2 KB -> 3).
// Block = 256 threads (4 waves); wave owns 32 query rows (2 m-frags).
// Grid: (96, QPAD/128 = 9) -- XCD-local (96 % 8 == 0).
// ---------------------------------------------------------------------------
__global__ __launch_bounds__(256) void attn_mfma_kernel(
    const short* __restrict__ qb, const short* __restrict__ kb,
    const short* __restrict__ vt, short* __restrict__ ab) {
  const int bh = blockIdx.x;
  const int b = bh / HEADS, h = bh - (bh / HEADS) * HEADS;
  const int wid = threadIdx.x >> 6;
  const int lane = threadIdx.x & 63;
  const int lo = lane & 15, hi = lane >> 4;
  const int q0 = blockIdx.y * 128;
  const int xsw = (lo & 7) << 3;          // read-side XOR swizzle (shorts)

  __shared__ short Ks[64 * 64];           // swizzled K tile  [key][d]
  __shared__ short Vs[64 * 64];           // swizzled V^T tile [d][key]
  __shared__ short Pb[4][32][72];         // per-wave P buffer

  const short* kg = kb + (size_t)bh * NKPAD * DH;
  const short* vg = vt + (size_t)bh * DH * NKPAD;

  const int sr = wid * 16 + (lane >> 3);               // staging row 0..63
  const int sw = ((lane & 7) ^ (lane >> 3)) << 3;      // pre-swizzled col
  auto stageK = [&](int kt) {
    #pragma unroll
    for (int i = 0; i < 2; ++i)
      gload16(kg + (size_t)(kt * 64 + sr + i * 8) * DH + sw,
              &Ks[wid * 1024 + i * 512]);
  };
  auto stageV = [&](int kt) {
    #pragma unroll
    for (int i = 0; i < 2; ++i)
      gload16(vg + (size_t)(sr + i * 8) * NKPAD + kt * 64 + sw,
              &Vs[wid * 1024 + i * 512]);
  };

  bf16x8 aq[2][2];
  #pragma unroll
  for (int m = 0; m < 2; ++m) {
    const short* qp = qb + (size_t)bh * QPAD * DH
                    + (size_t)(q0 + wid * 32 + m * 16 + lo) * DH + hi * 8;
    aq[m][0] = *(const bf16x8*)qp;
    aq[m][1] = *(const bf16x8*)(qp + 32);
  }

  f32x4 o[2][4];
  float lsum[2][4];
  #pragma unroll
  for (int m = 0; m < 2; ++m)
    #pragma unroll
    for (int nt = 0; nt < 4; ++nt) {
      o[m][nt][0] = o[m][nt][1] = o[m][nt][2] = o[m][nt][3] = 0.f;
      lsum[m][nt] = 0.f;
    }

  stageK(0);
  stageV(0);
  __syncthreads();   // drains vmcnt(0): tile 0 staged & visible

  for (int kt = 0; kt < 17; ++kt) {
    // ---- QK^T (reads Ks) ----
    f32x4 s[2][4];
    #pragma unroll
    for (int m = 0; m < 2; ++m)
      #pragma unroll
      for (int nt = 0; nt < 4; ++nt)
        s[m][nt][0] = s[m][nt][1] = s[m][nt][2] = s[m][nt][3] = 0.f;
    __builtin_amdgcn_s_setprio(1);
    #pragma unroll
    for (int kk = 0; kk < 2; ++kk) {
      bf16x8 kf[4];
      #pragma unroll
      for (int nt = 0; nt < 4; ++nt)
        kf[nt] = *(const bf16x8*)&Ks[(nt * 16 + lo) * 64
                                     + ((kk * 32 + hi * 8) ^ xsw)];
      #pragma unroll
      for (int m = 0; m < 2; ++m)
        #pragma unroll
        for (int nt = 0; nt < 4; ++nt)
          s[m][nt] = __builtin_amdgcn_mfma_f32_16x16x32_bf16(
              aq[m][kk], kf[nt], s[m][nt], 0, 0, 0);
    }
    __builtin_amdgcn_s_setprio(0);

    __syncthreads();                  // all waves done reading Ks
    if (kt < 16) stageK(kt + 1);      // overlaps softmax + PV below

    if (kt == 16) {
      #pragma unroll
      for (int m = 0; m < 2; ++m)
        #pragma unroll
        for (int nt = 0; nt < 4; ++nt)
          if (nt * 16 + lo >= 1)
            s[m][nt][0] = s[m][nt][1] = s[m][nt][2] = s[m][nt][3] = -1e30f;
    }
    // ---- softmax (fixed offset) + P staging (packed bf16 convert) ----
    #pragma unroll
    for (int m = 0; m < 2; ++m)
      #pragma unroll
      for (int nt = 0; nt < 4; ++nt) {
        float p0 = exp2f(s[m][nt][0] - SBOUND);
        float p1 = exp2f(s[m][nt][1] - SBOUND);
        float p2 = exp2f(s[m][nt][2] - SBOUND);
        float p3 = exp2f(s[m][nt][3] - SBOUND);
        lsum[m][0] += p0; lsum[m][1] += p1;
        lsum[m][2] += p2; lsum[m][3] += p3;
        unsigned int c01 = cvtpk_bf16(p0, p1);
        unsigned int c23 = cvtpk_bf16(p2, p3);
        unsigned short* pb = (unsigned short*)&Pb[wid][m * 16 + 4 * hi][nt * 16 + lo];
        pb[0]       = (unsigned short)c01;
        pb[72]      = (unsigned short)(c01 >> 16);
        pb[144]     = (unsigned short)c23;
        pb[216]     = (unsigned short)(c23 >> 16);
      }
    // ---- PV (reads Vs) ----
    __builtin_amdgcn_s_setprio(1);
    #pragma unroll
    for (int ks = 0; ks < 2; ++ks) {
      bf16x8 pa0 = *(const bf16x8*)&Pb[wid][lo][ks * 32 + hi * 8];
      bf16x8 pa1 = *(const bf16x8*)&Pb[wid][16 + lo][ks * 32 + hi * 8];
      #pragma unroll
      for (int nt = 0; nt < 4; ++nt) {
        bf16x8 vf = *(const bf16x8*)&Vs[(nt * 16 + lo) * 64
                                        + ((ks * 32 + hi * 8) ^ xsw)];
        o[0][nt] = __builtin_amdgcn_mfma_f32_16x16x32_bf16(pa0, vf, o[0][nt], 0, 0, 0);
        o[1][nt] = __builtin_amdgcn_mfma_f32_16x16x32_bf16(pa1, vf, o[1][nt], 0, 0, 0);
      }
    }
    __builtin_amdgcn_s_setprio(0);

    __syncthreads();                  // all waves done reading Vs; drains
    if (kt < 16) stageV(kt + 1);      //   stageK's vmcnt. V overlaps next QK^T
  }

  #pragma unroll
  for (int m = 0; m < 2; ++m)
    #pragma unroll
    for (int r = 0; r < 4; ++r) {
      float v = lsum[m][r];
      v += __shfl_xor(v, 1);
      v += __shfl_xor(v, 2);
      v += __shfl_xor(v, 4);
      v += __shfl_xor(v, 8);
      lsum[m][r] = v;
    }
  #pragma unroll
  for (int m = 0; m < 2; ++m)
    #pragma unroll
    for (int r = 0; r < 4; ++r) {
      const int qrow = q0 + wid * 32 + m * 16 + 4 * hi + r;
      if (qrow < NSEQ) {
        const float inv = 1.f / lsum[m][r];
        short* op = ab + (size_t)(b * NSEQ + qrow) * DIM + h * DH + lo;
        #pragma unroll
        for (int nt = 0; nt < 4; ++nt)
          op[nt * 16] = (short)f2bf(o[m][nt][r] * inv);
      }
    }
}

// ---------------------------------------------------------------------------
// attn_map pass A: per-(b,h) row-0 softmax max & inv-denominator (fp32 qkv).
// Grid 96, 256 threads. ms[bh] = {max, 1/(sum*HEADS)}.
// ---------------------------------------------------------------------------
__global__ __launch_bounds__(256) void map_ms_kernel(
    const float* __restrict__ qkv, float* __restrict__ ms) {
  const int bh = blockIdx.x;
  const int b = bh / HEADS, h = bh - (bh / HEADS) * HEADS;
  const int tid = threadIdx.x;
  __shared__ float q0s[64];
  __shared__ float red[256];
  const size_t rowbase = (size_t)b * NSEQ;
  if (tid < 64) q0s[tid] = qkv[rowbase * C3 + h * DH + tid];
  __syncthreads();
  float s[5];
  float lm = -INFINITY;
  #pragma unroll
  for (int sl = 0; sl < 5; ++sl) {
    int j = tid + sl * 256;
    s[sl] = -INFINITY;
    if (j < NSEQ) {
      const float* kp = &qkv[(rowbase + j) * C3 + DIM + h * DH];
      float d0 = 0.f;
      #pragma unroll
      for (int d = 0; d < 64; d += 4) {
        float4 kv = *(const float4*)&kp[d];
        d0 += q0s[d] * kv.x + q0s[d + 1] * kv.y + q0s[d + 2] * kv.z + q0s[d + 3] * kv.w;
      }
      s[sl] = d0;
      lm = fmaxf(lm, d0);
    }
  }
  red[tid] = lm; __syncthreads();
  for (int off = 128; off > 0; off >>= 1) {
    if (tid < off) red[tid] = fmaxf(red[tid], red[tid + off]);
    __syncthreads();
  }
  const float Mx = red[0]; __syncthreads();
  float ls = 0.f;
  #pragma unroll
  for (int sl = 0; sl < 5; ++sl) {
    int j = tid + sl * 256;
    if (j < NSEQ) ls += exp2f(s[sl] - Mx);
  }
  red[tid] = ls; __syncthreads();
  for (int off = 128; off > 0; off >>= 1) {
    if (tid < off) red[tid] += red[tid + off];
    __syncthreads();
  }
  if (tid == 0) {
    ms[bh * 2]     = Mx;
    ms[bh * 2 + 1] = 1.f / (red[0] * (float)HEADS);
  }
}

// ---------------------------------------------------------------------------
// attn_map pass B: map[b][j-1] = sum_h exp2(q0_h . k_jh - M_h) * inv_h.
// Grid (4, 8), 256 threads; thread handles one (b, j). fp32 qkv inputs.
// ---------------------------------------------------------------------------
__global__ __launch_bounds__(256) void map_p_kernel(
    const float* __restrict__ qkv, const float* __restrict__ ms,
    float* __restrict__ map) {
  const int b = blockIdx.y;
  const int j = blockIdx.x * 256 + threadIdx.x + 1;   // 1..1024
  const int tid = threadIdx.x;
  __shared__ float q0s[768];
  __shared__ float msb[24];
  const size_t rowbase = (size_t)b * NSEQ;
  for (int idx = tid; idx < 768; idx += 256) q0s[idx] = qkv[rowbase * C3 + idx];
  if (tid < 24) msb[tid] = ms[b * HEADS * 2 + tid];
  __syncthreads();
  const float* kp = &qkv[(rowbase + j) * C3 + DIM];
  float acc = 0.f;
  #pragma unroll
  for (int h = 0; h < HEADS; ++h) {
    float d0 = 0.f;
    #pragma unroll
    for (int d = 0; d < 64; d += 4) {
      float4 kv = *(const float4*)&kp[h * DH + d];
      const float* qp = &q0s[h * DH + d];
      d0 += qp[0] * kv.x + qp[1] * kv.y + qp[2] * kv.z + qp[3] * kv.w;
    }
    acc += exp2f(d0 - msb[h * 2]) * msb[h * 2 + 1];
  }
  map[(size_t)b * (NSEQ - 1) + j - 1] = acc;
}

// ---------------------------------------------------------------------------
extern "C" void kernel_launch(void* const* d_in, const int* in_sizes, int n_in,
                              void* d_out, int out_size, void* d_ws, size_t ws_size,
                              hipStream_t stream) {
  const float* x     = (const float*)d_in[0];
  const float* Wqkv  = (const float*)d_in[1];
  const float* bqkv  = (const float*)d_in[2];
  const float* Wproj = (const float*)d_in[3];
  const float* bproj = (const float*)d_in[4];
  const float* gq    = (const float*)d_in[5];
  const float* betaq = (const float*)d_in[6];
  const float* gk    = (const float*)d_in[7];
  const float* betak = (const float*)d_in[8];

  float* qkv = (float*)d_ws;                              // [8200,2304] f32
  short* xb  = (short*)(qkv + (size_t)MROWS * C3);        // [8320,768] bf16 (reused as attn out)
  short* qb  = xb + (size_t)MPAD * DIM;                   // [96,1152,64] bf16
  short* kb  = qb + (size_t)NBH * QPAD * DH;              // [96,1088,64] bf16
  short* vt  = kb + (size_t)NBH * NKPAD * DH;             // [96,64,1088] bf16
  short* wqt = vt + (size_t)NBH * DH * NKPAD;             // [2304,768] bf16
  short* wpt = wqt + (size_t)C3 * DIM;                    // [768,768] bf16
  float* ms  = (float*)(wpt + (size_t)DIM * DIM);         // [96,2] f32
  float* out = (float*)d_out;                             // [8200,768]
  float* map = out + (size_t)MROWS * DIM;                 // [8,1024]

  // 0) conversions
  convert_x_kernel<<<MPAD * DIM / 2048, 256, 0, stream>>>(x, xb);
  {
    dim3 grid(C3 / 64, DIM / 64);
    wtrans_kernel<<<grid, 256, 0, stream>>>(Wqkv, wqt, DIM, C3);
  }
  {
    dim3 grid(DIM / 64, DIM / 64);
    wtrans_kernel<<<grid, 256, 0, stream>>>(Wproj, wpt, DIM, DIM);
  }
  // 1) qkv = x @ Wqkv + bqkv   (bf16 MFMA)
  {
    dim3 grid(C3 / 128, MPAD / 128);
    gemm_bf16_kernel<<<grid, 256, 0, stream>>>(xb, wqt, bqkv, qkv, MROWS, C3, DIM);
  }
  // 2) LN on q,k (fp32 in-place + bf16 qb/kb)
  {
    int blocks = (MROWS * HEADS + 3) / 4;
    ln_qk_kernel<<<blocks, 256, 0, stream>>>(qkv, gq, betaq, gk, betak, qb, kb);
  }
  // 3) V transpose/convert
  {
    dim3 grid(17, NBH);
    vt_convert_kernel<<<grid, 256, 0, stream>>>(qkv, vt);
  }
  // 4) MFMA attention -> bf16 into xb (dead after step 1)
  {
    dim3 grid(NBH, QPAD / 128);
    attn_mfma_kernel<<<grid, 256, 0, stream>>>(qb, kb, vt, xb);
  }
  // 5) attn_map (exact fp32 path, two passes)
  map_ms_kernel<<<NBH, 256, 0, stream>>>(qkv, ms);
  {
    dim3 grid(4, BS);
    map_p_kernel<<<grid, 256, 0, stream>>>(qkv, ms, map);
  }
  // 6) out = attn_out @ Wproj + bproj   (bf16 MFMA)
  {
    dim3 grid(DIM / 128, MPAD / 128);
    gemm_bf16_kernel<<<grid, 256, 0, stream>>>(xb, wpt, bproj, out, MROWS, DIM, DIM);
  }
}

// Round 11
// 229.674 us; speedup vs baseline: 12.1422x; 1.0912x over previous
//
#include <hip/hip_runtime.h>
#include <hip/hip_bf16.h>
#include <math.h>

// Problem constants
#define BS   8
#define NSEQ 1025
#define DIM  768
#define C3   2304      // 3*DIM
#define C2   1536      // q,k packed width
#define HEADS 12
#define DH   64
#define MROWS (BS*NSEQ) // 8200
#define MPAD  8320      // 65*128, padded M for GEMM tiles
#define NKPAD 1088      // 17*64, padded key length for MFMA tiles
#define QPAD  1152      // 9*128, padded query length for attn blocks
#define NBH   (BS*HEADS)

// log2(e) folded into Q during LN so softmax uses exp2
#define QSCALE (0.125f * 1.44269504088896340736f)
#define SBOUND 10.0f    // fixed softmax offset (log2 domain); ratios unchanged

typedef __attribute__((ext_vector_type(8))) short bf16x8;
typedef __attribute__((ext_vector_type(4))) float f32x4;

static __device__ __forceinline__ unsigned short f2bf(float f) {
  unsigned int u = __float_as_uint(f);
  unsigned int r = (u + 0x7fffu + ((u >> 16) & 1u)) >> 16;
  return (unsigned short)r;
}

static __device__ __forceinline__ float bf2f(short u) {
  return __uint_as_float(((unsigned int)(unsigned short)u) << 16);
}

// packed f32x2 -> bf16x2 (RNE) in one instruction; low half = a, high = b
static __device__ __forceinline__ unsigned int cvtpk_bf16(float a, float b) {
  unsigned int r;
  asm("v_cvt_pk_bf16_f32 %0, %1, %2" : "=v"(r) : "v"(a), "v"(b));
  return r;
}

static __device__ __forceinline__ void gload16(const short* g, short* l) {
  __builtin_amdgcn_global_load_lds(
      (const __attribute__((address_space(1))) unsigned int*)g,
      (__attribute__((address_space(3))) unsigned int*)l, 16, 0, 0);
}

// ---------------------------------------------------------------------------
// x fp32 [MROWS][DIM] -> xb bf16 [MPAD][DIM], pad rows zeroed.
// ---------------------------------------------------------------------------
__global__ __launch_bounds__(256) void convert_x_kernel(
    const float* __restrict__ x, short* __restrict__ xb) {
  const size_t i = ((size_t)blockIdx.x * 256 + threadIdx.x) * 8;
  const size_t row = i / DIM;
  bf16x8 w;
  if (row < MROWS) {
    float4 v0 = *(const float4*)&x[i];
    float4 v1 = *(const float4*)&x[i + 4];
    w[0] = (short)f2bf(v0.x); w[1] = (short)f2bf(v0.y);
    w[2] = (short)f2bf(v0.z); w[3] = (short)f2bf(v0.w);
    w[4] = (short)f2bf(v1.x); w[5] = (short)f2bf(v1.y);
    w[6] = (short)f2bf(v1.z); w[7] = (short)f2bf(v1.w);
  } else {
    #pragma unroll
    for (int j = 0; j < 8; ++j) w[j] = 0;
  }
  *(bf16x8*)&xb[i] = w;
}

// ---------------------------------------------------------------------------
// W fp32 [K][N] -> Wt bf16 [N][K] (transpose + convert). Grid (N/64, K/64).
// ---------------------------------------------------------------------------
__global__ __launch_bounds__(256) void wtrans_kernel(
    const float* __restrict__ W, short* __restrict__ Wt, int K, int N) {
  const int n0 = blockIdx.x * 64, k0 = blockIdx.y * 64;
  __shared__ float tile[64][65];
  const int r = threadIdx.x >> 2;        // 0..63
  const int c0 = (threadIdx.x & 3) * 16; // 0,16,32,48
  const float* src = W + (size_t)(k0 + r) * N + n0 + c0;
  #pragma unroll
  for (int j = 0; j < 16; j += 4) {
    float4 v = *(const float4*)(src + j);
    tile[r][c0 + j]     = v.x;
    tile[r][c0 + j + 1] = v.y;
    tile[r][c0 + j + 2] = v.z;
    tile[r][c0 + j + 3] = v.w;
  }
  __syncthreads();
  bf16x8 w0, w1;
  #pragma unroll
  for (int j = 0; j < 8; ++j) {
    w0[j] = (short)f2bf(tile[c0 + j][r]);
    w1[j] = (short)f2bf(tile[c0 + 8 + j][r]);
  }
  short* dst = Wt + (size_t)(n0 + r) * K + k0 + c0;
  *(bf16x8*)dst = w0;
  *(bf16x8*)(dst + 8) = w1;
}

// ---------------------------------------------------------------------------
// QKV GEMM: A[MPAD,768]bf16 . Wt[2304,768]^T + bias.
// Epilogue: q,k columns -> fp32 qk32[row][1536] (LN needs fp32 accuracy);
// v columns -> bf16 vb[bh][key][64] directly (f2bf(acc+bias) is bitwise
// identical to the old fp32 store -> load -> f2bf path).
// 128x128 tile, BK=64, XCD-chunked bijective block swizzle.
// ---------------------------------------------------------------------------
__global__ __launch_bounds__(256) void gemm_qkv_kernel(
    const short* __restrict__ A, const short* __restrict__ Bt,
    const float* __restrict__ bias, float* __restrict__ qk32,
    short* __restrict__ vb) {
  __shared__ short As[128 * 64];
  __shared__ short Bs[128 * 64];
  const int tid = threadIdx.x;
  const int wid = tid >> 6, lane = tid & 63;
  const int lo = lane & 15, hi = lane >> 4;
  const int wr = wid >> 1, wc = wid & 1;

  const int nwg = gridDim.x * gridDim.y;
  int bid = blockIdx.y * gridDim.x + blockIdx.x;
  {
    const int q = nwg >> 3, rr = nwg & 7;
    const int xcd = bid & 7, idx = bid >> 3;
    bid = (xcd < rr ? xcd * (q + 1) : rr * (q + 1) + (xcd - rr) * q) + idx;
  }
  const int m0 = (bid / gridDim.x) * 128, n0 = (bid % gridDim.x) * 128;

  const int rl = lane >> 3;
  const int cb = (lane & 7) * 8;

  f32x4 acc[4][4];
  #pragma unroll
  for (int m = 0; m < 4; ++m)
    #pragma unroll
    for (int n = 0; n < 4; ++n)
      acc[m][n][0] = acc[m][n][1] = acc[m][n][2] = acc[m][n][3] = 0.f;

  const short* Abase = A + (size_t)(m0 + wid * 32 + rl) * DIM + cb;
  const short* Bbase = Bt + (size_t)(n0 + wid * 32 + rl) * DIM + cb;

  for (int k0 = 0; k0 < DIM; k0 += 64) {
    #pragma unroll
    for (int i = 0; i < 4; ++i) {
      gload16(Abase + (size_t)(i * 8) * DIM + k0, &As[(wid * 32 + i * 8) * 64]);
      gload16(Bbase + (size_t)(i * 8) * DIM + k0, &Bs[(wid * 32 + i * 8) * 64]);
    }
    __syncthreads();
    #pragma unroll
    for (int kk = 0; kk < 2; ++kk) {
      bf16x8 a[4], bfr[4];
      #pragma unroll
      for (int m = 0; m < 4; ++m)
        a[m] = *(const bf16x8*)&As[(wr * 64 + m * 16 + lo) * 64 + kk * 32 + hi * 8];
      #pragma unroll
      for (int n = 0; n < 4; ++n)
        bfr[n] = *(const bf16x8*)&Bs[(wc * 64 + n * 16 + lo) * 64 + kk * 32 + hi * 8];
      #pragma unroll
      for (int m = 0; m < 4; ++m)
        #pragma unroll
        for (int n = 0; n < 4; ++n)
          acc[m][n] = __builtin_amdgcn_mfma_f32_16x16x32_bf16(a[m], bfr[n], acc[m][n], 0, 0, 0);
    }
    __syncthreads();
  }

  const int col0 = n0 + wc * 64;           // 64-aligned => one head per wave
  const int hglob = col0 >> 6;             // 0..35
  const int htype = hglob / HEADS;         // 0=q 1=k 2=v
  const int hidx  = hglob - htype * HEADS;
  const float* bp = bias + col0 + lo;

  #pragma unroll
  for (int m = 0; m < 4; ++m) {
    #pragma unroll
    for (int r = 0; r < 4; ++r) {
      const int grow = m0 + wr * 64 + m * 16 + hi * 4 + r;
      if (grow < MROWS) {
        if (htype < 2) {
          float* cp = qk32 + (size_t)grow * C2 + col0 + lo;
          #pragma unroll
          for (int n = 0; n < 4; ++n) cp[n * 16] = acc[m][n][r] + bp[n * 16];
        } else {
          const int brow = grow / NSEQ;
          const int n1 = grow - brow * NSEQ;
          short* dst = vb + ((size_t)(brow * HEADS + hidx) * NKPAD + n1) * DH + lo;
          #pragma unroll
          for (int n = 0; n < 4; ++n)
            dst[n * 16] = (short)f2bf(acc[m][n][r] + bp[n * 16]);
        }
      }
    }
  }
}

// ---------------------------------------------------------------------------
// Generic bf16 MFMA GEMM (proj): C[M,N]f32 = A . Bt^T + bias.
// ---------------------------------------------------------------------------
__global__ __launch_bounds__(256) void gemm_bf16_kernel(
    const short* __restrict__ A, const short* __restrict__ Bt,
    const float* __restrict__ bias, float* __restrict__ C,
    int M, int N, int K) {
  __shared__ short As[128 * 64];
  __shared__ short Bs[128 * 64];
  const int tid = threadIdx.x;
  const int wid = tid >> 6, lane = tid & 63;
  const int lo = lane & 15, hi = lane >> 4;
  const int wr = wid >> 1, wc = wid & 1;

  const int nwg = gridDim.x * gridDim.y;
  int bid = blockIdx.y * gridDim.x + blockIdx.x;
  {
    const int q = nwg >> 3, rr = nwg & 7;
    const int xcd = bid & 7, idx = bid >> 3;
    bid = (xcd < rr ? xcd * (q + 1) : rr * (q + 1) + (xcd - rr) * q) + idx;
  }
  const int m0 = (bid / gridDim.x) * 128, n0 = (bid % gridDim.x) * 128;

  const int rl = lane >> 3;
  const int cb = (lane & 7) * 8;

  f32x4 acc[4][4];
  #pragma unroll
  for (int m = 0; m < 4; ++m)
    #pragma unroll
    for (int n = 0; n < 4; ++n)
      acc[m][n][0] = acc[m][n][1] = acc[m][n][2] = acc[m][n][3] = 0.f;

  const short* Abase = A + (size_t)(m0 + wid * 32 + rl) * K + cb;
  const short* Bbase = Bt + (size_t)(n0 + wid * 32 + rl) * K + cb;

  for (int k0 = 0; k0 < K; k0 += 64) {
    #pragma unroll
    for (int i = 0; i < 4; ++i) {
      gload16(Abase + (size_t)(i * 8) * K + k0, &As[(wid * 32 + i * 8) * 64]);
      gload16(Bbase + (size_t)(i * 8) * K + k0, &Bs[(wid * 32 + i * 8) * 64]);
    }
    __syncthreads();
    #pragma unroll
    for (int kk = 0; kk < 2; ++kk) {
      bf16x8 a[4], bfr[4];
      #pragma unroll
      for (int m = 0; m < 4; ++m)
        a[m] = *(const bf16x8*)&As[(wr * 64 + m * 16 + lo) * 64 + kk * 32 + hi * 8];
      #pragma unroll
      for (int n = 0; n < 4; ++n)
        bfr[n] = *(const bf16x8*)&Bs[(wc * 64 + n * 16 + lo) * 64 + kk * 32 + hi * 8];
      #pragma unroll
      for (int m = 0; m < 4; ++m)
        #pragma unroll
        for (int n = 0; n < 4; ++n)
          acc[m][n] = __builtin_amdgcn_mfma_f32_16x16x32_bf16(a[m], bfr[n], acc[m][n], 0, 0, 0);
    }
    __syncthreads();
  }

  #pragma unroll
  for (int m = 0; m < 4; ++m) {
    #pragma unroll
    for (int r = 0; r < 4; ++r) {
      const int grow = m0 + wr * 64 + m * 16 + hi * 4 + r;
      if (grow < M) {
        float* cp = C + (size_t)grow * N + n0 + wc * 64 + lo;
        const float* bp = bias + n0 + wc * 64 + lo;
        #pragma unroll
        for (int n = 0; n < 4; ++n) cp[n * 16] = acc[m][n][r] + bp[n * 16];
      }
    }
  }
}

// ---------------------------------------------------------------------------
// LayerNorm on q,k from qk32[row][1536]; Q scaled by 0.125*log2e.
// Writes ONLY bf16 qb [bh][QPAD][64], kb [bh][NKPAD][64] (no fp32 writeback).
// ---------------------------------------------------------------------------
__global__ __launch_bounds__(256) void ln_qk_kernel(
    const float* __restrict__ qk32,
    const float* __restrict__ gq, const float* __restrict__ bq,
    const float* __restrict__ gk, const float* __restrict__ bk,
    short* __restrict__ qb, short* __restrict__ kb) {
  const int task = blockIdx.x * 4 + (threadIdx.x >> 6);
  const int lane = threadIdx.x & 63;
  const int TASKS = MROWS * HEADS;
  if (task >= TASKS) return;
  const int row = task / HEADS;
  const int h = task - row * HEADS;
  const size_t base = (size_t)row * C2 + h * DH;
  float xq = qk32[base + lane];
  float xk = qk32[base + DIM + lane];
  float sq = xq, s2q = xq * xq, sk = xk, s2k = xk * xk;
  #pragma unroll
  for (int off = 32; off; off >>= 1) {
    sq  += __shfl_xor(sq,  off);
    s2q += __shfl_xor(s2q, off);
    sk  += __shfl_xor(sk,  off);
    s2k += __shfl_xor(s2k, off);
  }
  const float inv64 = 1.f / 64.f;
  float mq = sq * inv64, vq = s2q * inv64 - mq * mq;
  float mk = sk * inv64, vk = s2k * inv64 - mk * mk;
  float rq = rsqrtf(vq + 1e-5f), rk = rsqrtf(vk + 1e-5f);
  float qn = ((xq - mq) * rq * gq[lane] + bq[lane]) * QSCALE;
  float kn =  (xk - mk) * rk * gk[lane] + bk[lane];
  const int b = row / NSEQ;
  const int n = row - b * NSEQ;
  const int bh = b * HEADS + h;
  qb[((size_t)bh * QPAD  + n) * DH + lane] = (short)f2bf(qn);
  kb[((size_t)bh * NKPAD + n) * DH + lane] = (short)f2bf(kn);
}

// ---------------------------------------------------------------------------
// V transpose: vb bf16 [bh][key][64] -> vt bf16 [bh][d][NKPAD] (zero pad).
// Grid: (17, 96), 256 threads.
// ---------------------------------------------------------------------------
__global__ __launch_bounds__(256) void vt_convert_kernel(
    const short* __restrict__ vb, short* __restrict__ vt) {
  const int kt = blockIdx.x;     // key tile 0..16
  const int bh = blockIdx.y;     // 0..95
  const int t = threadIdx.x;
  __shared__ float tile[64][65];
  const int r = t >> 2;          // 0..63
  const int c0 = (t & 3) * 16;   // 0,16,32,48
  const int grow = kt * 64 + r;  // key index 0..1087

  if (grow < NSEQ) {
    const short* src = vb + ((size_t)bh * NKPAD + grow) * DH + c0;
    bf16x8 a = *(const bf16x8*)src;
    bf16x8 b2 = *(const bf16x8*)(src + 8);
    #pragma unroll
    for (int j = 0; j < 8; ++j) {
      tile[r][c0 + j]     = bf2f(a[j]);
      tile[r][c0 + 8 + j] = bf2f(b2[j]);
    }
  } else {
    #pragma unroll
    for (int j = 0; j < 16; ++j) tile[r][c0 + j] = 0.f;
  }
  __syncthreads();
  bf16x8 w0, w1;
  #pragma unroll
  for (int j = 0; j < 8; ++j) {
    w0[j] = (short)f2bf(tile[c0 + j][r]);
    w1[j] = (short)f2bf(tile[c0 + 8 + j][r]);
  }
  short* dst = vt + ((size_t)bh * DH + r) * NKPAD + kt * 64 + c0;
  *(bf16x8*)dst = w0;
  *(bf16x8*)(dst + 8) = w1;
}

// ---------------------------------------------------------------------------
// MFMA bf16 flash attention v5 (R10-proven): split-stage single-buffered K/V.
// Block = 256 threads (4 waves); wave owns 32 query rows (2 m-frags).
// Grid: (96, QPAD/128 = 9) -- XCD-local (96 % 8 == 0).
// ---------------------------------------------------------------------------
__global__ __launch_bounds__(256) void attn_mfma_kernel(
    const short* __restrict__ qb, const short* __restrict__ kb,
    const short* __restrict__ vt, short* __restrict__ ab) {
  const int bh = blockIdx.x;
  const int b = bh / HEADS, h = bh - (bh / HEADS) * HEADS;
  const int wid = threadIdx.x >> 6;
  const int lane = threadIdx.x & 63;
  const int lo = lane & 15, hi = lane >> 4;
  const int q0 = blockIdx.y * 128;
  const int xsw = (lo & 7) << 3;          // read-side XOR swizzle (shorts)

  __shared__ short Ks[64 * 64];           // swizzled K tile  [key][d]
  __shared__ short Vs[64 * 64];           // swizzled V^T tile [d][key]
  __shared__ short Pb[4][32][72];         // per-wave P buffer

  const short* kg = kb + (size_t)bh * NKPAD * DH;
  const short* vg = vt + (size_t)bh * DH * NKPAD;

  const int sr = wid * 16 + (lane >> 3);               // staging row 0..63
  const int sw = ((lane & 7) ^ (lane >> 3)) << 3;      // pre-swizzled col
  auto stageK = [&](int kt) {
    #pragma unroll
    for (int i = 0; i < 2; ++i)
      gload16(kg + (size_t)(kt * 64 + sr + i * 8) * DH + sw,
              &Ks[wid * 1024 + i * 512]);
  };
  auto stageV = [&](int kt) {
    #pragma unroll
    for (int i = 0; i < 2; ++i)
      gload16(vg + (size_t)(sr + i * 8) * NKPAD + kt * 64 + sw,
              &Vs[wid * 1024 + i * 512]);
  };

  bf16x8 aq[2][2];
  #pragma unroll
  for (int m = 0; m < 2; ++m) {
    const short* qp = qb + (size_t)bh * QPAD * DH
                    + (size_t)(q0 + wid * 32 + m * 16 + lo) * DH + hi * 8;
    aq[m][0] = *(const bf16x8*)qp;
    aq[m][1] = *(const bf16x8*)(qp + 32);
  }

  f32x4 o[2][4];
  float lsum[2][4];
  #pragma unroll
  for (int m = 0; m < 2; ++m)
    #pragma unroll
    for (int nt = 0; nt < 4; ++nt) {
      o[m][nt][0] = o[m][nt][1] = o[m][nt][2] = o[m][nt][3] = 0.f;
      lsum[m][nt] = 0.f;
    }

  stageK(0);
  stageV(0);
  __syncthreads();   // drains vmcnt(0): tile 0 staged & visible

  for (int kt = 0; kt < 17; ++kt) {
    // ---- QK^T (reads Ks) ----
    f32x4 s[2][4];
    #pragma unroll
    for (int m = 0; m < 2; ++m)
      #pragma unroll
      for (int nt = 0; nt < 4; ++nt)
        s[m][nt][0] = s[m][nt][1] = s[m][nt][2] = s[m][nt][3] = 0.f;
    __builtin_amdgcn_s_setprio(1);
    #pragma unroll
    for (int kk = 0; kk < 2; ++kk) {
      bf16x8 kf[4];
      #pragma unroll
      for (int nt = 0; nt < 4; ++nt)
        kf[nt] = *(const bf16x8*)&Ks[(nt * 16 + lo) * 64
                                     + ((kk * 32 + hi * 8) ^ xsw)];
      #pragma unroll
      for (int m = 0; m < 2; ++m)
        #pragma unroll
        for (int nt = 0; nt < 4; ++nt)
          s[m][nt] = __builtin_amdgcn_mfma_f32_16x16x32_bf16(
              aq[m][kk], kf[nt], s[m][nt], 0, 0, 0);
    }
    __builtin_amdgcn_s_setprio(0);

    __syncthreads();                  // all waves done reading Ks
    if (kt < 16) stageK(kt + 1);      // overlaps softmax + PV below

    if (kt == 16) {
      #pragma unroll
      for (int m = 0; m < 2; ++m)
        #pragma unroll
        for (int nt = 0; nt < 4; ++nt)
          if (nt * 16 + lo >= 1)
            s[m][nt][0] = s[m][nt][1] = s[m][nt][2] = s[m][nt][3] = -1e30f;
    }
    // ---- softmax (fixed offset) + P staging (packed bf16 convert) ----
    #pragma unroll
    for (int m = 0; m < 2; ++m)
      #pragma unroll
      for (int nt = 0; nt < 4; ++nt) {
        float p0 = exp2f(s[m][nt][0] - SBOUND);
        float p1 = exp2f(s[m][nt][1] - SBOUND);
        float p2 = exp2f(s[m][nt][2] - SBOUND);
        float p3 = exp2f(s[m][nt][3] - SBOUND);
        lsum[m][0] += p0; lsum[m][1] += p1;
        lsum[m][2] += p2; lsum[m][3] += p3;
        unsigned int c01 = cvtpk_bf16(p0, p1);
        unsigned int c23 = cvtpk_bf16(p2, p3);
        unsigned short* pb = (unsigned short*)&Pb[wid][m * 16 + 4 * hi][nt * 16 + lo];
        pb[0]       = (unsigned short)c01;
        pb[72]      = (unsigned short)(c01 >> 16);
        pb[144]     = (unsigned short)c23;
        pb[216]     = (unsigned short)(c23 >> 16);
      }
    // ---- PV (reads Vs) ----
    __builtin_amdgcn_s_setprio(1);
    #pragma unroll
    for (int ks = 0; ks < 2; ++ks) {
      bf16x8 pa0 = *(const bf16x8*)&Pb[wid][lo][ks * 32 + hi * 8];
      bf16x8 pa1 = *(const bf16x8*)&Pb[wid][16 + lo][ks * 32 + hi * 8];
      #pragma unroll
      for (int nt = 0; nt < 4; ++nt) {
        bf16x8 vf = *(const bf16x8*)&Vs[(nt * 16 + lo) * 64
                                        + ((ks * 32 + hi * 8) ^ xsw)];
        o[0][nt] = __builtin_amdgcn_mfma_f32_16x16x32_bf16(pa0, vf, o[0][nt], 0, 0, 0);
        o[1][nt] = __builtin_amdgcn_mfma_f32_16x16x32_bf16(pa1, vf, o[1][nt], 0, 0, 0);
      }
    }
    __builtin_amdgcn_s_setprio(0);

    __syncthreads();                  // all waves done reading Vs; drains
    if (kt < 16) stageV(kt + 1);      //   stageK's vmcnt. V overlaps next QK^T
  }

  #pragma unroll
  for (int m = 0; m < 2; ++m)
    #pragma unroll
    for (int r = 0; r < 4; ++r) {
      float v = lsum[m][r];
      v += __shfl_xor(v, 1);
      v += __shfl_xor(v, 2);
      v += __shfl_xor(v, 4);
      v += __shfl_xor(v, 8);
      lsum[m][r] = v;
    }
  #pragma unroll
  for (int m = 0; m < 2; ++m)
    #pragma unroll
    for (int r = 0; r < 4; ++r) {
      const int qrow = q0 + wid * 32 + m * 16 + 4 * hi + r;
      if (qrow < NSEQ) {
        const float inv = 1.f / lsum[m][r];
        short* op = ab + (size_t)(b * NSEQ + qrow) * DIM + h * DH + lo;
        #pragma unroll
        for (int nt = 0; nt < 4; ++nt)
          op[nt * 16] = (short)f2bf(o[m][nt][r] * inv);
      }
    }
}

// ---------------------------------------------------------------------------
// attn_map pass A: per-(b,h) row-0 softmax max & inv-denominator (bf16 in).
// Grid 96, 256 threads. ms[bh] = {max, 1/(sum*HEADS)}.
// ---------------------------------------------------------------------------
__global__ __launch_bounds__(256) void map_ms_kernel(
    const short* __restrict__ qb, const short* __restrict__ kb,
    float* __restrict__ ms) {
  const int bh = blockIdx.x;
  const int tid = threadIdx.x;
  __shared__ float q0s[64];
  __shared__ float red[256];
  if (tid < 64) q0s[tid] = bf2f(qb[(size_t)bh * QPAD * DH + tid]);
  __syncthreads();
  float s[5];
  float lm = -INFINITY;
  #pragma unroll
  for (int sl = 0; sl < 5; ++sl) {
    int j = tid + sl * 256;
    s[sl] = -INFINITY;
    if (j < NSEQ) {
      const short* kp = kb + ((size_t)bh * NKPAD + j) * DH;
      float d0 = 0.f;
      #pragma unroll
      for (int c = 0; c < 8; ++c) {
        bf16x8 kv = *(const bf16x8*)(kp + c * 8);
        #pragma unroll
        for (int e = 0; e < 8; ++e) d0 += q0s[c * 8 + e] * bf2f(kv[e]);
      }
      s[sl] = d0;
      lm = fmaxf(lm, d0);
    }
  }
  red[tid] = lm; __syncthreads();
  for (int off = 128; off > 0; off >>= 1) {
    if (tid < off) red[tid] = fmaxf(red[tid], red[tid + off]);
    __syncthreads();
  }
  const float Mx = red[0]; __syncthreads();
  float ls = 0.f;
  #pragma unroll
  for (int sl = 0; sl < 5; ++sl) {
    int j = tid + sl * 256;
    if (j < NSEQ) ls += exp2f(s[sl] - Mx);
  }
  red[tid] = ls; __syncthreads();
  for (int off = 128; off > 0; off >>= 1) {
    if (tid < off) red[tid] += red[tid + off];
    __syncthreads();
  }
  if (tid == 0) {
    ms[bh * 2]     = Mx;
    ms[bh * 2 + 1] = 1.f / (red[0] * (float)HEADS);
  }
}

// ---------------------------------------------------------------------------
// attn_map pass B: map[b][j-1] = sum_h exp2(q0_h . k_jh - M_h) * inv_h.
// Grid (4, 8), 256 threads; thread handles one (b, j). bf16 inputs.
// ---------------------------------------------------------------------------
__global__ __launch_bounds__(256) void map_p_kernel(
    const short* __restrict__ qb, const short* __restrict__ kb,
    const float* __restrict__ ms, float* __restrict__ map) {
  const int b = blockIdx.y;
  const int j = blockIdx.x * 256 + threadIdx.x + 1;   // 1..1024
  const int tid = threadIdx.x;
  __shared__ float q0s[768];
  __shared__ float msb[24];
  for (int idx = tid; idx < 768; idx += 256) {
    const int h = idx >> 6, d = idx & 63;
    q0s[idx] = bf2f(qb[(size_t)(b * HEADS + h) * QPAD * DH + d]);
  }
  if (tid < 24) msb[tid] = ms[b * HEADS * 2 + tid];
  __syncthreads();
  float acc = 0.f;
  #pragma unroll
  for (int h = 0; h < HEADS; ++h) {
    const short* kp = kb + ((size_t)(b * HEADS + h) * NKPAD + j) * DH;
    float d0 = 0.f;
    #pragma unroll
    for (int c = 0; c < 8; ++c) {
      bf16x8 kv = *(const bf16x8*)(kp + c * 8);
      const float* qp = &q0s[h * DH + c * 8];
      #pragma unroll
      for (int e = 0; e < 8; ++e) d0 += qp[e] * bf2f(kv[e]);
    }
    acc += exp2f(d0 - msb[h * 2]) * msb[h * 2 + 1];
  }
  map[(size_t)b * (NSEQ - 1) + j - 1] = acc;
}

// ---------------------------------------------------------------------------
extern "C" void kernel_launch(void* const* d_in, const int* in_sizes, int n_in,
                              void* d_out, int out_size, void* d_ws, size_t ws_size,
                              hipStream_t stream) {
  const float* x     = (const float*)d_in[0];
  const float* Wqkv  = (const float*)d_in[1];
  const float* bqkv  = (const float*)d_in[2];
  const float* Wproj = (const float*)d_in[3];
  const float* bproj = (const float*)d_in[4];
  const float* gq    = (const float*)d_in[5];
  const float* betaq = (const float*)d_in[6];
  const float* gk    = (const float*)d_in[7];
  const float* betak = (const float*)d_in[8];

  float* qk32 = (float*)d_ws;                             // [8200,1536] f32
  short* xb  = (short*)(qk32 + (size_t)MROWS * C2);       // [8320,768] bf16 (also attn out)
  short* qb  = xb + (size_t)MPAD * DIM;                   // [96,1152,64] bf16
  short* kb  = qb + (size_t)NBH * QPAD * DH;              // [96,1088,64] bf16
  short* vb  = kb + (size_t)NBH * NKPAD * DH;             // [96,1088,64] bf16
  short* vt  = vb + (size_t)NBH * NKPAD * DH;             // [96,64,1088] bf16
  short* wqt = vt + (size_t)NBH * DH * NKPAD;             // [2304,768] bf16
  short* wpt = wqt + (size_t)C3 * DIM;                    // [768,768] bf16
  float* ms  = (float*)(wpt + (size_t)DIM * DIM);         // [96,2] f32
  float* out = (float*)d_out;                             // [8200,768]
  float* map = out + (size_t)MROWS * DIM;                 // [8,1024]

  // 0) conversions
  convert_x_kernel<<<MPAD * DIM / 2048, 256, 0, stream>>>(x, xb);
  {
    dim3 grid(C3 / 64, DIM / 64);
    wtrans_kernel<<<grid, 256, 0, stream>>>(Wqkv, wqt, DIM, C3);
  }
  {
    dim3 grid(DIM / 64, DIM / 64);
    wtrans_kernel<<<grid, 256, 0, stream>>>(Wproj, wpt, DIM, DIM);
  }
  // 1) QKV GEMM: q,k -> fp32 qk32; v -> bf16 vb directly
  {
    dim3 grid(C3 / 128, MPAD / 128);
    gemm_qkv_kernel<<<grid, 256, 0, stream>>>(xb, wqt, bqkv, qk32, vb);
  }
  // 2) LN on q,k -> bf16 qb/kb only (no fp32 writeback)
  {
    int blocks = (MROWS * HEADS + 3) / 4;
    ln_qk_kernel<<<blocks, 256, 0, stream>>>(qk32, gq, betaq, gk, betak, qb, kb);
  }
  // 3) V transpose (bf16 in, bf16 out)
  {
    dim3 grid(17, NBH);
    vt_convert_kernel<<<grid, 256, 0, stream>>>(vb, vt);
  }
  // 4) MFMA attention -> bf16 into xb (dead after step 1)
  {
    dim3 grid(NBH, QPAD / 128);
    attn_mfma_kernel<<<grid, 256, 0, stream>>>(qb, kb, vt, xb);
  }
  // 5) attn_map (bf16 path, two passes)
  map_ms_kernel<<<NBH, 256, 0, stream>>>(qb, kb, ms);
  {
    dim3 grid(4, BS);
    map_p_kernel<<<grid, 256, 0, stream>>>(qb, kb, ms, map);
  }
  // 6) out = attn_out @ Wproj + bproj
  {
    dim3 grid(DIM / 128, MPAD / 128);
    gemm_bf16_kernel<<<grid, 256, 0, stream>>>(xb, wpt, bproj, out, MROWS, DIM, DIM);
  }
}